// Round 2
// baseline (1791.125 us; speedup 1.0000x reference)
//
#include <hip/hip_runtime.h>
#include <stdint.h>

// ============================================================================
// MultiHeadAttention: y = softmax((xq Wq^T)(xk Wk^T)^T * scale) (xv Wv^T) Wo^T
// B=2, S=2048, H=32, D=128, DM=4096.
// I/O is FLOAT32 (per reference dtypes). Internally: convert to bf16, MFMA.
// Stage 1: 3 projection GEMMs (f32 in -> bf16 staged -> bf16 out in ws)
// Stage 2: flash attention on bf16 intermediates
// Stage 3: output projection (bf16 ctx x f32 Wo -> f32 out)
// ============================================================================

using u16 = unsigned short;
using u32 = unsigned int;

typedef __attribute__((ext_vector_type(8))) short bf16x8;  // MFMA A/B frag (8 bf16)
typedef __attribute__((ext_vector_type(8))) u16 u16x8;
typedef __attribute__((ext_vector_type(4))) float f32x4;   // MFMA C/D frag

#define MFMA_BF16(A, B, C) __builtin_amdgcn_mfma_f32_16x16x32_bf16((A), (B), (C), 0, 0, 0)

static constexpr int kS = 2048, kDM = 4096, kD = 128;
// SCALE * log2(e): softmax computed in exp2 domain
static constexpr float kScaleLog2e = 0.08838834764831845f * 1.44269504088896340736f;

static __device__ __forceinline__ void gload_lds16(const u16* g, u16* l) {
  __builtin_amdgcn_global_load_lds((const __attribute__((address_space(1))) void*)g,
                                   (__attribute__((address_space(3))) void*)l, 16, 0, 0);
}

static __device__ __forceinline__ u16 f2bf(float f) {  // RNE f32 -> bf16 bits
  u32 u = __float_as_uint(f);
  u32 r = u + 0x7FFFu + ((u >> 16) & 1u);
  return (u16)(r >> 16);
}

static __device__ __forceinline__ u16x8 cvt8(float4 a, float4 b) {
  u16x8 r;
  r[0] = f2bf(a.x); r[1] = f2bf(a.y); r[2] = f2bf(a.z); r[3] = f2bf(a.w);
  r[4] = f2bf(b.x); r[5] = f2bf(b.y); r[6] = f2bf(b.z); r[7] = f2bf(b.w);
  return r;
}

// ---------------------------------------------------------------------------
// GEMM: Y[m][n] = sum_k X[m][k] * W[n][k], 4096x4096x4096.
// m97 structure: 128x128 tile, BK=32, 4 waves (each 64x64 = 4x4 frags).
// A_BF16: A is bf16 in global (use global_load_lds); else f32 (convert-stage).
// B always f32 (convert-stage). OUT_F32: write f32, else bf16.
// ---------------------------------------------------------------------------
template <bool A_BF16, bool OUT_F32>
static __device__ __forceinline__ void gemm_conv(const void* Xv, const float* Wf,
                                                 void* Yv) {
  constexpr int KD = 4096;
  __shared__ u16 Als[128 * 32];
  __shared__ u16 Bls[128 * 32];

  const int tid = threadIdx.x;
  const int lane = tid & 63;
  const int w = tid >> 6;
  const int fr = lane & 15;
  const int fq = lane >> 4;
  const int m0 = blockIdx.y * 128;
  const int n0 = blockIdx.x * 128;

  // convert-staging: tile = 512 chunks of 8 elems; thread t handles chunks t, t+256
  // chunk c: row = c>>2, col8 = (c&3)*8; LDS addr = c*16B (linear, conflict-free)
  const int r0 = tid >> 2, cc0 = (tid & 3) * 8;
  const int r1 = r0 + 64;  // chunk tid+256: same col8

  // bf16-A staging (global_load_lds): instance u covers 16 rows x 32 elems
  const int sr = lane >> 2, sc = (lane & 3) * 8;
  const int u0 = w * 2, u1 = w * 2 + 1;

  const u16* Xb = (const u16*)Xv;
  const float* Xf = (const float*)Xv;

  const int wm = (w >> 1) * 64;
  const int wn = (w & 1) * 64;

  f32x4 acc[4][4] = {};

  for (int kt = 0; kt < KD / 32; ++kt) {
    const int ko = kt * 32;
    if constexpr (A_BF16) {
      gload_lds16(Xb + (size_t)(m0 + u0 * 16 + sr) * KD + ko + sc, &Als[u0 * 512]);
      gload_lds16(Xb + (size_t)(m0 + u1 * 16 + sr) * KD + ko + sc, &Als[u1 * 512]);
    } else {
      const float* p0 = Xf + (size_t)(m0 + r0) * KD + ko + cc0;
      const float* p1 = Xf + (size_t)(m0 + r1) * KD + ko + cc0;
      float4 a0 = *(const float4*)(p0);
      float4 a1 = *(const float4*)(p0 + 4);
      float4 a2 = *(const float4*)(p1);
      float4 a3 = *(const float4*)(p1 + 4);
      *(u16x8*)&Als[r0 * 32 + cc0] = cvt8(a0, a1);
      *(u16x8*)&Als[r1 * 32 + cc0] = cvt8(a2, a3);
    }
    {
      const float* p0 = Wf + (size_t)(n0 + r0) * KD + ko + cc0;
      const float* p1 = Wf + (size_t)(n0 + r1) * KD + ko + cc0;
      float4 b0 = *(const float4*)(p0);
      float4 b1 = *(const float4*)(p0 + 4);
      float4 b2 = *(const float4*)(p1);
      float4 b3 = *(const float4*)(p1 + 4);
      *(u16x8*)&Bls[r0 * 32 + cc0] = cvt8(b0, b1);
      *(u16x8*)&Bls[r1 * 32 + cc0] = cvt8(b2, b3);
    }
    __syncthreads();

    bf16x8 af[4], bfv[4];
#pragma unroll
    for (int i = 0; i < 4; ++i)
      af[i] = *(const bf16x8*)&Als[(wm + i * 16 + fr) * 32 + fq * 8];
#pragma unroll
    for (int i = 0; i < 4; ++i)
      bfv[i] = *(const bf16x8*)&Bls[(wn + i * 16 + fr) * 32 + fq * 8];
#pragma unroll
    for (int mi = 0; mi < 4; ++mi)
#pragma unroll
      for (int ni = 0; ni < 4; ++ni)
        acc[mi][ni] = MFMA_BF16(af[mi], bfv[ni], acc[mi][ni]);
    __syncthreads();
  }

  // C/D layout: col = lane&15, row = (lane>>4)*4 + i  [m89/m91 verified]
#pragma unroll
  for (int mi = 0; mi < 4; ++mi)
#pragma unroll
    for (int ni = 0; ni < 4; ++ni) {
      const int row = m0 + wm + mi * 16 + fq * 4;
      const int col = n0 + wn + ni * 16 + fr;
      if constexpr (OUT_F32) {
        float* yp = (float*)Yv + (size_t)row * kDM + col;
#pragma unroll
        for (int i = 0; i < 4; ++i) yp[(size_t)i * kDM] = acc[mi][ni][i];
      } else {
        u16* yp = (u16*)Yv + (size_t)row * kDM + col;
#pragma unroll
        for (int i = 0; i < 4; ++i) yp[(size_t)i * kDM] = f2bf(acc[mi][ni][i]);
      }
    }
}

__global__ __launch_bounds__(256) void proj_qkv_kernel(
    const float* __restrict__ q, const float* __restrict__ k, const float* __restrict__ v,
    const float* __restrict__ Wq, const float* __restrict__ Wk, const float* __restrict__ Wv,
    u16* __restrict__ qp, u16* __restrict__ kp, u16* __restrict__ vp) {
  const int z = blockIdx.z;
  const float* X = (z == 0) ? q : (z == 1) ? k : v;
  const float* W = (z == 0) ? Wq : (z == 1) ? Wk : Wv;
  u16* Y = (z == 0) ? qp : (z == 1) ? kp : vp;
  gemm_conv<false, false>(X, W, Y);
}

__global__ __launch_bounds__(256) void out_proj_kernel(const u16* __restrict__ ctx,
                                                       const float* __restrict__ Wo,
                                                       float* __restrict__ out) {
  gemm_conv<true, true>(ctx, Wo, out);
}

// ---------------------------------------------------------------------------
// Flash attention. Grid: (S/128, B*H). Block 256 = 4 waves.
// Each wave owns 32 q-rows (2 row-blocks of 16). KB=64 keys per tile.
// K in LDS [key][d] with 16B-chunk XOR swizzle (chunk ^= key&7), staged via
// global_load_lds with pre-swizzled SOURCE address (linear LDS dest).
// V in LDS transposed [d][key], chunks XOR-swizzled: c ^= (d&7)^((d>>3)&7).
// ---------------------------------------------------------------------------
__global__ __launch_bounds__(256) void attn_kernel(const u16* __restrict__ qp,
                                                   const u16* __restrict__ kp,
                                                   const u16* __restrict__ vp,
                                                   u16* __restrict__ ctx) {
  constexpr int KB = 64;
  constexpr int PST = 72;  // P row stride (elems)

  __shared__ u16 Kls[KB * 128];        // 16 KB
  __shared__ u16 Vtls[128 * KB];       // 16 KB  [d][key], chunk-swizzled
  __shared__ u16 Pls[4][2 * 16 * PST]; // per-wave P tiles

  const int tid = threadIdx.x, lane = tid & 63, w = tid >> 6;
  const int fr = lane & 15, fq = lane >> 4;
  const int bh = blockIdx.y;
  const int b = bh >> 5, h = bh & 31;
  const int q0 = blockIdx.x * 128;

  const u16* qbase = qp + ((size_t)b * kS) * kDM + h * kD;
  const u16* kbase = kp + ((size_t)b * kS) * kDM + h * kD;
  const u16* vbase = vp + ((size_t)b * kS) * kDM + h * kD;

  bf16x8 qf[2][4];
#pragma unroll
  for (int rb = 0; rb < 2; ++rb)
#pragma unroll
    for (int kc = 0; kc < 4; ++kc)
      qf[rb][kc] = *(const bf16x8*)(qbase + (size_t)(q0 + w * 32 + rb * 16 + fr) * kDM +
                                    kc * 32 + fq * 8);

  f32x4 oacc[2][8] = {};
  float mrun[2][4], lrun[2][4];
#pragma unroll
  for (int rb = 0; rb < 2; ++rb)
#pragma unroll
    for (int i = 0; i < 4; ++i) {
      mrun[rb][i] = -1e30f;
      lrun[rb][i] = 0.f;
    }

  const int krl = lane >> 4;
  const int kdp = lane & 15;
  const int vdp = tid & 15;

  for (int kt = 0; kt < kS / KB; ++kt) {
    const int kr0 = kt * KB;
#pragma unroll
    for (int t = 0; t < 4; ++t) {
      const int u = w * 4 + t;
      const int r = u * 4 + krl;
      const int dps = kdp ^ (r & 7);
      gload_lds16(kbase + (size_t)(kr0 + r) * kDM + dps * 8, &Kls[u * 512]);
    }
    u16x8 vv[4];
#pragma unroll
    for (int t = 0; t < 4; ++t) {
      const int r = (tid >> 4) + 16 * t;
      vv[t] = *(const u16x8*)(vbase + (size_t)(kr0 + r) * kDM + vdp * 8);
    }
#pragma unroll
    for (int t = 0; t < 4; ++t) {
      const int r = (tid >> 4) + 16 * t;
#pragma unroll
      for (int j = 0; j < 8; ++j) {
        const int d = vdp * 8 + j;
        const int cs = (r >> 3) ^ (d & 7) ^ ((d >> 3) & 7);
        Vtls[d * KB + cs * 8 + (r & 7)] = vv[t][j];
      }
    }
    __syncthreads();

    // --- QK^T ---
    f32x4 sacc[2][4] = {};
#pragma unroll
    for (int cb = 0; cb < 4; ++cb) {
      const int n = cb * 16 + fr;
      bf16x8 kf[4];
#pragma unroll
      for (int kc = 0; kc < 4; ++kc) {
        const int d0 = kc * 4 + fq;
        kf[kc] = *(const bf16x8*)&Kls[n * 128 + (d0 ^ (n & 7)) * 8];
      }
#pragma unroll
      for (int rb = 0; rb < 2; ++rb)
#pragma unroll
        for (int kc = 0; kc < 4; ++kc)
          sacc[rb][cb] = MFMA_BF16(qf[rb][kc], kf[kc], sacc[rb][cb]);
    }

    // --- online softmax (exp2 domain) ---
#pragma unroll
    for (int rb = 0; rb < 2; ++rb) {
      float s2[4][4];
#pragma unroll
      for (int cb = 0; cb < 4; ++cb)
#pragma unroll
        for (int i = 0; i < 4; ++i) s2[cb][i] = sacc[rb][cb][i] * kScaleLog2e;
      float mt[4];
#pragma unroll
      for (int i = 0; i < 4; ++i)
        mt[i] = fmaxf(fmaxf(s2[0][i], s2[1][i]), fmaxf(s2[2][i], s2[3][i]));
#pragma unroll
      for (int off = 1; off < 16; off <<= 1)
#pragma unroll
        for (int i = 0; i < 4; ++i) mt[i] = fmaxf(mt[i], __shfl_xor(mt[i], off));

      float scl[4], rsum[4];
#pragma unroll
      for (int i = 0; i < 4; ++i) {
        const float mnew = fmaxf(mrun[rb][i], mt[i]);
        scl[i] = exp2f(mrun[rb][i] - mnew);
        mrun[rb][i] = mnew;
        rsum[i] = 0.f;
      }
#pragma unroll
      for (int cb = 0; cb < 4; ++cb)
#pragma unroll
        for (int i = 0; i < 4; ++i) {
          const float p = exp2f(s2[cb][i] - mrun[rb][i]);
          rsum[i] += p;
          Pls[w][rb * (16 * PST) + (fq * 4 + i) * PST + cb * 16 + fr] = f2bf(p);
        }
#pragma unroll
      for (int off = 1; off < 16; off <<= 1)
#pragma unroll
        for (int i = 0; i < 4; ++i) rsum[i] += __shfl_xor(rsum[i], off);
#pragma unroll
      for (int i = 0; i < 4; ++i) lrun[rb][i] = lrun[rb][i] * scl[i] + rsum[i];
#pragma unroll
      for (int db = 0; db < 8; ++db)
#pragma unroll
        for (int i = 0; i < 4; ++i) oacc[rb][db][i] *= scl[i];
    }

    asm volatile("s_waitcnt lgkmcnt(0)" ::: "memory");

    // --- PV ---
    bf16x8 pf[2][2];
#pragma unroll
    for (int rb = 0; rb < 2; ++rb)
#pragma unroll
      for (int kb = 0; kb < 2; ++kb)
        pf[rb][kb] = *(const bf16x8*)&Pls[w][rb * (16 * PST) + fr * PST + kb * 32 + fq * 8];
#pragma unroll
    for (int db = 0; db < 8; ++db) {
      const int d = db * 16 + fr;
      const int xs = (d & 7) ^ ((d >> 3) & 7);
      bf16x8 vf0 = *(const bf16x8*)&Vtls[d * KB + ((0 + fq) ^ xs) * 8];
      bf16x8 vf1 = *(const bf16x8*)&Vtls[d * KB + ((4 + fq) ^ xs) * 8];
#pragma unroll
      for (int rb = 0; rb < 2; ++rb) {
        oacc[rb][db] = MFMA_BF16(pf[rb][0], vf0, oacc[rb][db]);
        oacc[rb][db] = MFMA_BF16(pf[rb][1], vf1, oacc[rb][db]);
      }
    }
    __syncthreads();
  }

  u16* cbase = ctx + ((size_t)b * kS) * kDM + h * kD;
#pragma unroll
  for (int rb = 0; rb < 2; ++rb) {
    float inv[4];
#pragma unroll
    for (int i = 0; i < 4; ++i) inv[i] = 1.0f / lrun[rb][i];
#pragma unroll
    for (int db = 0; db < 8; ++db)
#pragma unroll
      for (int i = 0; i < 4; ++i) {
        const int row = q0 + w * 32 + rb * 16 + fq * 4 + i;
        const int col = db * 16 + fr;
        cbase[(size_t)row * kDM + col] = f2bf(oacc[rb][db][i] * inv[i]);
      }
  }
}

// ---------------------------------------------------------------------------
extern "C" void kernel_launch(void* const* d_in, const int* in_sizes, int n_in,
                              void* d_out, int out_size, void* d_ws, size_t ws_size,
                              hipStream_t stream) {
  const float* q = (const float*)d_in[0];
  const float* k = (const float*)d_in[1];
  const float* v = (const float*)d_in[2];
  const float* Wq = (const float*)d_in[3];
  const float* Wk = (const float*)d_in[4];
  const float* Wv = (const float*)d_in[5];
  const float* Wo = (const float*)d_in[6];
  float* out = (float*)d_out;

  const size_t mat = (size_t)4096 * 4096;  // elems per [B*S, DM] matrix
  u16* qp = (u16*)d_ws;
  u16* kp = qp + mat;
  u16* vp = kp + mat;
  u16* ctx = vp + mat;

  proj_qkv_kernel<<<dim3(32, 32, 3), 256, 0, stream>>>(q, k, v, Wq, Wk, Wv, qp, kp, vp);
  attn_kernel<<<dim3(16, 64), 256, 0, stream>>>(qp, kp, vp, ctx);
  out_proj_kernel<<<dim3(32, 32, 1), 256, 0, stream>>>(ctx, Wo, out);
}

// Round 3
// 1323.971 us; speedup vs baseline: 1.3528x; 1.3528x over previous
//
#include <hip/hip_runtime.h>
#include <stdint.h>

// ============================================================================
// MultiHeadAttention: y = softmax((xq Wq^T)(xk Wk^T)^T * scale) (xv Wv^T) Wo^T
// B=2, S=2048, H=32, D=128, DM=4096. I/O float32.
// R3: pre-convert all 7 f32 matrices to bf16 in ws (memory-bound pass), then
// pure-bf16 m97-structure GEMMs with global_load_lds on both operands.
// Fallback to in-GEMM convert-staging if ws_size is too small.
// ============================================================================

using u16 = unsigned short;
using u32 = unsigned int;

typedef __attribute__((ext_vector_type(8))) short bf16x8;  // MFMA A/B frag (8 bf16)
typedef __attribute__((ext_vector_type(8))) u16 u16x8;
typedef __attribute__((ext_vector_type(4))) float f32x4;   // MFMA C/D frag

#define MFMA_BF16(A, B, C) __builtin_amdgcn_mfma_f32_16x16x32_bf16((A), (B), (C), 0, 0, 0)

static constexpr int kS = 2048, kDM = 4096, kD = 128;
static constexpr size_t kMat = (size_t)4096 * 4096;
// SCALE * log2(e): softmax computed in exp2 domain
static constexpr float kScaleLog2e = 0.08838834764831845f * 1.44269504088896340736f;

static __device__ __forceinline__ void gload_lds16(const u16* g, u16* l) {
  __builtin_amdgcn_global_load_lds((const __attribute__((address_space(1))) void*)g,
                                   (__attribute__((address_space(3))) void*)l, 16, 0, 0);
}

static __device__ __forceinline__ u16 f2bf(float f) {  // RNE f32 -> bf16 bits
  u32 u = __float_as_uint(f);
  u32 r = u + 0x7FFFu + ((u >> 16) & 1u);
  return (u16)(r >> 16);
}

static __device__ __forceinline__ u16x8 cvt8(float4 a, float4 b) {
  u16x8 r;
  r[0] = f2bf(a.x); r[1] = f2bf(a.y); r[2] = f2bf(a.z); r[3] = f2bf(a.w);
  r[4] = f2bf(b.x); r[5] = f2bf(b.y); r[6] = f2bf(b.z); r[7] = f2bf(b.w);
  return r;
}

// ---------------------------------------------------------------------------
// f32 -> bf16 bulk conversion: 7 matrices of kMat elems. Grid (X, 7).
// ---------------------------------------------------------------------------
__global__ __launch_bounds__(256) void cvt_kernel(
    const float* __restrict__ s0, const float* __restrict__ s1,
    const float* __restrict__ s2, const float* __restrict__ s3,
    const float* __restrict__ s4, const float* __restrict__ s5,
    const float* __restrict__ s6, u16* __restrict__ dst) {
  const int y = blockIdx.y;
  const float* s = (y == 0) ? s0 : (y == 1) ? s1 : (y == 2) ? s2 : (y == 3) ? s3
                  : (y == 4) ? s4 : (y == 5) ? s5 : s6;
  u16* d = dst + (size_t)y * kMat;
  const size_t nchunk = kMat / 8;
  const size_t step = (size_t)gridDim.x * 256;
  for (size_t c = (size_t)blockIdx.x * 256 + threadIdx.x; c < nchunk; c += step) {
    const float* p = s + c * 8;
    float4 a = *(const float4*)p;
    float4 b = *(const float4*)(p + 4);
    *(u16x8*)(d + c * 8) = cvt8(a, b);
  }
}

// ---------------------------------------------------------------------------
// Pure-bf16 GEMM: Y[m][n] = sum_k X[m][k] * W[n][k], 4096x4096x4096.
// m97 structure: 128x128 tile, BK=32, 4 waves, global_load_lds both sides.
// ---------------------------------------------------------------------------
template <bool OUT_F32>
static __device__ __forceinline__ void gemm_bt_128(const u16* __restrict__ X,
                                                   const u16* __restrict__ W,
                                                   void* __restrict__ Yv) {
  constexpr int KD = 4096;
  __shared__ u16 Als[128 * 32];
  __shared__ u16 Bls[128 * 32];

  const int tid = threadIdx.x;
  const int lane = tid & 63;
  const int w = tid >> 6;
  const int fr = lane & 15;
  const int fq = lane >> 4;
  const int m0 = blockIdx.y * 128;
  const int n0 = blockIdx.x * 128;

  // staging: instance u covers 16 rows x 32 elems (1024B); lane i -> row i/4, chunk i%4
  const int sr = lane >> 2;
  const int sc = (lane & 3) * 8;
  const int u0 = w * 2 + 0, u1 = w * 2 + 1;
  const u16* gA0 = X + (size_t)(m0 + u0 * 16 + sr) * KD + sc;
  const u16* gA1 = X + (size_t)(m0 + u1 * 16 + sr) * KD + sc;
  const u16* gB0 = W + (size_t)(n0 + u0 * 16 + sr) * KD + sc;
  const u16* gB1 = W + (size_t)(n0 + u1 * 16 + sr) * KD + sc;
  u16* lA0 = &Als[u0 * 512];
  u16* lA1 = &Als[u1 * 512];
  u16* lB0 = &Bls[u0 * 512];
  u16* lB1 = &Bls[u1 * 512];

  const int wm = (w >> 1) * 64;
  const int wn = (w & 1) * 64;

  f32x4 acc[4][4] = {};

  for (int kt = 0; kt < KD / 32; ++kt) {
    const int ko = kt * 32;
    gload_lds16(gA0 + ko, lA0);
    gload_lds16(gA1 + ko, lA1);
    gload_lds16(gB0 + ko, lB0);
    gload_lds16(gB1 + ko, lB1);
    __syncthreads();

    bf16x8 af[4], bfv[4];
#pragma unroll
    for (int i = 0; i < 4; ++i)
      af[i] = *(const bf16x8*)&Als[(wm + i * 16 + fr) * 32 + fq * 8];
#pragma unroll
    for (int i = 0; i < 4; ++i)
      bfv[i] = *(const bf16x8*)&Bls[(wn + i * 16 + fr) * 32 + fq * 8];
#pragma unroll
    for (int mi = 0; mi < 4; ++mi)
#pragma unroll
      for (int ni = 0; ni < 4; ++ni)
        acc[mi][ni] = MFMA_BF16(af[mi], bfv[ni], acc[mi][ni]);
    __syncthreads();
  }

  // C/D layout: col = lane&15, row = (lane>>4)*4 + i  [m89/m91 verified]
#pragma unroll
  for (int mi = 0; mi < 4; ++mi)
#pragma unroll
    for (int ni = 0; ni < 4; ++ni) {
      const int row = m0 + wm + mi * 16 + fq * 4;
      const int col = n0 + wn + ni * 16 + fr;
      if constexpr (OUT_F32) {
        float* yp = (float*)Yv + (size_t)row * kDM + col;
#pragma unroll
        for (int i = 0; i < 4; ++i) yp[(size_t)i * kDM] = acc[mi][ni][i];
      } else {
        u16* yp = (u16*)Yv + (size_t)row * kDM + col;
#pragma unroll
        for (int i = 0; i < 4; ++i) yp[(size_t)i * kDM] = f2bf(acc[mi][ni][i]);
      }
    }
}

__global__ __launch_bounds__(256) void proj_qkv_bf16_kernel(
    const u16* __restrict__ ws_base, u16* __restrict__ qp, u16* __restrict__ kp,
    u16* __restrict__ vp) {
  const int z = blockIdx.z;
  const u16* X = ws_base + (size_t)z * kMat;        // qb/kb/vb
  const u16* W = ws_base + (size_t)(3 + z) * kMat;  // Wqb/Wkb/Wvb
  u16* Y = (z == 0) ? qp : (z == 1) ? kp : vp;
  gemm_bt_128<false>(X, W, Y);
}

__global__ __launch_bounds__(256) void out_proj_bf16_kernel(
    const u16* __restrict__ ctx, const u16* __restrict__ Wob, float* __restrict__ out) {
  gemm_bt_128<true>(ctx, Wob, out);
}

// ---------------------------------------------------------------------------
// FALLBACK path (ws too small): in-GEMM convert staging (round-2 verified).
// ---------------------------------------------------------------------------
template <bool A_BF16, bool OUT_F32>
static __device__ __forceinline__ void gemm_conv(const void* Xv, const float* Wf,
                                                 void* Yv) {
  constexpr int KD = 4096;
  __shared__ u16 Als[128 * 32];
  __shared__ u16 Bls[128 * 32];

  const int tid = threadIdx.x;
  const int lane = tid & 63;
  const int w = tid >> 6;
  const int fr = lane & 15;
  const int fq = lane >> 4;
  const int m0 = blockIdx.y * 128;
  const int n0 = blockIdx.x * 128;

  const int r0 = tid >> 2, cc0 = (tid & 3) * 8;
  const int r1 = r0 + 64;
  const int sr = lane >> 2, sc = (lane & 3) * 8;
  const int u0 = w * 2, u1 = w * 2 + 1;

  const u16* Xb = (const u16*)Xv;
  const float* Xf = (const float*)Xv;

  const int wm = (w >> 1) * 64;
  const int wn = (w & 1) * 64;

  f32x4 acc[4][4] = {};

  for (int kt = 0; kt < KD / 32; ++kt) {
    const int ko = kt * 32;
    if constexpr (A_BF16) {
      gload_lds16(Xb + (size_t)(m0 + u0 * 16 + sr) * KD + ko + sc, &Als[u0 * 512]);
      gload_lds16(Xb + (size_t)(m0 + u1 * 16 + sr) * KD + ko + sc, &Als[u1 * 512]);
    } else {
      const float* p0 = Xf + (size_t)(m0 + r0) * KD + ko + cc0;
      const float* p1 = Xf + (size_t)(m0 + r1) * KD + ko + cc0;
      float4 a0 = *(const float4*)(p0);
      float4 a1 = *(const float4*)(p0 + 4);
      float4 a2 = *(const float4*)(p1);
      float4 a3 = *(const float4*)(p1 + 4);
      *(u16x8*)&Als[r0 * 32 + cc0] = cvt8(a0, a1);
      *(u16x8*)&Als[r1 * 32 + cc0] = cvt8(a2, a3);
    }
    {
      const float* p0 = Wf + (size_t)(n0 + r0) * KD + ko + cc0;
      const float* p1 = Wf + (size_t)(n0 + r1) * KD + ko + cc0;
      float4 b0 = *(const float4*)(p0);
      float4 b1 = *(const float4*)(p0 + 4);
      float4 b2 = *(const float4*)(p1);
      float4 b3 = *(const float4*)(p1 + 4);
      *(u16x8*)&Bls[r0 * 32 + cc0] = cvt8(b0, b1);
      *(u16x8*)&Bls[r1 * 32 + cc0] = cvt8(b2, b3);
    }
    __syncthreads();

    bf16x8 af[4], bfv[4];
#pragma unroll
    for (int i = 0; i < 4; ++i)
      af[i] = *(const bf16x8*)&Als[(wm + i * 16 + fr) * 32 + fq * 8];
#pragma unroll
    for (int i = 0; i < 4; ++i)
      bfv[i] = *(const bf16x8*)&Bls[(wn + i * 16 + fr) * 32 + fq * 8];
#pragma unroll
    for (int mi = 0; mi < 4; ++mi)
#pragma unroll
      for (int ni = 0; ni < 4; ++ni)
        acc[mi][ni] = MFMA_BF16(af[mi], bfv[ni], acc[mi][ni]);
    __syncthreads();
  }

#pragma unroll
  for (int mi = 0; mi < 4; ++mi)
#pragma unroll
    for (int ni = 0; ni < 4; ++ni) {
      const int row = m0 + wm + mi * 16 + fq * 4;
      const int col = n0 + wn + ni * 16 + fr;
      if constexpr (OUT_F32) {
        float* yp = (float*)Yv + (size_t)row * kDM + col;
#pragma unroll
        for (int i = 0; i < 4; ++i) yp[(size_t)i * kDM] = acc[mi][ni][i];
      } else {
        u16* yp = (u16*)Yv + (size_t)row * kDM + col;
#pragma unroll
        for (int i = 0; i < 4; ++i) yp[(size_t)i * kDM] = f2bf(acc[mi][ni][i]);
      }
    }
}

__global__ __launch_bounds__(256) void proj_qkv_conv_kernel(
    const float* __restrict__ q, const float* __restrict__ k, const float* __restrict__ v,
    const float* __restrict__ Wq, const float* __restrict__ Wk, const float* __restrict__ Wv,
    u16* __restrict__ qp, u16* __restrict__ kp, u16* __restrict__ vp) {
  const int z = blockIdx.z;
  const float* X = (z == 0) ? q : (z == 1) ? k : v;
  const float* W = (z == 0) ? Wq : (z == 1) ? Wk : Wv;
  u16* Y = (z == 0) ? qp : (z == 1) ? kp : vp;
  gemm_conv<false, false>(X, W, Y);
}

__global__ __launch_bounds__(256) void out_proj_conv_kernel(const u16* __restrict__ ctx,
                                                            const float* __restrict__ Wo,
                                                            float* __restrict__ out) {
  gemm_conv<true, true>(ctx, Wo, out);
}

// ---------------------------------------------------------------------------
// Flash attention. Grid: (S/128, B*H). Block 256 = 4 waves.
// Each wave owns 32 q-rows (2 row-blocks of 16). KB=64 keys per tile.
// ---------------------------------------------------------------------------
__global__ __launch_bounds__(256) void attn_kernel(const u16* __restrict__ qp,
                                                   const u16* __restrict__ kp,
                                                   const u16* __restrict__ vp,
                                                   u16* __restrict__ ctx) {
  constexpr int KB = 64;
  constexpr int PST = 72;  // P row stride (elems)

  __shared__ u16 Kls[KB * 128];        // 16 KB
  __shared__ u16 Vtls[128 * KB];       // 16 KB  [d][key], chunk-swizzled
  __shared__ u16 Pls[4][2 * 16 * PST]; // per-wave P tiles

  const int tid = threadIdx.x, lane = tid & 63, w = tid >> 6;
  const int fr = lane & 15, fq = lane >> 4;
  const int bh = blockIdx.y;
  const int b = bh >> 5, h = bh & 31;
  const int q0 = blockIdx.x * 128;

  const u16* qbase = qp + ((size_t)b * kS) * kDM + h * kD;
  const u16* kbase = kp + ((size_t)b * kS) * kDM + h * kD;
  const u16* vbase = vp + ((size_t)b * kS) * kDM + h * kD;

  bf16x8 qf[2][4];
#pragma unroll
  for (int rb = 0; rb < 2; ++rb)
#pragma unroll
    for (int kc = 0; kc < 4; ++kc)
      qf[rb][kc] = *(const bf16x8*)(qbase + (size_t)(q0 + w * 32 + rb * 16 + fr) * kDM +
                                    kc * 32 + fq * 8);

  f32x4 oacc[2][8] = {};
  float mrun[2][4], lrun[2][4];
#pragma unroll
  for (int rb = 0; rb < 2; ++rb)
#pragma unroll
    for (int i = 0; i < 4; ++i) {
      mrun[rb][i] = -1e30f;
      lrun[rb][i] = 0.f;
    }

  const int krl = lane >> 4;
  const int kdp = lane & 15;
  const int vdp = tid & 15;

  for (int kt = 0; kt < kS / KB; ++kt) {
    const int kr0 = kt * KB;
#pragma unroll
    for (int t = 0; t < 4; ++t) {
      const int u = w * 4 + t;
      const int r = u * 4 + krl;
      const int dps = kdp ^ (r & 7);
      gload_lds16(kbase + (size_t)(kr0 + r) * kDM + dps * 8, &Kls[u * 512]);
    }
    u16x8 vv[4];
#pragma unroll
    for (int t = 0; t < 4; ++t) {
      const int r = (tid >> 4) + 16 * t;
      vv[t] = *(const u16x8*)(vbase + (size_t)(kr0 + r) * kDM + vdp * 8);
    }
#pragma unroll
    for (int t = 0; t < 4; ++t) {
      const int r = (tid >> 4) + 16 * t;
#pragma unroll
      for (int j = 0; j < 8; ++j) {
        const int d = vdp * 8 + j;
        const int cs = (r >> 3) ^ (d & 7) ^ ((d >> 3) & 7);
        Vtls[d * KB + cs * 8 + (r & 7)] = vv[t][j];
      }
    }
    __syncthreads();

    // --- QK^T ---
    f32x4 sacc[2][4] = {};
#pragma unroll
    for (int cb = 0; cb < 4; ++cb) {
      const int n = cb * 16 + fr;
      bf16x8 kf[4];
#pragma unroll
      for (int kc = 0; kc < 4; ++kc) {
        const int d0 = kc * 4 + fq;
        kf[kc] = *(const bf16x8*)&Kls[n * 128 + (d0 ^ (n & 7)) * 8];
      }
#pragma unroll
      for (int rb = 0; rb < 2; ++rb)
#pragma unroll
        for (int kc = 0; kc < 4; ++kc)
          sacc[rb][cb] = MFMA_BF16(qf[rb][kc], kf[kc], sacc[rb][cb]);
    }

    // --- online softmax (exp2 domain) ---
#pragma unroll
    for (int rb = 0; rb < 2; ++rb) {
      float s2[4][4];
#pragma unroll
      for (int cb = 0; cb < 4; ++cb)
#pragma unroll
        for (int i = 0; i < 4; ++i) s2[cb][i] = sacc[rb][cb][i] * kScaleLog2e;
      float mt[4];
#pragma unroll
      for (int i = 0; i < 4; ++i)
        mt[i] = fmaxf(fmaxf(s2[0][i], s2[1][i]), fmaxf(s2[2][i], s2[3][i]));
#pragma unroll
      for (int off = 1; off < 16; off <<= 1)
#pragma unroll
        for (int i = 0; i < 4; ++i) mt[i] = fmaxf(mt[i], __shfl_xor(mt[i], off));

      float scl[4], rsum[4];
#pragma unroll
      for (int i = 0; i < 4; ++i) {
        const float mnew = fmaxf(mrun[rb][i], mt[i]);
        scl[i] = exp2f(mrun[rb][i] - mnew);
        mrun[rb][i] = mnew;
        rsum[i] = 0.f;
      }
#pragma unroll
      for (int cb = 0; cb < 4; ++cb)
#pragma unroll
        for (int i = 0; i < 4; ++i) {
          const float p = exp2f(s2[cb][i] - mrun[rb][i]);
          rsum[i] += p;
          Pls[w][rb * (16 * PST) + (fq * 4 + i) * PST + cb * 16 + fr] = f2bf(p);
        }
#pragma unroll
      for (int off = 1; off < 16; off <<= 1)
#pragma unroll
        for (int i = 0; i < 4; ++i) rsum[i] += __shfl_xor(rsum[i], off);
#pragma unroll
      for (int i = 0; i < 4; ++i) lrun[rb][i] = lrun[rb][i] * scl[i] + rsum[i];
#pragma unroll
      for (int db = 0; db < 8; ++db)
#pragma unroll
        for (int i = 0; i < 4; ++i) oacc[rb][db][i] *= scl[i];
    }

    asm volatile("s_waitcnt lgkmcnt(0)" ::: "memory");

    // --- PV ---
    bf16x8 pf[2][2];
#pragma unroll
    for (int rb = 0; rb < 2; ++rb)
#pragma unroll
      for (int kb = 0; kb < 2; ++kb)
        pf[rb][kb] = *(const bf16x8*)&Pls[w][rb * (16 * PST) + fr * PST + kb * 32 + fq * 8];
#pragma unroll
    for (int db = 0; db < 8; ++db) {
      const int d = db * 16 + fr;
      const int xs = (d & 7) ^ ((d >> 3) & 7);
      bf16x8 vf0 = *(const bf16x8*)&Vtls[d * KB + ((0 + fq) ^ xs) * 8];
      bf16x8 vf1 = *(const bf16x8*)&Vtls[d * KB + ((4 + fq) ^ xs) * 8];
#pragma unroll
      for (int rb = 0; rb < 2; ++rb) {
        oacc[rb][db] = MFMA_BF16(pf[rb][0], vf0, oacc[rb][db]);
        oacc[rb][db] = MFMA_BF16(pf[rb][1], vf1, oacc[rb][db]);
      }
    }
    __syncthreads();
  }

  u16* cbase = ctx + ((size_t)b * kS) * kDM + h * kD;
#pragma unroll
  for (int rb = 0; rb < 2; ++rb) {
    float inv[4];
#pragma unroll
    for (int i = 0; i < 4; ++i) inv[i] = 1.0f / lrun[rb][i];
#pragma unroll
    for (int db = 0; db < 8; ++db)
#pragma unroll
      for (int i = 0; i < 4; ++i) {
        const int row = q0 + w * 32 + rb * 16 + fq * 4 + i;
        const int col = db * 16 + fr;
        cbase[(size_t)row * kDM + col] = f2bf(oacc[rb][db][i] * inv[i]);
      }
  }
}

// ---------------------------------------------------------------------------
extern "C" void kernel_launch(void* const* d_in, const int* in_sizes, int n_in,
                              void* d_out, int out_size, void* d_ws, size_t ws_size,
                              hipStream_t stream) {
  const float* q = (const float*)d_in[0];
  const float* k = (const float*)d_in[1];
  const float* v = (const float*)d_in[2];
  const float* Wq = (const float*)d_in[3];
  const float* Wk = (const float*)d_in[4];
  const float* Wv = (const float*)d_in[5];
  const float* Wo = (const float*)d_in[6];
  float* out = (float*)d_out;

  const size_t needFast = 11 * kMat * sizeof(u16);  // 7 bf16 inputs + qp/kp/vp/ctx

  if (ws_size >= needFast) {
    u16* wsb = (u16*)d_ws;            // [0..6]: qb kb vb Wqb Wkb Wvb Wob
    u16* qp = wsb + 7 * kMat;
    u16* kp = wsb + 8 * kMat;
    u16* vp = wsb + 9 * kMat;
    u16* ctx = wsb + 10 * kMat;

    cvt_kernel<<<dim3(1024, 7), 256, 0, stream>>>(q, k, v, Wq, Wk, Wv, Wo, wsb);
    proj_qkv_bf16_kernel<<<dim3(32, 32, 3), 256, 0, stream>>>(wsb, qp, kp, vp);
    attn_kernel<<<dim3(16, 64), 256, 0, stream>>>(qp, kp, vp, ctx);
    out_proj_bf16_kernel<<<dim3(32, 32, 1), 256, 0, stream>>>(ctx, wsb + 6 * kMat, out);
  } else {
    u16* qp = (u16*)d_ws;
    u16* kp = qp + kMat;
    u16* vp = kp + kMat;
    u16* ctx = vp + kMat;

    proj_qkv_conv_kernel<<<dim3(32, 32, 3), 256, 0, stream>>>(q, k, v, Wq, Wk, Wv, qp, kp, vp);
    attn_kernel<<<dim3(16, 64), 256, 0, stream>>>(qp, kp, vp, ctx);
    out_proj_conv_kernel<<<dim3(32, 32, 1), 256, 0, stream>>>(ctx, Wo, out);
  }
}

// Round 4
// 1274.821 us; speedup vs baseline: 1.4050x; 1.0386x over previous
//
#include <hip/hip_runtime.h>
#include <stdint.h>

// ============================================================================
// MultiHeadAttention: y = softmax((xq Wq^T)(xk Wk^T)^T * scale) (xv Wv^T) Wo^T
// B=2, S=2048, H=32, D=128, DM=4096. I/O float32.
// R4: V-projection emits vp TRANSPOSED (vpT[n=h*128+d][m=b*2048+s]) by
// swapping MFMA operands — attn V-staging becomes plain global_load_lds and
// the PV B-fragment a conflict-free ds_read_b128 (removes 32 scalar LDS
// writes/thread/tile + the reg-transpose VALU).
// ============================================================================

using u16 = unsigned short;
using u32 = unsigned int;

typedef __attribute__((ext_vector_type(8))) short bf16x8;  // MFMA A/B frag (8 bf16)
typedef __attribute__((ext_vector_type(8))) u16 u16x8;
typedef __attribute__((ext_vector_type(4))) float f32x4;   // MFMA C/D frag

#define MFMA_BF16(A, B, C) __builtin_amdgcn_mfma_f32_16x16x32_bf16((A), (B), (C), 0, 0, 0)

static constexpr int kS = 2048, kDM = 4096, kD = 128;
static constexpr size_t kMat = (size_t)4096 * 4096;
// SCALE * log2(e): softmax computed in exp2 domain
static constexpr float kScaleLog2e = 0.08838834764831845f * 1.44269504088896340736f;

static __device__ __forceinline__ void gload_lds16(const u16* g, u16* l) {
  __builtin_amdgcn_global_load_lds((const __attribute__((address_space(1))) void*)g,
                                   (__attribute__((address_space(3))) void*)l, 16, 0, 0);
}

static __device__ __forceinline__ u16 f2bf(float f) {  // RNE f32 -> bf16 bits
  u32 u = __float_as_uint(f);
  u32 r = u + 0x7FFFu + ((u >> 16) & 1u);
  return (u16)(r >> 16);
}

static __device__ __forceinline__ u16x8 cvt8(float4 a, float4 b) {
  u16x8 r;
  r[0] = f2bf(a.x); r[1] = f2bf(a.y); r[2] = f2bf(a.z); r[3] = f2bf(a.w);
  r[4] = f2bf(b.x); r[5] = f2bf(b.y); r[6] = f2bf(b.z); r[7] = f2bf(b.w);
  return r;
}

// ---------------------------------------------------------------------------
// f32 -> bf16 bulk conversion: 7 matrices of kMat elems. Grid (X, 7).
// ---------------------------------------------------------------------------
__global__ __launch_bounds__(256) void cvt_kernel(
    const float* __restrict__ s0, const float* __restrict__ s1,
    const float* __restrict__ s2, const float* __restrict__ s3,
    const float* __restrict__ s4, const float* __restrict__ s5,
    const float* __restrict__ s6, u16* __restrict__ dst) {
  const int y = blockIdx.y;
  const float* s = (y == 0) ? s0 : (y == 1) ? s1 : (y == 2) ? s2 : (y == 3) ? s3
                  : (y == 4) ? s4 : (y == 5) ? s5 : s6;
  u16* d = dst + (size_t)y * kMat;
  const size_t nchunk = kMat / 8;
  const size_t step = (size_t)gridDim.x * 256;
  for (size_t c = (size_t)blockIdx.x * 256 + threadIdx.x; c < nchunk; c += step) {
    const float* p = s + c * 8;
    float4 a = *(const float4*)p;
    float4 b = *(const float4*)(p + 4);
    *(u16x8*)(d + c * 8) = cvt8(a, b);
  }
}

// ---------------------------------------------------------------------------
// Pure-bf16 GEMM: logical Y[m][n] = sum_k X[m][k] * W[n][k], 4096^3.
// m97 structure: 128x128 tile, BK=32, 4 waves, global_load_lds both sides.
// TRANS: store Y transposed (Y[n][m]) by swapping MFMA operands.
// ---------------------------------------------------------------------------
template <bool TRANS, bool OUT_F32>
static __device__ __forceinline__ void gemm_bt_128(const u16* __restrict__ X,
                                                   const u16* __restrict__ W,
                                                   void* __restrict__ Yv) {
  constexpr int KD = 4096;
  __shared__ u16 Als[128 * 32];
  __shared__ u16 Bls[128 * 32];

  const int tid = threadIdx.x;
  const int lane = tid & 63;
  const int w = tid >> 6;
  const int fr = lane & 15;
  const int fq = lane >> 4;
  const int m0 = blockIdx.y * 128;
  const int n0 = blockIdx.x * 128;

  const int sr = lane >> 2;
  const int sc = (lane & 3) * 8;
  const int u0 = w * 2 + 0, u1 = w * 2 + 1;
  const u16* gA0 = X + (size_t)(m0 + u0 * 16 + sr) * KD + sc;
  const u16* gA1 = X + (size_t)(m0 + u1 * 16 + sr) * KD + sc;
  const u16* gB0 = W + (size_t)(n0 + u0 * 16 + sr) * KD + sc;
  const u16* gB1 = W + (size_t)(n0 + u1 * 16 + sr) * KD + sc;
  u16* lA0 = &Als[u0 * 512];
  u16* lA1 = &Als[u1 * 512];
  u16* lB0 = &Bls[u0 * 512];
  u16* lB1 = &Bls[u1 * 512];

  const int wm = (w >> 1) * 64;
  const int wn = (w & 1) * 64;

  f32x4 acc[4][4] = {};  // TRANS ? acc[ni][mi] : acc[mi][ni]

  for (int kt = 0; kt < KD / 32; ++kt) {
    const int ko = kt * 32;
    gload_lds16(gA0 + ko, lA0);
    gload_lds16(gA1 + ko, lA1);
    gload_lds16(gB0 + ko, lB0);
    gload_lds16(gB1 + ko, lB1);
    __syncthreads();

    bf16x8 af[4], bfv[4];
#pragma unroll
    for (int i = 0; i < 4; ++i)
      af[i] = *(const bf16x8*)&Als[(wm + i * 16 + fr) * 32 + fq * 8];
#pragma unroll
    for (int i = 0; i < 4; ++i)
      bfv[i] = *(const bf16x8*)&Bls[(wn + i * 16 + fr) * 32 + fq * 8];
#pragma unroll
    for (int a = 0; a < 4; ++a)
#pragma unroll
      for (int bb = 0; bb < 4; ++bb) {
        if constexpr (TRANS)
          acc[a][bb] = MFMA_BF16(bfv[a], af[bb], acc[a][bb]);  // D rows = n
        else
          acc[a][bb] = MFMA_BF16(af[a], bfv[bb], acc[a][bb]);  // D rows = m
      }
    __syncthreads();
  }

  // C/D layout: col = lane&15, row = (lane>>4)*4 + i  [m89/m91 verified]
#pragma unroll
  for (int a = 0; a < 4; ++a)
#pragma unroll
    for (int bb = 0; bb < 4; ++bb) {
      const int row = TRANS ? (n0 + wn + a * 16 + fq * 4) : (m0 + wm + a * 16 + fq * 4);
      const int col = TRANS ? (m0 + wm + bb * 16 + fr) : (n0 + wn + bb * 16 + fr);
      if constexpr (OUT_F32) {
        float* yp = (float*)Yv + (size_t)row * kDM + col;
#pragma unroll
        for (int i = 0; i < 4; ++i) yp[(size_t)i * kDM] = acc[a][bb][i];
      } else {
        u16* yp = (u16*)Yv + (size_t)row * kDM + col;
#pragma unroll
        for (int i = 0; i < 4; ++i) yp[(size_t)i * kDM] = f2bf(acc[a][bb][i]);
      }
    }
}

__global__ __launch_bounds__(256) void proj_qkv_bf16_kernel(
    const u16* __restrict__ ws_base, u16* __restrict__ qp, u16* __restrict__ kp,
    u16* __restrict__ vpT) {
  const int z = blockIdx.z;
  const u16* X = ws_base + (size_t)z * kMat;        // qb/kb/vb
  const u16* W = ws_base + (size_t)(3 + z) * kMat;  // Wqb/Wkb/Wvb
  if (z == 0)      gemm_bt_128<false, false>(X, W, qp);
  else if (z == 1) gemm_bt_128<false, false>(X, W, kp);
  else             gemm_bt_128<true, false>(X, W, vpT);  // transposed V
}

__global__ __launch_bounds__(256) void out_proj_bf16_kernel(
    const u16* __restrict__ ctx, const u16* __restrict__ Wob, float* __restrict__ out) {
  gemm_bt_128<false, true>(ctx, Wob, out);
}

// ---------------------------------------------------------------------------
// FALLBACK path (ws too small): in-GEMM convert staging.
// ---------------------------------------------------------------------------
template <bool A_BF16, bool TRANS, bool OUT_F32>
static __device__ __forceinline__ void gemm_conv(const void* Xv, const float* Wf,
                                                 void* Yv) {
  constexpr int KD = 4096;
  __shared__ u16 Als[128 * 32];
  __shared__ u16 Bls[128 * 32];

  const int tid = threadIdx.x;
  const int lane = tid & 63;
  const int w = tid >> 6;
  const int fr = lane & 15;
  const int fq = lane >> 4;
  const int m0 = blockIdx.y * 128;
  const int n0 = blockIdx.x * 128;

  const int r0 = tid >> 2, cc0 = (tid & 3) * 8;
  const int r1 = r0 + 64;
  const int sr = lane >> 2, sc = (lane & 3) * 8;
  const int u0 = w * 2, u1 = w * 2 + 1;

  const u16* Xb = (const u16*)Xv;
  const float* Xf = (const float*)Xv;

  const int wm = (w >> 1) * 64;
  const int wn = (w & 1) * 64;

  f32x4 acc[4][4] = {};

  for (int kt = 0; kt < KD / 32; ++kt) {
    const int ko = kt * 32;
    if constexpr (A_BF16) {
      gload_lds16(Xb + (size_t)(m0 + u0 * 16 + sr) * KD + ko + sc, &Als[u0 * 512]);
      gload_lds16(Xb + (size_t)(m0 + u1 * 16 + sr) * KD + ko + sc, &Als[u1 * 512]);
    } else {
      const float* p0 = Xf + (size_t)(m0 + r0) * KD + ko + cc0;
      const float* p1 = Xf + (size_t)(m0 + r1) * KD + ko + cc0;
      float4 a0 = *(const float4*)(p0);
      float4 a1 = *(const float4*)(p0 + 4);
      float4 a2 = *(const float4*)(p1);
      float4 a3 = *(const float4*)(p1 + 4);
      *(u16x8*)&Als[r0 * 32 + cc0] = cvt8(a0, a1);
      *(u16x8*)&Als[r1 * 32 + cc0] = cvt8(a2, a3);
    }
    {
      const float* p0 = Wf + (size_t)(n0 + r0) * KD + ko + cc0;
      const float* p1 = Wf + (size_t)(n0 + r1) * KD + ko + cc0;
      float4 b0 = *(const float4*)(p0);
      float4 b1 = *(const float4*)(p0 + 4);
      float4 b2 = *(const float4*)(p1);
      float4 b3 = *(const float4*)(p1 + 4);
      *(u16x8*)&Bls[r0 * 32 + cc0] = cvt8(b0, b1);
      *(u16x8*)&Bls[r1 * 32 + cc0] = cvt8(b2, b3);
    }
    __syncthreads();

    bf16x8 af[4], bfv[4];
#pragma unroll
    for (int i = 0; i < 4; ++i)
      af[i] = *(const bf16x8*)&Als[(wm + i * 16 + fr) * 32 + fq * 8];
#pragma unroll
    for (int i = 0; i < 4; ++i)
      bfv[i] = *(const bf16x8*)&Bls[(wn + i * 16 + fr) * 32 + fq * 8];
#pragma unroll
    for (int a = 0; a < 4; ++a)
#pragma unroll
      for (int bb = 0; bb < 4; ++bb) {
        if constexpr (TRANS)
          acc[a][bb] = MFMA_BF16(bfv[a], af[bb], acc[a][bb]);
        else
          acc[a][bb] = MFMA_BF16(af[a], bfv[bb], acc[a][bb]);
      }
    __syncthreads();
  }

#pragma unroll
  for (int a = 0; a < 4; ++a)
#pragma unroll
    for (int bb = 0; bb < 4; ++bb) {
      const int row = TRANS ? (n0 + wn + a * 16 + fq * 4) : (m0 + wm + a * 16 + fq * 4);
      const int col = TRANS ? (m0 + wm + bb * 16 + fr) : (n0 + wn + bb * 16 + fr);
      if constexpr (OUT_F32) {
        float* yp = (float*)Yv + (size_t)row * kDM + col;
#pragma unroll
        for (int i = 0; i < 4; ++i) yp[(size_t)i * kDM] = acc[a][bb][i];
      } else {
        u16* yp = (u16*)Yv + (size_t)row * kDM + col;
#pragma unroll
        for (int i = 0; i < 4; ++i) yp[(size_t)i * kDM] = f2bf(acc[a][bb][i]);
      }
    }
}

__global__ __launch_bounds__(256) void proj_qkv_conv_kernel(
    const float* __restrict__ q, const float* __restrict__ k, const float* __restrict__ v,
    const float* __restrict__ Wq, const float* __restrict__ Wk, const float* __restrict__ Wv,
    u16* __restrict__ qp, u16* __restrict__ kp, u16* __restrict__ vpT) {
  const int z = blockIdx.z;
  if (z == 0)      gemm_conv<false, false, false>(q, Wq, qp);
  else if (z == 1) gemm_conv<false, false, false>(k, Wk, kp);
  else             gemm_conv<false, true, false>(v, Wv, vpT);
}

__global__ __launch_bounds__(256) void out_proj_conv_kernel(const u16* __restrict__ ctx,
                                                            const float* __restrict__ Wo,
                                                            float* __restrict__ out) {
  gemm_conv<true, false, true>(ctx, Wo, out);
}

// ---------------------------------------------------------------------------
// Flash attention. Grid: (S/128, B*H). Block 256 = 4 waves.
// Each wave owns 32 q-rows (2 row-blocks of 16). KB=64 keys per tile.
// K in LDS [key][d], chunk-swizzled via pre-swizzled gload_lds source.
// V read from vpT[d_global][b*2048+s]: staged [d][k] via gload_lds, chunk
// swizzle c ^= d&7; PV B-frag is a direct ds_read_b128.
// ---------------------------------------------------------------------------
__global__ __launch_bounds__(256) void attn_kernel(const u16* __restrict__ qp,
                                                   const u16* __restrict__ kp,
                                                   const u16* __restrict__ vpT,
                                                   u16* __restrict__ ctx) {
  constexpr int KB = 64;
  constexpr int PST = 72;  // P row stride (elems)

  __shared__ u16 Kls[KB * 128];        // 16 KB [key][d] swizzled
  __shared__ u16 Vt[kD * KB];          // 16 KB [d][key] swizzled
  __shared__ u16 Pls[4][2 * 16 * PST]; // per-wave P tiles

  const int tid = threadIdx.x, lane = tid & 63, w = tid >> 6;
  const int fr = lane & 15, fq = lane >> 4;
  const int bh = blockIdx.y;
  const int b = bh >> 5, h = bh & 31;
  const int q0 = blockIdx.x * 128;

  const u16* qbase = qp + ((size_t)b * kS) * kDM + h * kD;
  const u16* kbase = kp + ((size_t)b * kS) * kDM + h * kD;
  const u16* vtbase = vpT + (size_t)(h * kD) * kDM + b * kS;  // row d, stride kDM

  bf16x8 qf[2][4];
#pragma unroll
  for (int rb = 0; rb < 2; ++rb)
#pragma unroll
    for (int kc = 0; kc < 4; ++kc)
      qf[rb][kc] = *(const bf16x8*)(qbase + (size_t)(q0 + w * 32 + rb * 16 + fr) * kDM +
                                    kc * 32 + fq * 8);

  f32x4 oacc[2][8] = {};
  float mrun[2][4], lrun[2][4];
#pragma unroll
  for (int rb = 0; rb < 2; ++rb)
#pragma unroll
    for (int i = 0; i < 4; ++i) {
      mrun[rb][i] = -1e30f;
      lrun[rb][i] = 0.f;
    }

  const int krl = lane >> 4;   // K staging: row within 4-row group
  const int kdp = lane & 15;   // K staging: 16B chunk within 256B row
  const int vdl = lane >> 3;   // V staging: d within 8-row group
  const int vc = lane & 7;     // V staging: 16B chunk within 128B row

  for (int kt = 0; kt < kS / KB; ++kt) {
    const int kr0 = kt * KB;
    // --- stage K [key][d]: linear LDS dest, XOR-swizzled global source ---
#pragma unroll
    for (int t = 0; t < 4; ++t) {
      const int u = w * 4 + t;
      const int r = u * 4 + krl;
      const int dps = kdp ^ (r & 7);
      gload_lds16(kbase + (size_t)(kr0 + r) * kDM + dps * 8, &Kls[u * 512]);
    }
    // --- stage V [d][key] from vpT: linear dest, chunk-swizzled source ---
#pragma unroll
    for (int t = 0; t < 4; ++t) {
      const int u = w * 4 + t;
      const int d = u * 8 + vdl;
      gload_lds16(vtbase + (size_t)d * kDM + kr0 + ((vc ^ (d & 7)) * 8), &Vt[u * 512]);
    }
    __syncthreads();

    // --- QK^T ---
    f32x4 sacc[2][4] = {};
#pragma unroll
    for (int cb = 0; cb < 4; ++cb) {
      const int n = cb * 16 + fr;
      bf16x8 kf[4];
#pragma unroll
      for (int kc = 0; kc < 4; ++kc) {
        const int d0 = kc * 4 + fq;
        kf[kc] = *(const bf16x8*)&Kls[n * 128 + (d0 ^ (n & 7)) * 8];
      }
#pragma unroll
      for (int rb = 0; rb < 2; ++rb)
#pragma unroll
        for (int kc = 0; kc < 4; ++kc)
          sacc[rb][cb] = MFMA_BF16(qf[rb][kc], kf[kc], sacc[rb][cb]);
    }

    // --- online softmax (exp2 domain) ---
#pragma unroll
    for (int rb = 0; rb < 2; ++rb) {
      float s2[4][4];
#pragma unroll
      for (int cb = 0; cb < 4; ++cb)
#pragma unroll
        for (int i = 0; i < 4; ++i) s2[cb][i] = sacc[rb][cb][i] * kScaleLog2e;
      float mt[4];
#pragma unroll
      for (int i = 0; i < 4; ++i)
        mt[i] = fmaxf(fmaxf(s2[0][i], s2[1][i]), fmaxf(s2[2][i], s2[3][i]));
#pragma unroll
      for (int off = 1; off < 16; off <<= 1)
#pragma unroll
        for (int i = 0; i < 4; ++i) mt[i] = fmaxf(mt[i], __shfl_xor(mt[i], off));

      float scl[4], rsum[4];
#pragma unroll
      for (int i = 0; i < 4; ++i) {
        const float mnew = fmaxf(mrun[rb][i], mt[i]);
        scl[i] = exp2f(mrun[rb][i] - mnew);
        mrun[rb][i] = mnew;
        rsum[i] = 0.f;
      }
#pragma unroll
      for (int cb = 0; cb < 4; ++cb)
#pragma unroll
        for (int i = 0; i < 4; ++i) {
          const float p = exp2f(s2[cb][i] - mrun[rb][i]);
          rsum[i] += p;
          Pls[w][rb * (16 * PST) + (fq * 4 + i) * PST + cb * 16 + fr] = f2bf(p);
        }
#pragma unroll
      for (int off = 1; off < 16; off <<= 1)
#pragma unroll
        for (int i = 0; i < 4; ++i) rsum[i] += __shfl_xor(rsum[i], off);
#pragma unroll
      for (int i = 0; i < 4; ++i) lrun[rb][i] = lrun[rb][i] * scl[i] + rsum[i];
#pragma unroll
      for (int db = 0; db < 8; ++db)
#pragma unroll
        for (int i = 0; i < 4; ++i) oacc[rb][db][i] *= scl[i];
    }

    asm volatile("s_waitcnt lgkmcnt(0)" ::: "memory");

    // --- PV: O[q][d] += P[q][k] V[k][d]; B-frag = Vt row d (V^T[d][k]) ---
    bf16x8 pf[2][2];
#pragma unroll
    for (int rb = 0; rb < 2; ++rb)
#pragma unroll
      for (int kb = 0; kb < 2; ++kb)
        pf[rb][kb] = *(const bf16x8*)&Pls[w][rb * (16 * PST) + fr * PST + kb * 32 + fq * 8];
#pragma unroll
    for (int db = 0; db < 8; ++db) {
      const int d = db * 16 + fr;
      bf16x8 vf0 = *(const bf16x8*)&Vt[d * KB + ((fq ^ (d & 7)) << 3)];
      bf16x8 vf1 = *(const bf16x8*)&Vt[d * KB + (((4 + fq) ^ (d & 7)) << 3)];
#pragma unroll
      for (int rb = 0; rb < 2; ++rb) {
        oacc[rb][db] = MFMA_BF16(pf[rb][0], vf0, oacc[rb][db]);
        oacc[rb][db] = MFMA_BF16(pf[rb][1], vf1, oacc[rb][db]);
      }
    }
    __syncthreads();
  }

  u16* cbase = ctx + ((size_t)b * kS) * kDM + h * kD;
#pragma unroll
  for (int rb = 0; rb < 2; ++rb) {
    float inv[4];
#pragma unroll
    for (int i = 0; i < 4; ++i) inv[i] = 1.0f / lrun[rb][i];
#pragma unroll
    for (int db = 0; db < 8; ++db)
#pragma unroll
      for (int i = 0; i < 4; ++i) {
        const int row = q0 + w * 32 + rb * 16 + fq * 4 + i;
        const int col = db * 16 + fr;
        cbase[(size_t)row * kDM + col] = f2bf(oacc[rb][db][i] * inv[i]);
      }
  }
}

// ---------------------------------------------------------------------------
extern "C" void kernel_launch(void* const* d_in, const int* in_sizes, int n_in,
                              void* d_out, int out_size, void* d_ws, size_t ws_size,
                              hipStream_t stream) {
  const float* q = (const float*)d_in[0];
  const float* k = (const float*)d_in[1];
  const float* v = (const float*)d_in[2];
  const float* Wq = (const float*)d_in[3];
  const float* Wk = (const float*)d_in[4];
  const float* Wv = (const float*)d_in[5];
  const float* Wo = (const float*)d_in[6];
  float* out = (float*)d_out;

  const size_t needFast = 11 * kMat * sizeof(u16);  // 7 bf16 inputs + qp/kp/vpT/ctx

  if (ws_size >= needFast) {
    u16* wsb = (u16*)d_ws;            // [0..6]: qb kb vb Wqb Wkb Wvb Wob
    u16* qp = wsb + 7 * kMat;
    u16* kp = wsb + 8 * kMat;
    u16* vpT = wsb + 9 * kMat;
    u16* ctx = wsb + 10 * kMat;

    cvt_kernel<<<dim3(1024, 7), 256, 0, stream>>>(q, k, v, Wq, Wk, Wv, Wo, wsb);
    proj_qkv_bf16_kernel<<<dim3(32, 32, 3), 256, 0, stream>>>(wsb, qp, kp, vpT);
    attn_kernel<<<dim3(16, 64), 256, 0, stream>>>(qp, kp, vpT, ctx);
    out_proj_bf16_kernel<<<dim3(32, 32, 1), 256, 0, stream>>>(ctx, wsb + 6 * kMat, out);
  } else {
    u16* qp = (u16*)d_ws;
    u16* kp = qp + kMat;
    u16* vpT = kp + kMat;
    u16* ctx = vpT + kMat;

    proj_qkv_conv_kernel<<<dim3(32, 32, 3), 256, 0, stream>>>(q, k, v, Wq, Wk, Wv, qp, kp, vpT);
    attn_kernel<<<dim3(16, 64), 256, 0, stream>>>(qp, kp, vpT, ctx);
    out_proj_conv_kernel<<<dim3(32, 32, 1), 256, 0, stream>>>(ctx, Wo, out);
  }
}

// Round 5
// 1154.691 us; speedup vs baseline: 1.5512x; 1.1040x over previous
//
#include <hip/hip_runtime.h>
#include <stdint.h>

// ============================================================================
// MultiHeadAttention: y = softmax((xq Wq^T)(xk Wk^T)^T * scale) (xv Wv^T) Wo^T
// B=2, S=2048, H=32, D=128, DM=4096. I/O float32.
// R5: fix R4 occupancy regression — __shared__ hoisted to kernel scope
// (multi-inlined device fn had duplicated 16KB LDS -> 32KB/block), and the
// projection split into single-instantiation kernels (qk and vT).
// ============================================================================

using u16 = unsigned short;
using u32 = unsigned int;

typedef __attribute__((ext_vector_type(8))) short bf16x8;  // MFMA A/B frag (8 bf16)
typedef __attribute__((ext_vector_type(8))) u16 u16x8;
typedef __attribute__((ext_vector_type(4))) float f32x4;   // MFMA C/D frag

#define MFMA_BF16(A, B, C) __builtin_amdgcn_mfma_f32_16x16x32_bf16((A), (B), (C), 0, 0, 0)

static constexpr int kS = 2048, kDM = 4096, kD = 128;
static constexpr size_t kMat = (size_t)4096 * 4096;
// SCALE * log2(e): softmax computed in exp2 domain
static constexpr float kScaleLog2e = 0.08838834764831845f * 1.44269504088896340736f;

static __device__ __forceinline__ void gload_lds16(const u16* g, u16* l) {
  __builtin_amdgcn_global_load_lds((const __attribute__((address_space(1))) void*)g,
                                   (__attribute__((address_space(3))) void*)l, 16, 0, 0);
}

static __device__ __forceinline__ u16 f2bf(float f) {  // RNE f32 -> bf16 bits
  u32 u = __float_as_uint(f);
  u32 r = u + 0x7FFFu + ((u >> 16) & 1u);
  return (u16)(r >> 16);
}

static __device__ __forceinline__ u16x8 cvt8(float4 a, float4 b) {
  u16x8 r;
  r[0] = f2bf(a.x); r[1] = f2bf(a.y); r[2] = f2bf(a.z); r[3] = f2bf(a.w);
  r[4] = f2bf(b.x); r[5] = f2bf(b.y); r[6] = f2bf(b.z); r[7] = f2bf(b.w);
  return r;
}

// ---------------------------------------------------------------------------
// f32 -> bf16 bulk conversion: 7 matrices of kMat elems. Grid (X, 7).
// ---------------------------------------------------------------------------
__global__ __launch_bounds__(256) void cvt_kernel(
    const float* __restrict__ s0, const float* __restrict__ s1,
    const float* __restrict__ s2, const float* __restrict__ s3,
    const float* __restrict__ s4, const float* __restrict__ s5,
    const float* __restrict__ s6, u16* __restrict__ dst) {
  const int y = blockIdx.y;
  const float* s = (y == 0) ? s0 : (y == 1) ? s1 : (y == 2) ? s2 : (y == 3) ? s3
                  : (y == 4) ? s4 : (y == 5) ? s5 : s6;
  u16* d = dst + (size_t)y * kMat;
  const size_t nchunk = kMat / 8;
  const size_t step = (size_t)gridDim.x * 256;
  for (size_t c = (size_t)blockIdx.x * 256 + threadIdx.x; c < nchunk; c += step) {
    const float* p = s + c * 8;
    float4 a = *(const float4*)p;
    float4 b = *(const float4*)(p + 4);
    *(u16x8*)(d + c * 8) = cvt8(a, b);
  }
}

// ---------------------------------------------------------------------------
// Pure-bf16 GEMM: logical Y[m][n] = sum_k X[m][k] * W[n][k], 4096^3.
// m97 structure: 128x128 tile, BK=32, 4 waves, global_load_lds both sides.
// TRANS: store Y transposed (Y[n][m]) by swapping MFMA operands.
// LDS tiles are passed in (declared ONCE at kernel scope — multi-inlining a
// device-scope __shared__ duplicates the allocation per call site).
// ---------------------------------------------------------------------------
template <bool TRANS, bool OUT_F32>
static __device__ __forceinline__ void gemm_bt_128(const u16* __restrict__ X,
                                                   const u16* __restrict__ W,
                                                   void* __restrict__ Yv,
                                                   u16* __restrict__ Als,
                                                   u16* __restrict__ Bls) {
  constexpr int KD = 4096;
  const int tid = threadIdx.x;
  const int lane = tid & 63;
  const int w = tid >> 6;
  const int fr = lane & 15;
  const int fq = lane >> 4;
  const int m0 = blockIdx.y * 128;
  const int n0 = blockIdx.x * 128;

  const int sr = lane >> 2;
  const int sc = (lane & 3) * 8;
  const int u0 = w * 2 + 0, u1 = w * 2 + 1;
  const u16* gA0 = X + (size_t)(m0 + u0 * 16 + sr) * KD + sc;
  const u16* gA1 = X + (size_t)(m0 + u1 * 16 + sr) * KD + sc;
  const u16* gB0 = W + (size_t)(n0 + u0 * 16 + sr) * KD + sc;
  const u16* gB1 = W + (size_t)(n0 + u1 * 16 + sr) * KD + sc;
  u16* lA0 = &Als[u0 * 512];
  u16* lA1 = &Als[u1 * 512];
  u16* lB0 = &Bls[u0 * 512];
  u16* lB1 = &Bls[u1 * 512];

  const int wm = (w >> 1) * 64;
  const int wn = (w & 1) * 64;

  f32x4 acc[4][4] = {};  // TRANS ? acc[ni][mi] : acc[mi][ni]

  for (int kt = 0; kt < KD / 32; ++kt) {
    const int ko = kt * 32;
    gload_lds16(gA0 + ko, lA0);
    gload_lds16(gA1 + ko, lA1);
    gload_lds16(gB0 + ko, lB0);
    gload_lds16(gB1 + ko, lB1);
    __syncthreads();

    bf16x8 af[4], bfv[4];
#pragma unroll
    for (int i = 0; i < 4; ++i)
      af[i] = *(const bf16x8*)&Als[(wm + i * 16 + fr) * 32 + fq * 8];
#pragma unroll
    for (int i = 0; i < 4; ++i)
      bfv[i] = *(const bf16x8*)&Bls[(wn + i * 16 + fr) * 32 + fq * 8];
#pragma unroll
    for (int a = 0; a < 4; ++a)
#pragma unroll
      for (int bb = 0; bb < 4; ++bb) {
        if constexpr (TRANS)
          acc[a][bb] = MFMA_BF16(bfv[a], af[bb], acc[a][bb]);  // D rows = n
        else
          acc[a][bb] = MFMA_BF16(af[a], bfv[bb], acc[a][bb]);  // D rows = m
      }
    __syncthreads();
  }

  // C/D layout: col = lane&15, row = (lane>>4)*4 + i  [m89/m91 verified]
#pragma unroll
  for (int a = 0; a < 4; ++a)
#pragma unroll
    for (int bb = 0; bb < 4; ++bb) {
      const int row = TRANS ? (n0 + wn + a * 16 + fq * 4) : (m0 + wm + a * 16 + fq * 4);
      const int col = TRANS ? (m0 + wm + bb * 16 + fr) : (n0 + wn + bb * 16 + fr);
      if constexpr (OUT_F32) {
        float* yp = (float*)Yv + (size_t)row * kDM + col;
#pragma unroll
        for (int i = 0; i < 4; ++i) yp[(size_t)i * kDM] = acc[a][bb][i];
      } else {
        u16* yp = (u16*)Yv + (size_t)row * kDM + col;
#pragma unroll
        for (int i = 0; i < 4; ++i) yp[(size_t)i * kDM] = f2bf(acc[a][bb][i]);
      }
    }
}

// Q/K projections: z in {0,1}, single template body (R3-proven shape).
__global__ __launch_bounds__(256) void proj_qk_kernel(const u16* __restrict__ wsb,
                                                      u16* __restrict__ qp,
                                                      u16* __restrict__ kp) {
  __shared__ u16 Als[128 * 32];
  __shared__ u16 Bls[128 * 32];
  const int z = blockIdx.z;
  const u16* X = wsb + (size_t)z * kMat;
  const u16* W = wsb + (size_t)(3 + z) * kMat;
  u16* Y = z ? kp : qp;
  gemm_bt_128<false, false>(X, W, Y, Als, Bls);
}

// V projection, transposed output: vpT[h*128+d][b*2048+s].
__global__ __launch_bounds__(256) void proj_vT_kernel(const u16* __restrict__ wsb,
                                                      u16* __restrict__ vpT) {
  __shared__ u16 Als[128 * 32];
  __shared__ u16 Bls[128 * 32];
  gemm_bt_128<true, false>(wsb + 2 * kMat, wsb + 5 * kMat, vpT, Als, Bls);
}

__global__ __launch_bounds__(256) void out_proj_bf16_kernel(
    const u16* __restrict__ ctx, const u16* __restrict__ Wob, float* __restrict__ out) {
  __shared__ u16 Als[128 * 32];
  __shared__ u16 Bls[128 * 32];
  gemm_bt_128<false, true>(ctx, Wob, out, Als, Bls);
}

// ---------------------------------------------------------------------------
// FALLBACK path (ws too small): in-GEMM convert staging.
// ---------------------------------------------------------------------------
template <bool A_BF16, bool TRANS, bool OUT_F32>
static __device__ __forceinline__ void gemm_conv(const void* Xv, const float* Wf,
                                                 void* Yv, u16* __restrict__ Als,
                                                 u16* __restrict__ Bls) {
  constexpr int KD = 4096;
  const int tid = threadIdx.x;
  const int lane = tid & 63;
  const int w = tid >> 6;
  const int fr = lane & 15;
  const int fq = lane >> 4;
  const int m0 = blockIdx.y * 128;
  const int n0 = blockIdx.x * 128;

  const int r0 = tid >> 2, cc0 = (tid & 3) * 8;
  const int r1 = r0 + 64;
  const int sr = lane >> 2, sc = (lane & 3) * 8;
  const int u0 = w * 2, u1 = w * 2 + 1;

  const u16* Xb = (const u16*)Xv;
  const float* Xf = (const float*)Xv;

  const int wm = (w >> 1) * 64;
  const int wn = (w & 1) * 64;

  f32x4 acc[4][4] = {};

  for (int kt = 0; kt < KD / 32; ++kt) {
    const int ko = kt * 32;
    if constexpr (A_BF16) {
      gload_lds16(Xb + (size_t)(m0 + u0 * 16 + sr) * KD + ko + sc, &Als[u0 * 512]);
      gload_lds16(Xb + (size_t)(m0 + u1 * 16 + sr) * KD + ko + sc, &Als[u1 * 512]);
    } else {
      const float* p0 = Xf + (size_t)(m0 + r0) * KD + ko + cc0;
      const float* p1 = Xf + (size_t)(m0 + r1) * KD + ko + cc0;
      float4 a0 = *(const float4*)(p0);
      float4 a1 = *(const float4*)(p0 + 4);
      float4 a2 = *(const float4*)(p1);
      float4 a3 = *(const float4*)(p1 + 4);
      *(u16x8*)&Als[r0 * 32 + cc0] = cvt8(a0, a1);
      *(u16x8*)&Als[r1 * 32 + cc0] = cvt8(a2, a3);
    }
    {
      const float* p0 = Wf + (size_t)(n0 + r0) * KD + ko + cc0;
      const float* p1 = Wf + (size_t)(n0 + r1) * KD + ko + cc0;
      float4 b0 = *(const float4*)(p0);
      float4 b1 = *(const float4*)(p0 + 4);
      float4 b2 = *(const float4*)(p1);
      float4 b3 = *(const float4*)(p1 + 4);
      *(u16x8*)&Bls[r0 * 32 + cc0] = cvt8(b0, b1);
      *(u16x8*)&Bls[r1 * 32 + cc0] = cvt8(b2, b3);
    }
    __syncthreads();

    bf16x8 af[4], bfv[4];
#pragma unroll
    for (int i = 0; i < 4; ++i)
      af[i] = *(const bf16x8*)&Als[(wm + i * 16 + fr) * 32 + fq * 8];
#pragma unroll
    for (int i = 0; i < 4; ++i)
      bfv[i] = *(const bf16x8*)&Bls[(wn + i * 16 + fr) * 32 + fq * 8];
#pragma unroll
    for (int a = 0; a < 4; ++a)
#pragma unroll
      for (int bb = 0; bb < 4; ++bb) {
        if constexpr (TRANS)
          acc[a][bb] = MFMA_BF16(bfv[a], af[bb], acc[a][bb]);
        else
          acc[a][bb] = MFMA_BF16(af[a], bfv[bb], acc[a][bb]);
      }
    __syncthreads();
  }

#pragma unroll
  for (int a = 0; a < 4; ++a)
#pragma unroll
    for (int bb = 0; bb < 4; ++bb) {
      const int row = TRANS ? (n0 + wn + a * 16 + fq * 4) : (m0 + wm + a * 16 + fq * 4);
      const int col = TRANS ? (m0 + wm + bb * 16 + fr) : (n0 + wn + bb * 16 + fr);
      if constexpr (OUT_F32) {
        float* yp = (float*)Yv + (size_t)row * kDM + col;
#pragma unroll
        for (int i = 0; i < 4; ++i) yp[(size_t)i * kDM] = acc[a][bb][i];
      } else {
        u16* yp = (u16*)Yv + (size_t)row * kDM + col;
#pragma unroll
        for (int i = 0; i < 4; ++i) yp[(size_t)i * kDM] = f2bf(acc[a][bb][i]);
      }
    }
}

__global__ __launch_bounds__(256) void proj_qk_conv_kernel(
    const float* __restrict__ q, const float* __restrict__ k,
    const float* __restrict__ Wq, const float* __restrict__ Wk,
    u16* __restrict__ qp, u16* __restrict__ kp) {
  __shared__ u16 Als[128 * 32];
  __shared__ u16 Bls[128 * 32];
  const int z = blockIdx.z;
  gemm_conv<false, false, false>(z ? k : q, z ? Wk : Wq, z ? kp : qp, Als, Bls);
}

__global__ __launch_bounds__(256) void proj_vT_conv_kernel(
    const float* __restrict__ v, const float* __restrict__ Wv, u16* __restrict__ vpT) {
  __shared__ u16 Als[128 * 32];
  __shared__ u16 Bls[128 * 32];
  gemm_conv<false, true, false>(v, Wv, vpT, Als, Bls);
}

__global__ __launch_bounds__(256) void out_proj_conv_kernel(const u16* __restrict__ ctx,
                                                            const float* __restrict__ Wo,
                                                            float* __restrict__ out) {
  __shared__ u16 Als[128 * 32];
  __shared__ u16 Bls[128 * 32];
  gemm_conv<true, false, true>(ctx, Wo, out, Als, Bls);
}

// ---------------------------------------------------------------------------
// Flash attention. Grid: (S/128, B*H). Block 256 = 4 waves.
// Each wave owns 32 q-rows (2 row-blocks of 16). KB=64 keys per tile.
// K in LDS [key][d], chunk-swizzled via pre-swizzled gload_lds source.
// V read from vpT[d_global][b*2048+s]: staged [d][k] via gload_lds, chunk
// swizzle c ^= d&7; PV B-frag is a direct ds_read_b128.
// ---------------------------------------------------------------------------
__global__ __launch_bounds__(256) void attn_kernel(const u16* __restrict__ qp,
                                                   const u16* __restrict__ kp,
                                                   const u16* __restrict__ vpT,
                                                   u16* __restrict__ ctx) {
  constexpr int KB = 64;
  constexpr int PST = 72;  // P row stride (elems)

  __shared__ u16 Kls[KB * 128];        // 16 KB [key][d] swizzled
  __shared__ u16 Vt[kD * KB];          // 16 KB [d][key] swizzled
  __shared__ u16 Pls[4][2 * 16 * PST]; // per-wave P tiles

  const int tid = threadIdx.x, lane = tid & 63, w = tid >> 6;
  const int fr = lane & 15, fq = lane >> 4;
  const int bh = blockIdx.y;
  const int b = bh >> 5, h = bh & 31;
  const int q0 = blockIdx.x * 128;

  const u16* qbase = qp + ((size_t)b * kS) * kDM + h * kD;
  const u16* kbase = kp + ((size_t)b * kS) * kDM + h * kD;
  const u16* vtbase = vpT + (size_t)(h * kD) * kDM + b * kS;  // row d, stride kDM

  bf16x8 qf[2][4];
#pragma unroll
  for (int rb = 0; rb < 2; ++rb)
#pragma unroll
    for (int kc = 0; kc < 4; ++kc)
      qf[rb][kc] = *(const bf16x8*)(qbase + (size_t)(q0 + w * 32 + rb * 16 + fr) * kDM +
                                    kc * 32 + fq * 8);

  f32x4 oacc[2][8] = {};
  float mrun[2][4], lrun[2][4];
#pragma unroll
  for (int rb = 0; rb < 2; ++rb)
#pragma unroll
    for (int i = 0; i < 4; ++i) {
      mrun[rb][i] = -1e30f;
      lrun[rb][i] = 0.f;
    }

  const int krl = lane >> 4;   // K staging: row within 4-row group
  const int kdp = lane & 15;   // K staging: 16B chunk within 256B row
  const int vdl = lane >> 3;   // V staging: d within 8-row group
  const int vc = lane & 7;     // V staging: 16B chunk within 128B row

  for (int kt = 0; kt < kS / KB; ++kt) {
    const int kr0 = kt * KB;
    // --- stage K [key][d]: linear LDS dest, XOR-swizzled global source ---
#pragma unroll
    for (int t = 0; t < 4; ++t) {
      const int u = w * 4 + t;
      const int r = u * 4 + krl;
      const int dps = kdp ^ (r & 7);
      gload_lds16(kbase + (size_t)(kr0 + r) * kDM + dps * 8, &Kls[u * 512]);
    }
    // --- stage V [d][key] from vpT: linear dest, chunk-swizzled source ---
#pragma unroll
    for (int t = 0; t < 4; ++t) {
      const int u = w * 4 + t;
      const int d = u * 8 + vdl;
      gload_lds16(vtbase + (size_t)d * kDM + kr0 + ((vc ^ (d & 7)) * 8), &Vt[u * 512]);
    }
    __syncthreads();

    // --- QK^T ---
    f32x4 sacc[2][4] = {};
#pragma unroll
    for (int cb = 0; cb < 4; ++cb) {
      const int n = cb * 16 + fr;
      bf16x8 kf[4];
#pragma unroll
      for (int kc = 0; kc < 4; ++kc) {
        const int d0 = kc * 4 + fq;
        kf[kc] = *(const bf16x8*)&Kls[n * 128 + (d0 ^ (n & 7)) * 8];
      }
#pragma unroll
      for (int rb = 0; rb < 2; ++rb)
#pragma unroll
        for (int kc = 0; kc < 4; ++kc)
          sacc[rb][cb] = MFMA_BF16(qf[rb][kc], kf[kc], sacc[rb][cb]);
    }

    // --- online softmax (exp2 domain) ---
#pragma unroll
    for (int rb = 0; rb < 2; ++rb) {
      float s2[4][4];
#pragma unroll
      for (int cb = 0; cb < 4; ++cb)
#pragma unroll
        for (int i = 0; i < 4; ++i) s2[cb][i] = sacc[rb][cb][i] * kScaleLog2e;
      float mt[4];
#pragma unroll
      for (int i = 0; i < 4; ++i)
        mt[i] = fmaxf(fmaxf(s2[0][i], s2[1][i]), fmaxf(s2[2][i], s2[3][i]));
#pragma unroll
      for (int off = 1; off < 16; off <<= 1)
#pragma unroll
        for (int i = 0; i < 4; ++i) mt[i] = fmaxf(mt[i], __shfl_xor(mt[i], off));

      float scl[4], rsum[4];
#pragma unroll
      for (int i = 0; i < 4; ++i) {
        const float mnew = fmaxf(mrun[rb][i], mt[i]);
        scl[i] = exp2f(mrun[rb][i] - mnew);
        mrun[rb][i] = mnew;
        rsum[i] = 0.f;
      }
#pragma unroll
      for (int cb = 0; cb < 4; ++cb)
#pragma unroll
        for (int i = 0; i < 4; ++i) {
          const float p = exp2f(s2[cb][i] - mrun[rb][i]);
          rsum[i] += p;
          Pls[w][rb * (16 * PST) + (fq * 4 + i) * PST + cb * 16 + fr] = f2bf(p);
        }
#pragma unroll
      for (int off = 1; off < 16; off <<= 1)
#pragma unroll
        for (int i = 0; i < 4; ++i) rsum[i] += __shfl_xor(rsum[i], off);
#pragma unroll
      for (int i = 0; i < 4; ++i) lrun[rb][i] = lrun[rb][i] * scl[i] + rsum[i];
#pragma unroll
      for (int db = 0; db < 8; ++db)
#pragma unroll
        for (int i = 0; i < 4; ++i) oacc[rb][db][i] *= scl[i];
    }

    asm volatile("s_waitcnt lgkmcnt(0)" ::: "memory");

    // --- PV: O[q][d] += P[q][k] V[k][d]; B-frag = Vt row d (V^T[d][k]) ---
    bf16x8 pf[2][2];
#pragma unroll
    for (int rb = 0; rb < 2; ++rb)
#pragma unroll
      for (int kb = 0; kb < 2; ++kb)
        pf[rb][kb] = *(const bf16x8*)&Pls[w][rb * (16 * PST) + fr * PST + kb * 32 + fq * 8];
#pragma unroll
    for (int db = 0; db < 8; ++db) {
      const int d = db * 16 + fr;
      bf16x8 vf0 = *(const bf16x8*)&Vt[d * KB + ((fq ^ (d & 7)) << 3)];
      bf16x8 vf1 = *(const bf16x8*)&Vt[d * KB + (((4 + fq) ^ (d & 7)) << 3)];
#pragma unroll
      for (int rb = 0; rb < 2; ++rb) {
        oacc[rb][db] = MFMA_BF16(pf[rb][0], vf0, oacc[rb][db]);
        oacc[rb][db] = MFMA_BF16(pf[rb][1], vf1, oacc[rb][db]);
      }
    }
    __syncthreads();
  }

  u16* cbase = ctx + ((size_t)b * kS) * kDM + h * kD;
#pragma unroll
  for (int rb = 0; rb < 2; ++rb) {
    float inv[4];
#pragma unroll
    for (int i = 0; i < 4; ++i) inv[i] = 1.0f / lrun[rb][i];
#pragma unroll
    for (int db = 0; db < 8; ++db)
#pragma unroll
      for (int i = 0; i < 4; ++i) {
        const int row = q0 + w * 32 + rb * 16 + fq * 4 + i;
        const int col = db * 16 + fr;
        cbase[(size_t)row * kDM + col] = f2bf(oacc[rb][db][i] * inv[i]);
      }
  }
}

// ---------------------------------------------------------------------------
extern "C" void kernel_launch(void* const* d_in, const int* in_sizes, int n_in,
                              void* d_out, int out_size, void* d_ws, size_t ws_size,
                              hipStream_t stream) {
  const float* q = (const float*)d_in[0];
  const float* k = (const float*)d_in[1];
  const float* v = (const float*)d_in[2];
  const float* Wq = (const float*)d_in[3];
  const float* Wk = (const float*)d_in[4];
  const float* Wv = (const float*)d_in[5];
  const float* Wo = (const float*)d_in[6];
  float* out = (float*)d_out;

  const size_t needFast = 11 * kMat * sizeof(u16);  // 7 bf16 inputs + qp/kp/vpT/ctx

  if (ws_size >= needFast) {
    u16* wsb = (u16*)d_ws;            // [0..6]: qb kb vb Wqb Wkb Wvb Wob
    u16* qp = wsb + 7 * kMat;
    u16* kp = wsb + 8 * kMat;
    u16* vpT = wsb + 9 * kMat;
    u16* ctx = wsb + 10 * kMat;

    cvt_kernel<<<dim3(1024, 7), 256, 0, stream>>>(q, k, v, Wq, Wk, Wv, Wo, wsb);
    proj_qk_kernel<<<dim3(32, 32, 2), 256, 0, stream>>>(wsb, qp, kp);
    proj_vT_kernel<<<dim3(32, 32), 256, 0, stream>>>(wsb, vpT);
    attn_kernel<<<dim3(16, 64), 256, 0, stream>>>(qp, kp, vpT, ctx);
    out_proj_bf16_kernel<<<dim3(32, 32, 1), 256, 0, stream>>>(ctx, wsb + 6 * kMat, out);
  } else {
    u16* qp = (u16*)d_ws;
    u16* kp = qp + kMat;
    u16* vpT = kp + kMat;
    u16* ctx = vpT + kMat;

    proj_qk_conv_kernel<<<dim3(32, 32, 2), 256, 0, stream>>>(q, k, Wq, Wk, qp, kp);
    proj_vT_conv_kernel<<<dim3(32, 32), 256, 0, stream>>>(v, Wv, vpT);
    attn_kernel<<<dim3(16, 64), 256, 0, stream>>>(qp, kp, vpT, ctx);
    out_proj_conv_kernel<<<dim3(32, 32, 1), 256, 0, stream>>>(ctx, Wo, out);
  }
}

// Round 6
// 878.198 us; speedup vs baseline: 2.0395x; 1.3148x over previous
//
#include <hip/hip_runtime.h>
#include <stdint.h>

// ============================================================================
// MultiHeadAttention: y = softmax((xq Wq^T)(xk Wk^T)^T * scale) (xv Wv^T) Wo^T
// B=2, S=2048, H=32, D=128, DM=4096. I/O float32.
// R6: GEMMs ported to the 256x256 8-phase template (T2 swizzle + T3/T4 counted
// vmcnt + T5 setprio). BK=64, 8 waves, 128KB LDS double-buffer, staging
// staggered 3 quarters ahead, vmcnt(6) once per K-tile. Attn unchanged.
// ============================================================================

using u16 = unsigned short;
using u32 = unsigned int;

typedef __attribute__((ext_vector_type(8))) short bf16x8;  // MFMA A/B frag (8 bf16)
typedef __attribute__((ext_vector_type(8))) u16 u16x8;
typedef __attribute__((ext_vector_type(4))) float f32x4;   // MFMA C/D frag

#define MFMA_BF16(A, B, C) __builtin_amdgcn_mfma_f32_16x16x32_bf16((A), (B), (C), 0, 0, 0)

static constexpr int kS = 2048, kDM = 4096, kD = 128;
static constexpr size_t kMat = (size_t)4096 * 4096;
// SCALE * log2(e): softmax computed in exp2 domain
static constexpr float kScaleLog2e = 0.08838834764831845f * 1.44269504088896340736f;

static __device__ __forceinline__ void gload_lds16(const u16* g, u16* l) {
  __builtin_amdgcn_global_load_lds((const __attribute__((address_space(1))) void*)g,
                                   (__attribute__((address_space(3))) void*)l, 16, 0, 0);
}

static __device__ __forceinline__ u16 f2bf(float f) {  // RNE f32 -> bf16 bits
  u32 u = __float_as_uint(f);
  u32 r = u + 0x7FFFu + ((u >> 16) & 1u);
  return (u16)(r >> 16);
}

static __device__ __forceinline__ u16x8 cvt8(float4 a, float4 b) {
  u16x8 r;
  r[0] = f2bf(a.x); r[1] = f2bf(a.y); r[2] = f2bf(a.z); r[3] = f2bf(a.w);
  r[4] = f2bf(b.x); r[5] = f2bf(b.y); r[6] = f2bf(b.z); r[7] = f2bf(b.w);
  return r;
}

// ---------------------------------------------------------------------------
// f32 -> bf16 bulk conversion: 7 matrices of kMat elems. Grid (X, 7).
// ---------------------------------------------------------------------------
__global__ __launch_bounds__(256) void cvt_kernel(
    const float* __restrict__ s0, const float* __restrict__ s1,
    const float* __restrict__ s2, const float* __restrict__ s3,
    const float* __restrict__ s4, const float* __restrict__ s5,
    const float* __restrict__ s6, u16* __restrict__ dst) {
  const int y = blockIdx.y;
  const float* s = (y == 0) ? s0 : (y == 1) ? s1 : (y == 2) ? s2 : (y == 3) ? s3
                  : (y == 4) ? s4 : (y == 5) ? s5 : s6;
  u16* d = dst + (size_t)y * kMat;
  const size_t nchunk = kMat / 8;
  const size_t step = (size_t)gridDim.x * 256;
  for (size_t c = (size_t)blockIdx.x * 256 + threadIdx.x; c < nchunk; c += step) {
    const float* p = s + c * 8;
    float4 a = *(const float4*)p;
    float4 b = *(const float4*)(p + 4);
    *(u16x8*)(d + c * 8) = cvt8(a, b);
  }
}

// ---------------------------------------------------------------------------
// 256x256 8-phase GEMM (T2+T3+T4+T5): Y[m][n] = sum_k X[m][k] * W[n][k].
// 512 threads = 8 waves (2M x 4N); per-wave 128x64 out; BK=64; NT=64 K-tiles.
// LDS per dbuf: B[256][64] @ 0, A[256][64] @ 16384 elems; dbuf stride 32768.
// Chunk swizzle: logical 16B-chunk c of row r lives at slot c ^ (r&7)
// (applied to stage SOURCE and ds_read — both-sides involution, G21).
// Staging stagger: phase0(t) -> QA1(t+1); phases1-3(t) -> QB0,QB1,QA0(t+2).
// Safety: every staged region is read-dead behind a barrier (B+Ag0/g1 read
// ph0, g2 ph1, g3 ph2 + lgkmcnt(0) drain); vmcnt(6) once per K-tile.
// ---------------------------------------------------------------------------
template <bool TRANS, bool OUT_F32>
static __device__ __forceinline__ void gemm256(const u16* __restrict__ X,
                                               const u16* __restrict__ W,
                                               void* __restrict__ Yv,
                                               u16* __restrict__ lds) {
  constexpr int NT = kDM / 64;
  const int tid = threadIdx.x;
  const int lane = tid & 63;
  const int w = tid >> 6;
  const int fr = lane & 15;
  const int fq = lane >> 4;
  const int wr = w >> 2;  // 0..1  (M half)
  const int wc = w & 3;   // 0..3  (N quarter)
  const int m0 = blockIdx.y * 256;
  const int n0 = blockIdx.x * 256;

  // staging thread mapping: row = tid>>3 (64 rows/instr), slot = tid&7;
  // source chunk pre-swizzled so linear LDS dest ends up swizzled.
  const int srow = tid >> 3;
  const int scol = ((tid & 7) ^ (srow & 7)) * 8;
  const u16* Xrow = X + (size_t)(m0 + srow) * kDM + scol;
  const u16* Wrow = W + (size_t)(n0 + srow) * kDM + scol;
  const int w512 = w * 512;

  const int rBb = wc * 64 + fr;   // B region row base (+ nf*16)
  const int rAb = wr * 128 + fr;  // A region row base (+ mi*16)
  const int swz = fr & 7;         // row&7 == fr&7 (16-aligned frag rows)

  f32x4 acc[8][4] = {};

#define STAGE2(ROWP, qrow, k0, ldq)                                       \
  do {                                                                    \
    gload_lds16((ROWP) + (size_t)(qrow) * kDM + (k0), &lds[(ldq) + w512]); \
    gload_lds16((ROWP) + (size_t)((qrow) + 64) * kDM + (k0),              \
                &lds[(ldq) + 4096 + w512]);                               \
  } while (0)

  // prologue: K-tile0 (dbuf0) QB0,QB1,QA0,QA1; K-tile1 (dbuf1) QB0,QB1,QA0
  STAGE2(Wrow, 0, 0, 0);
  STAGE2(Wrow, 128, 0, 8192);
  STAGE2(Xrow, 0, 0, 16384);
  STAGE2(Xrow, 128, 0, 24576);
  STAGE2(Wrow, 0, 64, 32768);
  STAGE2(Wrow, 128, 64, 32768 + 8192);
  STAGE2(Xrow, 0, 64, 32768 + 16384);
  asm volatile("s_waitcnt vmcnt(6)" ::: "memory");
  __builtin_amdgcn_s_barrier();

  for (int t = 0; t < NT; ++t) {
    const int d = t & 1;
    const int Boff = d * 32768;
    const int Aoff = Boff + 16384;
    bf16x8 bfr[4][2], af[8][2];

    // ---------------- phase 0: read B(8) + A g0,g1(8); stage QA1(t+1) ------
#pragma unroll
    for (int nf = 0; nf < 4; ++nf)
#pragma unroll
      for (int ks = 0; ks < 2; ++ks)
        bfr[nf][ks] = *(const bf16x8*)&lds[Boff + (rBb + nf * 16) * 64 +
                                           (((ks * 4 + fq) ^ swz) * 8)];
#pragma unroll
    for (int mi = 0; mi < 4; ++mi)
#pragma unroll
      for (int ks = 0; ks < 2; ++ks)
        af[mi][ks] = *(const bf16x8*)&lds[Aoff + (rAb + mi * 16) * 64 +
                                          (((ks * 4 + fq) ^ swz) * 8)];
    if (t + 1 < NT) STAGE2(Xrow, 128, (t + 1) * 64, ((t + 1) & 1) * 32768 + 24576);
    __builtin_amdgcn_s_barrier();
    __builtin_amdgcn_s_setprio(1);
#pragma unroll
    for (int mi = 0; mi < 2; ++mi)
#pragma unroll
      for (int nf = 0; nf < 4; ++nf)
#pragma unroll
        for (int ks = 0; ks < 2; ++ks)
          acc[mi][nf] = TRANS ? MFMA_BF16(bfr[nf][ks], af[mi][ks], acc[mi][nf])
                              : MFMA_BF16(af[mi][ks], bfr[nf][ks], acc[mi][nf]);
    __builtin_amdgcn_s_setprio(0);
    __builtin_amdgcn_s_barrier();

    // ---------------- phase 1: read A g2; stage QB0(t+2) -------------------
#pragma unroll
    for (int mi = 4; mi < 6; ++mi)
#pragma unroll
      for (int ks = 0; ks < 2; ++ks)
        af[mi][ks] = *(const bf16x8*)&lds[Aoff + (rAb + mi * 16) * 64 +
                                          (((ks * 4 + fq) ^ swz) * 8)];
    if (t + 2 < NT) STAGE2(Wrow, 0, (t + 2) * 64, d * 32768 + 0);
    __builtin_amdgcn_s_barrier();
    __builtin_amdgcn_s_setprio(1);
#pragma unroll
    for (int mi = 2; mi < 4; ++mi)
#pragma unroll
      for (int nf = 0; nf < 4; ++nf)
#pragma unroll
        for (int ks = 0; ks < 2; ++ks)
          acc[mi][nf] = TRANS ? MFMA_BF16(bfr[nf][ks], af[mi][ks], acc[mi][nf])
                              : MFMA_BF16(af[mi][ks], bfr[nf][ks], acc[mi][nf]);
    __builtin_amdgcn_s_setprio(0);
    __builtin_amdgcn_s_barrier();

    // ---------------- phase 2: read A g3; stage QB1(t+2); drain lgkm -------
#pragma unroll
    for (int mi = 6; mi < 8; ++mi)
#pragma unroll
      for (int ks = 0; ks < 2; ++ks)
        af[mi][ks] = *(const bf16x8*)&lds[Aoff + (rAb + mi * 16) * 64 +
                                          (((ks * 4 + fq) ^ swz) * 8)];
    if (t + 2 < NT) STAGE2(Wrow, 128, (t + 2) * 64, d * 32768 + 8192);
    __builtin_amdgcn_s_barrier();
    __builtin_amdgcn_s_setprio(1);
#pragma unroll
    for (int mi = 4; mi < 6; ++mi)
#pragma unroll
      for (int nf = 0; nf < 4; ++nf)
#pragma unroll
        for (int ks = 0; ks < 2; ++ks)
          acc[mi][nf] = TRANS ? MFMA_BF16(bfr[nf][ks], af[mi][ks], acc[mi][nf])
                              : MFMA_BF16(af[mi][ks], bfr[nf][ks], acc[mi][nf]);
    __builtin_amdgcn_s_setprio(0);
    asm volatile("s_waitcnt lgkmcnt(0)" ::: "memory");  // A reads all serviced
    __builtin_amdgcn_s_barrier();

    // ---------------- phase 3: stage QA0(t+2); vmcnt(6) --------------------
    if (t + 2 < NT) STAGE2(Xrow, 0, (t + 2) * 64, d * 32768 + 16384);
    __builtin_amdgcn_s_barrier();
    __builtin_amdgcn_s_setprio(1);
#pragma unroll
    for (int mi = 6; mi < 8; ++mi)
#pragma unroll
      for (int nf = 0; nf < 4; ++nf)
#pragma unroll
        for (int ks = 0; ks < 2; ++ks)
          acc[mi][nf] = TRANS ? MFMA_BF16(bfr[nf][ks], af[mi][ks], acc[mi][nf])
                              : MFMA_BF16(af[mi][ks], bfr[nf][ks], acc[mi][nf]);
    __builtin_amdgcn_s_setprio(0);
    if (t + 2 < NT)
      asm volatile("s_waitcnt vmcnt(6)" ::: "memory");
    else
      asm volatile("s_waitcnt vmcnt(0)" ::: "memory");
    __builtin_amdgcn_s_barrier();
  }
#undef STAGE2

  // epilogue: C/D layout col=lane&15, row=(lane>>4)*4+i [m89/m91]
#pragma unroll
  for (int mi = 0; mi < 8; ++mi)
#pragma unroll
    for (int nf = 0; nf < 4; ++nf) {
      int row, col;
      if constexpr (TRANS) {
        row = n0 + wc * 64 + nf * 16 + fq * 4;
        col = m0 + wr * 128 + mi * 16 + fr;
      } else {
        row = m0 + wr * 128 + mi * 16 + fq * 4;
        col = n0 + wc * 64 + nf * 16 + fr;
      }
      if constexpr (OUT_F32) {
        float* yp = (float*)Yv + (size_t)row * kDM + col;
#pragma unroll
        for (int i = 0; i < 4; ++i) yp[(size_t)i * kDM] = acc[mi][nf][i];
      } else {
        u16* yp = (u16*)Yv + (size_t)row * kDM + col;
#pragma unroll
        for (int i = 0; i < 4; ++i) yp[(size_t)i * kDM] = f2bf(acc[mi][nf][i]);
      }
    }
}

__global__ __launch_bounds__(512, 2) void proj_qk256_kernel(const u16* __restrict__ wsb,
                                                            u16* __restrict__ qp,
                                                            u16* __restrict__ kp) {
  __shared__ u16 lds[65536];
  const int z = blockIdx.z;
  gemm256<false, false>(wsb + (size_t)z * kMat, wsb + (size_t)(3 + z) * kMat,
                        z ? kp : qp, lds);
}

__global__ __launch_bounds__(512, 2) void proj_vT256_kernel(const u16* __restrict__ wsb,
                                                            u16* __restrict__ vpT) {
  __shared__ u16 lds[65536];
  gemm256<true, false>(wsb + 2 * kMat, wsb + 5 * kMat, vpT, lds);
}

__global__ __launch_bounds__(512, 2) void out_proj256_kernel(const u16* __restrict__ ctx,
                                                             const u16* __restrict__ Wob,
                                                             float* __restrict__ out) {
  __shared__ u16 lds[65536];
  gemm256<false, true>(ctx, Wob, out, lds);
}

// ---------------------------------------------------------------------------
// FALLBACK path (ws too small): in-GEMM convert staging (R5-verified).
// ---------------------------------------------------------------------------
template <bool A_BF16, bool TRANS, bool OUT_F32>
static __device__ __forceinline__ void gemm_conv(const void* Xv, const float* Wf,
                                                 void* Yv, u16* __restrict__ Als,
                                                 u16* __restrict__ Bls) {
  constexpr int KD = 4096;
  const int tid = threadIdx.x;
  const int lane = tid & 63;
  const int w = tid >> 6;
  const int fr = lane & 15;
  const int fq = lane >> 4;
  const int m0 = blockIdx.y * 128;
  const int n0 = blockIdx.x * 128;

  const int r0 = tid >> 2, cc0 = (tid & 3) * 8;
  const int r1 = r0 + 64;
  const int sr = lane >> 2, sc = (lane & 3) * 8;
  const int u0 = w * 2, u1 = w * 2 + 1;

  const u16* Xb = (const u16*)Xv;
  const float* Xf = (const float*)Xv;

  const int wm = (w >> 1) * 64;
  const int wn = (w & 1) * 64;

  f32x4 acc[4][4] = {};

  for (int kt = 0; kt < KD / 32; ++kt) {
    const int ko = kt * 32;
    if constexpr (A_BF16) {
      gload_lds16(Xb + (size_t)(m0 + u0 * 16 + sr) * KD + ko + sc, &Als[u0 * 512]);
      gload_lds16(Xb + (size_t)(m0 + u1 * 16 + sr) * KD + ko + sc, &Als[u1 * 512]);
    } else {
      const float* p0 = Xf + (size_t)(m0 + r0) * KD + ko + cc0;
      const float* p1 = Xf + (size_t)(m0 + r1) * KD + ko + cc0;
      float4 a0 = *(const float4*)(p0);
      float4 a1 = *(const float4*)(p0 + 4);
      float4 a2 = *(const float4*)(p1);
      float4 a3 = *(const float4*)(p1 + 4);
      *(u16x8*)&Als[r0 * 32 + cc0] = cvt8(a0, a1);
      *(u16x8*)&Als[r1 * 32 + cc0] = cvt8(a2, a3);
    }
    {
      const float* p0 = Wf + (size_t)(n0 + r0) * KD + ko + cc0;
      const float* p1 = Wf + (size_t)(n0 + r1) * KD + ko + cc0;
      float4 b0 = *(const float4*)(p0);
      float4 b1 = *(const float4*)(p0 + 4);
      float4 b2 = *(const float4*)(p1);
      float4 b3 = *(const float4*)(p1 + 4);
      *(u16x8*)&Bls[r0 * 32 + cc0] = cvt8(b0, b1);
      *(u16x8*)&Bls[r1 * 32 + cc0] = cvt8(b2, b3);
    }
    __syncthreads();

    bf16x8 af[4], bfv[4];
#pragma unroll
    for (int i = 0; i < 4; ++i)
      af[i] = *(const bf16x8*)&Als[(wm + i * 16 + fr) * 32 + fq * 8];
#pragma unroll
    for (int i = 0; i < 4; ++i)
      bfv[i] = *(const bf16x8*)&Bls[(wn + i * 16 + fr) * 32 + fq * 8];
#pragma unroll
    for (int a = 0; a < 4; ++a)
#pragma unroll
      for (int bb = 0; bb < 4; ++bb) {
        if constexpr (TRANS)
          acc[a][bb] = MFMA_BF16(bfv[a], af[bb], acc[a][bb]);
        else
          acc[a][bb] = MFMA_BF16(af[a], bfv[bb], acc[a][bb]);
      }
    __syncthreads();
  }

#pragma unroll
  for (int a = 0; a < 4; ++a)
#pragma unroll
    for (int bb = 0; bb < 4; ++bb) {
      const int row = TRANS ? (n0 + wn + a * 16 + fq * 4) : (m0 + wm + a * 16 + fq * 4);
      const int col = TRANS ? (m0 + wm + bb * 16 + fr) : (n0 + wn + bb * 16 + fr);
      if constexpr (OUT_F32) {
        float* yp = (float*)Yv + (size_t)row * kDM + col;
#pragma unroll
        for (int i = 0; i < 4; ++i) yp[(size_t)i * kDM] = acc[a][bb][i];
      } else {
        u16* yp = (u16*)Yv + (size_t)row * kDM + col;
#pragma unroll
        for (int i = 0; i < 4; ++i) yp[(size_t)i * kDM] = f2bf(acc[a][bb][i]);
      }
    }
}

__global__ __launch_bounds__(256) void proj_qk_conv_kernel(
    const float* __restrict__ q, const float* __restrict__ k,
    const float* __restrict__ Wq, const float* __restrict__ Wk,
    u16* __restrict__ qp, u16* __restrict__ kp) {
  __shared__ u16 Als[128 * 32];
  __shared__ u16 Bls[128 * 32];
  const int z = blockIdx.z;
  gemm_conv<false, false, false>(z ? k : q, z ? Wk : Wq, z ? kp : qp, Als, Bls);
}

__global__ __launch_bounds__(256) void proj_vT_conv_kernel(
    const float* __restrict__ v, const float* __restrict__ Wv, u16* __restrict__ vpT) {
  __shared__ u16 Als[128 * 32];
  __shared__ u16 Bls[128 * 32];
  gemm_conv<false, true, false>(v, Wv, vpT, Als, Bls);
}

__global__ __launch_bounds__(256) void out_proj_conv_kernel(const u16* __restrict__ ctx,
                                                            const float* __restrict__ Wo,
                                                            float* __restrict__ out) {
  __shared__ u16 Als[128 * 32];
  __shared__ u16 Bls[128 * 32];
  gemm_conv<true, false, true>(ctx, Wo, out, Als, Bls);
}

// ---------------------------------------------------------------------------
// Flash attention (unchanged from R5). Grid: (S/128, B*H). Block 256 = 4 waves.
// ---------------------------------------------------------------------------
__global__ __launch_bounds__(256) void attn_kernel(const u16* __restrict__ qp,
                                                   const u16* __restrict__ kp,
                                                   const u16* __restrict__ vpT,
                                                   u16* __restrict__ ctx) {
  constexpr int KB = 64;
  constexpr int PST = 72;  // P row stride (elems)

  __shared__ u16 Kls[KB * 128];        // 16 KB [key][d] swizzled
  __shared__ u16 Vt[kD * KB];          // 16 KB [d][key] swizzled
  __shared__ u16 Pls[4][2 * 16 * PST]; // per-wave P tiles

  const int tid = threadIdx.x, lane = tid & 63, w = tid >> 6;
  const int fr = lane & 15, fq = lane >> 4;
  const int bh = blockIdx.y;
  const int b = bh >> 5, h = bh & 31;
  const int q0 = blockIdx.x * 128;

  const u16* qbase = qp + ((size_t)b * kS) * kDM + h * kD;
  const u16* kbase = kp + ((size_t)b * kS) * kDM + h * kD;
  const u16* vtbase = vpT + (size_t)(h * kD) * kDM + b * kS;  // row d, stride kDM

  bf16x8 qf[2][4];
#pragma unroll
  for (int rb = 0; rb < 2; ++rb)
#pragma unroll
    for (int kc = 0; kc < 4; ++kc)
      qf[rb][kc] = *(const bf16x8*)(qbase + (size_t)(q0 + w * 32 + rb * 16 + fr) * kDM +
                                    kc * 32 + fq * 8);

  f32x4 oacc[2][8] = {};
  float mrun[2][4], lrun[2][4];
#pragma unroll
  for (int rb = 0; rb < 2; ++rb)
#pragma unroll
    for (int i = 0; i < 4; ++i) {
      mrun[rb][i] = -1e30f;
      lrun[rb][i] = 0.f;
    }

  const int krl = lane >> 4;
  const int kdp = lane & 15;
  const int vdl = lane >> 3;
  const int vc = lane & 7;

  for (int kt = 0; kt < kS / KB; ++kt) {
    const int kr0 = kt * KB;
#pragma unroll
    for (int t = 0; t < 4; ++t) {
      const int u = w * 4 + t;
      const int r = u * 4 + krl;
      const int dps = kdp ^ (r & 7);
      gload_lds16(kbase + (size_t)(kr0 + r) * kDM + dps * 8, &Kls[u * 512]);
    }
#pragma unroll
    for (int t = 0; t < 4; ++t) {
      const int u = w * 4 + t;
      const int d = u * 8 + vdl;
      gload_lds16(vtbase + (size_t)d * kDM + kr0 + ((vc ^ (d & 7)) * 8), &Vt[u * 512]);
    }
    __syncthreads();

    // --- QK^T ---
    f32x4 sacc[2][4] = {};
#pragma unroll
    for (int cb = 0; cb < 4; ++cb) {
      const int n = cb * 16 + fr;
      bf16x8 kf[4];
#pragma unroll
      for (int kc = 0; kc < 4; ++kc) {
        const int d0 = kc * 4 + fq;
        kf[kc] = *(const bf16x8*)&Kls[n * 128 + (d0 ^ (n & 7)) * 8];
      }
#pragma unroll
      for (int rb = 0; rb < 2; ++rb)
#pragma unroll
        for (int kc = 0; kc < 4; ++kc)
          sacc[rb][cb] = MFMA_BF16(qf[rb][kc], kf[kc], sacc[rb][cb]);
    }

    // --- online softmax (exp2 domain) ---
#pragma unroll
    for (int rb = 0; rb < 2; ++rb) {
      float s2[4][4];
#pragma unroll
      for (int cb = 0; cb < 4; ++cb)
#pragma unroll
        for (int i = 0; i < 4; ++i) s2[cb][i] = sacc[rb][cb][i] * kScaleLog2e;
      float mt[4];
#pragma unroll
      for (int i = 0; i < 4; ++i)
        mt[i] = fmaxf(fmaxf(s2[0][i], s2[1][i]), fmaxf(s2[2][i], s2[3][i]));
#pragma unroll
      for (int off = 1; off < 16; off <<= 1)
#pragma unroll
        for (int i = 0; i < 4; ++i) mt[i] = fmaxf(mt[i], __shfl_xor(mt[i], off));

      float scl[4], rsum[4];
#pragma unroll
      for (int i = 0; i < 4; ++i) {
        const float mnew = fmaxf(mrun[rb][i], mt[i]);
        scl[i] = exp2f(mrun[rb][i] - mnew);
        mrun[rb][i] = mnew;
        rsum[i] = 0.f;
      }
#pragma unroll
      for (int cb = 0; cb < 4; ++cb)
#pragma unroll
        for (int i = 0; i < 4; ++i) {
          const float p = exp2f(s2[cb][i] - mrun[rb][i]);
          rsum[i] += p;
          Pls[w][rb * (16 * PST) + (fq * 4 + i) * PST + cb * 16 + fr] = f2bf(p);
        }
#pragma unroll
      for (int off = 1; off < 16; off <<= 1)
#pragma unroll
        for (int i = 0; i < 4; ++i) rsum[i] += __shfl_xor(rsum[i], off);
#pragma unroll
      for (int i = 0; i < 4; ++i) lrun[rb][i] = lrun[rb][i] * scl[i] + rsum[i];
#pragma unroll
      for (int db = 0; db < 8; ++db)
#pragma unroll
        for (int i = 0; i < 4; ++i) oacc[rb][db][i] *= scl[i];
    }

    asm volatile("s_waitcnt lgkmcnt(0)" ::: "memory");

    // --- PV ---
    bf16x8 pf[2][2];
#pragma unroll
    for (int rb = 0; rb < 2; ++rb)
#pragma unroll
      for (int kb = 0; kb < 2; ++kb)
        pf[rb][kb] = *(const bf16x8*)&Pls[w][rb * (16 * PST) + fr * PST + kb * 32 + fq * 8];
#pragma unroll
    for (int db = 0; db < 8; ++db) {
      const int d = db * 16 + fr;
      bf16x8 vf0 = *(const bf16x8*)&Vt[d * KB + ((fq ^ (d & 7)) << 3)];
      bf16x8 vf1 = *(const bf16x8*)&Vt[d * KB + (((4 + fq) ^ (d & 7)) << 3)];
#pragma unroll
      for (int rb = 0; rb < 2; ++rb) {
        oacc[rb][db] = MFMA_BF16(pf[rb][0], vf0, oacc[rb][db]);
        oacc[rb][db] = MFMA_BF16(pf[rb][1], vf1, oacc[rb][db]);
      }
    }
    __syncthreads();
  }

  u16* cbase = ctx + ((size_t)b * kS) * kDM + h * kD;
#pragma unroll
  for (int rb = 0; rb < 2; ++rb) {
    float inv[4];
#pragma unroll
    for (int i = 0; i < 4; ++i) inv[i] = 1.0f / lrun[rb][i];
#pragma unroll
    for (int db = 0; db < 8; ++db)
#pragma unroll
      for (int i = 0; i < 4; ++i) {
        const int row = q0 + w * 32 + rb * 16 + fq * 4 + i;
        const int col = db * 16 + fr;
        cbase[(size_t)row * kDM + col] = f2bf(oacc[rb][db][i] * inv[i]);
      }
  }
}

// ---------------------------------------------------------------------------
extern "C" void kernel_launch(void* const* d_in, const int* in_sizes, int n_in,
                              void* d_out, int out_size, void* d_ws, size_t ws_size,
                              hipStream_t stream) {
  const float* q = (const float*)d_in[0];
  const float* k = (const float*)d_in[1];
  const float* v = (const float*)d_in[2];
  const float* Wq = (const float*)d_in[3];
  const float* Wk = (const float*)d_in[4];
  const float* Wv = (const float*)d_in[5];
  const float* Wo = (const float*)d_in[6];
  float* out = (float*)d_out;

  const size_t needFast = 11 * kMat * sizeof(u16);  // 7 bf16 inputs + qp/kp/vpT/ctx

  if (ws_size >= needFast) {
    u16* wsb = (u16*)d_ws;            // [0..6]: qb kb vb Wqb Wkb Wvb Wob
    u16* qp = wsb + 7 * kMat;
    u16* kp = wsb + 8 * kMat;
    u16* vpT = wsb + 9 * kMat;
    u16* ctx = wsb + 10 * kMat;

    cvt_kernel<<<dim3(1024, 7), 256, 0, stream>>>(q, k, v, Wq, Wk, Wv, Wo, wsb);
    proj_qk256_kernel<<<dim3(16, 16, 2), 512, 0, stream>>>(wsb, qp, kp);
    proj_vT256_kernel<<<dim3(16, 16), 512, 0, stream>>>(wsb, vpT);
    attn_kernel<<<dim3(16, 64), 256, 0, stream>>>(qp, kp, vpT, ctx);
    out_proj256_kernel<<<dim3(16, 16), 512, 0, stream>>>(ctx, wsb + 6 * kMat, out);
  } else {
    u16* qp = (u16*)d_ws;
    u16* kp = qp + kMat;
    u16* vpT = kp + kMat;
    u16* ctx = vpT + kMat;

    proj_qk_conv_kernel<<<dim3(32, 32, 2), 256, 0, stream>>>(q, k, Wq, Wk, qp, kp);
    proj_vT_conv_kernel<<<dim3(32, 32), 256, 0, stream>>>(v, Wv, vpT);
    attn_kernel<<<dim3(16, 64), 256, 0, stream>>>(qp, kp, vpT, ctx);
    out_proj_conv_kernel<<<dim3(32, 32, 1), 256, 0, stream>>>(ctx, Wo, out);
  }
}

// Round 7
// 830.432 us; speedup vs baseline: 2.1569x; 1.0575x over previous
//
#include <hip/hip_runtime.h>
#include <hip/hip_bf16.h>
#include <stdint.h>

// ============================================================================
// MultiHeadAttention: y = softmax((xq Wq^T)(xk Wk^T)^T * scale) (xv Wv^T) Wo^T
// B=2, S=2048, H=32, D=128, DM=4096. I/O float32.
// R7: attn rework — 8-wave blocks (256 q-rows, grid 512 = 2/CU, no tail),
// Q pre-scaled by SCALE*log2e, defer-max rescale (THR=11.5 log2), native
// bf16 casts in hot path, setprio around MFMA clusters. GEMMs unchanged (R6
// 256x256 8-phase template).
// ============================================================================

using u16 = unsigned short;
using u32 = unsigned int;

typedef __attribute__((ext_vector_type(8))) short bf16x8;  // MFMA A/B frag (8 bf16)
typedef __attribute__((ext_vector_type(8))) u16 u16x8;
typedef __attribute__((ext_vector_type(4))) float f32x4;   // MFMA C/D frag

#define MFMA_BF16(A, B, C) __builtin_amdgcn_mfma_f32_16x16x32_bf16((A), (B), (C), 0, 0, 0)

static constexpr int kS = 2048, kDM = 4096, kD = 128;
static constexpr size_t kMat = (size_t)4096 * 4096;
// SCALE * log2(e): softmax computed in exp2 domain
static constexpr float kScaleLog2e = 0.08838834764831845f * 1.44269504088896340736f;

static __device__ __forceinline__ void gload_lds16(const u16* g, u16* l) {
  __builtin_amdgcn_global_load_lds((const __attribute__((address_space(1))) void*)g,
                                   (__attribute__((address_space(3))) void*)l, 16, 0, 0);
}

static __device__ __forceinline__ u16 f2bf(float f) {  // RNE f32 -> bf16 bits (sw)
  u32 u = __float_as_uint(f);
  u32 r = u + 0x7FFFu + ((u >> 16) & 1u);
  return (u16)(r >> 16);
}

static __device__ __forceinline__ float bf2f(u16 x) {  // exact bf16 -> f32
  return __uint_as_float((u32)x << 16);
}

static __device__ __forceinline__ u16 nbf(float f) {  // native cast (hw cvt)
  union { __hip_bfloat16 h; u16 u; } cv;
  cv.h = __float2bfloat16(f);
  return cv.u;
}

static __device__ __forceinline__ u16x8 cvt8(float4 a, float4 b) {
  u16x8 r;
  r[0] = f2bf(a.x); r[1] = f2bf(a.y); r[2] = f2bf(a.z); r[3] = f2bf(a.w);
  r[4] = f2bf(b.x); r[5] = f2bf(b.y); r[6] = f2bf(b.z); r[7] = f2bf(b.w);
  return r;
}

// ---------------------------------------------------------------------------
// f32 -> bf16 bulk conversion: 7 matrices of kMat elems. Grid (X, 7).
// ---------------------------------------------------------------------------
__global__ __launch_bounds__(256) void cvt_kernel(
    const float* __restrict__ s0, const float* __restrict__ s1,
    const float* __restrict__ s2, const float* __restrict__ s3,
    const float* __restrict__ s4, const float* __restrict__ s5,
    const float* __restrict__ s6, u16* __restrict__ dst) {
  const int y = blockIdx.y;
  const float* s = (y == 0) ? s0 : (y == 1) ? s1 : (y == 2) ? s2 : (y == 3) ? s3
                  : (y == 4) ? s4 : (y == 5) ? s5 : s6;
  u16* d = dst + (size_t)y * kMat;
  const size_t nchunk = kMat / 8;
  const size_t step = (size_t)gridDim.x * 256;
  for (size_t c = (size_t)blockIdx.x * 256 + threadIdx.x; c < nchunk; c += step) {
    const float* p = s + c * 8;
    float4 a = *(const float4*)p;
    float4 b = *(const float4*)(p + 4);
    *(u16x8*)(d + c * 8) = cvt8(a, b);
  }
}

// ---------------------------------------------------------------------------
// 256x256 8-phase GEMM (T2+T3+T4+T5): Y[m][n] = sum_k X[m][k] * W[n][k].
// (unchanged from R6 — verified)
// ---------------------------------------------------------------------------
template <bool TRANS, bool OUT_F32>
static __device__ __forceinline__ void gemm256(const u16* __restrict__ X,
                                               const u16* __restrict__ W,
                                               void* __restrict__ Yv,
                                               u16* __restrict__ lds) {
  constexpr int NT = kDM / 64;
  const int tid = threadIdx.x;
  const int lane = tid & 63;
  const int w = tid >> 6;
  const int fr = lane & 15;
  const int fq = lane >> 4;
  const int wr = w >> 2;  // 0..1  (M half)
  const int wc = w & 3;   // 0..3  (N quarter)
  const int m0 = blockIdx.y * 256;
  const int n0 = blockIdx.x * 256;

  const int srow = tid >> 3;
  const int scol = ((tid & 7) ^ (srow & 7)) * 8;
  const u16* Xrow = X + (size_t)(m0 + srow) * kDM + scol;
  const u16* Wrow = W + (size_t)(n0 + srow) * kDM + scol;
  const int w512 = w * 512;

  const int rBb = wc * 64 + fr;
  const int rAb = wr * 128 + fr;
  const int swz = fr & 7;

  f32x4 acc[8][4] = {};

#define STAGE2(ROWP, qrow, k0, ldq)                                       \
  do {                                                                    \
    gload_lds16((ROWP) + (size_t)(qrow) * kDM + (k0), &lds[(ldq) + w512]); \
    gload_lds16((ROWP) + (size_t)((qrow) + 64) * kDM + (k0),              \
                &lds[(ldq) + 4096 + w512]);                               \
  } while (0)

  STAGE2(Wrow, 0, 0, 0);
  STAGE2(Wrow, 128, 0, 8192);
  STAGE2(Xrow, 0, 0, 16384);
  STAGE2(Xrow, 128, 0, 24576);
  STAGE2(Wrow, 0, 64, 32768);
  STAGE2(Wrow, 128, 64, 32768 + 8192);
  STAGE2(Xrow, 0, 64, 32768 + 16384);
  asm volatile("s_waitcnt vmcnt(6)" ::: "memory");
  __builtin_amdgcn_s_barrier();

  for (int t = 0; t < NT; ++t) {
    const int d = t & 1;
    const int Boff = d * 32768;
    const int Aoff = Boff + 16384;
    bf16x8 bfr[4][2], af[8][2];

    // phase 0
#pragma unroll
    for (int nf = 0; nf < 4; ++nf)
#pragma unroll
      for (int ks = 0; ks < 2; ++ks)
        bfr[nf][ks] = *(const bf16x8*)&lds[Boff + (rBb + nf * 16) * 64 +
                                           (((ks * 4 + fq) ^ swz) * 8)];
#pragma unroll
    for (int mi = 0; mi < 4; ++mi)
#pragma unroll
      for (int ks = 0; ks < 2; ++ks)
        af[mi][ks] = *(const bf16x8*)&lds[Aoff + (rAb + mi * 16) * 64 +
                                          (((ks * 4 + fq) ^ swz) * 8)];
    if (t + 1 < NT) STAGE2(Xrow, 128, (t + 1) * 64, ((t + 1) & 1) * 32768 + 24576);
    __builtin_amdgcn_s_barrier();
    __builtin_amdgcn_s_setprio(1);
#pragma unroll
    for (int mi = 0; mi < 2; ++mi)
#pragma unroll
      for (int nf = 0; nf < 4; ++nf)
#pragma unroll
        for (int ks = 0; ks < 2; ++ks)
          acc[mi][nf] = TRANS ? MFMA_BF16(bfr[nf][ks], af[mi][ks], acc[mi][nf])
                              : MFMA_BF16(af[mi][ks], bfr[nf][ks], acc[mi][nf]);
    __builtin_amdgcn_s_setprio(0);
    __builtin_amdgcn_s_barrier();

    // phase 1
#pragma unroll
    for (int mi = 4; mi < 6; ++mi)
#pragma unroll
      for (int ks = 0; ks < 2; ++ks)
        af[mi][ks] = *(const bf16x8*)&lds[Aoff + (rAb + mi * 16) * 64 +
                                          (((ks * 4 + fq) ^ swz) * 8)];
    if (t + 2 < NT) STAGE2(Wrow, 0, (t + 2) * 64, d * 32768 + 0);
    __builtin_amdgcn_s_barrier();
    __builtin_amdgcn_s_setprio(1);
#pragma unroll
    for (int mi = 2; mi < 4; ++mi)
#pragma unroll
      for (int nf = 0; nf < 4; ++nf)
#pragma unroll
        for (int ks = 0; ks < 2; ++ks)
          acc[mi][nf] = TRANS ? MFMA_BF16(bfr[nf][ks], af[mi][ks], acc[mi][nf])
                              : MFMA_BF16(af[mi][ks], bfr[nf][ks], acc[mi][nf]);
    __builtin_amdgcn_s_setprio(0);
    __builtin_amdgcn_s_barrier();

    // phase 2
#pragma unroll
    for (int mi = 6; mi < 8; ++mi)
#pragma unroll
      for (int ks = 0; ks < 2; ++ks)
        af[mi][ks] = *(const bf16x8*)&lds[Aoff + (rAb + mi * 16) * 64 +
                                          (((ks * 4 + fq) ^ swz) * 8)];
    if (t + 2 < NT) STAGE2(Wrow, 128, (t + 2) * 64, d * 32768 + 8192);
    __builtin_amdgcn_s_barrier();
    __builtin_amdgcn_s_setprio(1);
#pragma unroll
    for (int mi = 4; mi < 6; ++mi)
#pragma unroll
      for (int nf = 0; nf < 4; ++nf)
#pragma unroll
        for (int ks = 0; ks < 2; ++ks)
          acc[mi][nf] = TRANS ? MFMA_BF16(bfr[nf][ks], af[mi][ks], acc[mi][nf])
                              : MFMA_BF16(af[mi][ks], bfr[nf][ks], acc[mi][nf]);
    __builtin_amdgcn_s_setprio(0);
    asm volatile("s_waitcnt lgkmcnt(0)" ::: "memory");
    __builtin_amdgcn_s_barrier();

    // phase 3
    if (t + 2 < NT) STAGE2(Xrow, 0, (t + 2) * 64, d * 32768 + 16384);
    __builtin_amdgcn_s_barrier();
    __builtin_amdgcn_s_setprio(1);
#pragma unroll
    for (int mi = 6; mi < 8; ++mi)
#pragma unroll
      for (int nf = 0; nf < 4; ++nf)
#pragma unroll
        for (int ks = 0; ks < 2; ++ks)
          acc[mi][nf] = TRANS ? MFMA_BF16(bfr[nf][ks], af[mi][ks], acc[mi][nf])
                              : MFMA_BF16(af[mi][ks], bfr[nf][ks], acc[mi][nf]);
    __builtin_amdgcn_s_setprio(0);
    if (t + 2 < NT)
      asm volatile("s_waitcnt vmcnt(6)" ::: "memory");
    else
      asm volatile("s_waitcnt vmcnt(0)" ::: "memory");
    __builtin_amdgcn_s_barrier();
  }
#undef STAGE2

#pragma unroll
  for (int mi = 0; mi < 8; ++mi)
#pragma unroll
    for (int nf = 0; nf < 4; ++nf) {
      int row, col;
      if constexpr (TRANS) {
        row = n0 + wc * 64 + nf * 16 + fq * 4;
        col = m0 + wr * 128 + mi * 16 + fr;
      } else {
        row = m0 + wr * 128 + mi * 16 + fq * 4;
        col = n0 + wc * 64 + nf * 16 + fr;
      }
      if constexpr (OUT_F32) {
        float* yp = (float*)Yv + (size_t)row * kDM + col;
#pragma unroll
        for (int i = 0; i < 4; ++i) yp[(size_t)i * kDM] = acc[mi][nf][i];
      } else {
        u16* yp = (u16*)Yv + (size_t)row * kDM + col;
#pragma unroll
        for (int i = 0; i < 4; ++i) yp[(size_t)i * kDM] = f2bf(acc[mi][nf][i]);
      }
    }
}

__global__ __launch_bounds__(512, 2) void proj_qk256_kernel(const u16* __restrict__ wsb,
                                                            u16* __restrict__ qp,
                                                            u16* __restrict__ kp) {
  __shared__ u16 lds[65536];
  const int z = blockIdx.z;
  gemm256<false, false>(wsb + (size_t)z * kMat, wsb + (size_t)(3 + z) * kMat,
                        z ? kp : qp, lds);
}

__global__ __launch_bounds__(512, 2) void proj_vT256_kernel(const u16* __restrict__ wsb,
                                                            u16* __restrict__ vpT) {
  __shared__ u16 lds[65536];
  gemm256<true, false>(wsb + 2 * kMat, wsb + 5 * kMat, vpT, lds);
}

__global__ __launch_bounds__(512, 2) void out_proj256_kernel(const u16* __restrict__ ctx,
                                                             const u16* __restrict__ Wob,
                                                             float* __restrict__ out) {
  __shared__ u16 lds[65536];
  gemm256<false, true>(ctx, Wob, out, lds);
}

// ---------------------------------------------------------------------------
// FALLBACK path (ws too small): in-GEMM convert staging (R5-verified).
// ---------------------------------------------------------------------------
template <bool A_BF16, bool TRANS, bool OUT_F32>
static __device__ __forceinline__ void gemm_conv(const void* Xv, const float* Wf,
                                                 void* Yv, u16* __restrict__ Als,
                                                 u16* __restrict__ Bls) {
  constexpr int KD = 4096;
  const int tid = threadIdx.x;
  const int lane = tid & 63;
  const int w = tid >> 6;
  const int fr = lane & 15;
  const int fq = lane >> 4;
  const int m0 = blockIdx.y * 128;
  const int n0 = blockIdx.x * 128;

  const int r0 = tid >> 2, cc0 = (tid & 3) * 8;
  const int r1 = r0 + 64;
  const int sr = lane >> 2, sc = (lane & 3) * 8;
  const int u0 = w * 2, u1 = w * 2 + 1;

  const u16* Xb = (const u16*)Xv;
  const float* Xf = (const float*)Xv;

  const int wm = (w >> 1) * 64;
  const int wn = (w & 1) * 64;

  f32x4 acc[4][4] = {};

  for (int kt = 0; kt < KD / 32; ++kt) {
    const int ko = kt * 32;
    if constexpr (A_BF16) {
      gload_lds16(Xb + (size_t)(m0 + u0 * 16 + sr) * KD + ko + sc, &Als[u0 * 512]);
      gload_lds16(Xb + (size_t)(m0 + u1 * 16 + sr) * KD + ko + sc, &Als[u1 * 512]);
    } else {
      const float* p0 = Xf + (size_t)(m0 + r0) * KD + ko + cc0;
      const float* p1 = Xf + (size_t)(m0 + r1) * KD + ko + cc0;
      float4 a0 = *(const float4*)(p0);
      float4 a1 = *(const float4*)(p0 + 4);
      float4 a2 = *(const float4*)(p1);
      float4 a3 = *(const float4*)(p1 + 4);
      *(u16x8*)&Als[r0 * 32 + cc0] = cvt8(a0, a1);
      *(u16x8*)&Als[r1 * 32 + cc0] = cvt8(a2, a3);
    }
    {
      const float* p0 = Wf + (size_t)(n0 + r0) * KD + ko + cc0;
      const float* p1 = Wf + (size_t)(n0 + r1) * KD + ko + cc0;
      float4 b0 = *(const float4*)(p0);
      float4 b1 = *(const float4*)(p0 + 4);
      float4 b2 = *(const float4*)(p1);
      float4 b3 = *(const float4*)(p1 + 4);
      *(u16x8*)&Bls[r0 * 32 + cc0] = cvt8(b0, b1);
      *(u16x8*)&Bls[r1 * 32 + cc0] = cvt8(b2, b3);
    }
    __syncthreads();

    bf16x8 af[4], bfv[4];
#pragma unroll
    for (int i = 0; i < 4; ++i)
      af[i] = *(const bf16x8*)&Als[(wm + i * 16 + fr) * 32 + fq * 8];
#pragma unroll
    for (int i = 0; i < 4; ++i)
      bfv[i] = *(const bf16x8*)&Bls[(wn + i * 16 + fr) * 32 + fq * 8];
#pragma unroll
    for (int a = 0; a < 4; ++a)
#pragma unroll
      for (int bb = 0; bb < 4; ++bb) {
        if constexpr (TRANS)
          acc[a][bb] = MFMA_BF16(bfv[a], af[bb], acc[a][bb]);
        else
          acc[a][bb] = MFMA_BF16(af[a], bfv[bb], acc[a][bb]);
      }
    __syncthreads();
  }

#pragma unroll
  for (int a = 0; a < 4; ++a)
#pragma unroll
    for (int bb = 0; bb < 4; ++bb) {
      const int row = TRANS ? (n0 + wn + a * 16 + fq * 4) : (m0 + wm + a * 16 + fq * 4);
      const int col = TRANS ? (m0 + wm + bb * 16 + fr) : (n0 + wn + bb * 16 + fr);
      if constexpr (OUT_F32) {
        float* yp = (float*)Yv + (size_t)row * kDM + col;
#pragma unroll
        for (int i = 0; i < 4; ++i) yp[(size_t)i * kDM] = acc[a][bb][i];
      } else {
        u16* yp = (u16*)Yv + (size_t)row * kDM + col;
#pragma unroll
        for (int i = 0; i < 4; ++i) yp[(size_t)i * kDM] = f2bf(acc[a][bb][i]);
      }
    }
}

__global__ __launch_bounds__(256) void proj_qk_conv_kernel(
    const float* __restrict__ q, const float* __restrict__ k,
    const float* __restrict__ Wq, const float* __restrict__ Wk,
    u16* __restrict__ qp, u16* __restrict__ kp) {
  __shared__ u16 Als[128 * 32];
  __shared__ u16 Bls[128 * 32];
  const int z = blockIdx.z;
  gemm_conv<false, false, false>(z ? k : q, z ? Wk : Wq, z ? kp : qp, Als, Bls);
}

__global__ __launch_bounds__(256) void proj_vT_conv_kernel(
    const float* __restrict__ v, const float* __restrict__ Wv, u16* __restrict__ vpT) {
  __shared__ u16 Als[128 * 32];
  __shared__ u16 Bls[128 * 32];
  gemm_conv<false, true, false>(v, Wv, vpT, Als, Bls);
}

__global__ __launch_bounds__(256) void out_proj_conv_kernel(const u16* __restrict__ ctx,
                                                            const float* __restrict__ Wo,
                                                            float* __restrict__ out) {
  __shared__ u16 Als[128 * 32];
  __shared__ u16 Bls[128 * 32];
  gemm_conv<true, false, true>(ctx, Wo, out, Als, Bls);
}

// ---------------------------------------------------------------------------
// Flash attention R7: Grid (S/256, B*H), block 512 = 8 waves (zero tail:
// 512 blocks = 2/CU resident). Each wave owns 32 q-rows. KB=64 keys/tile.
// K [key][d] chunk-swizzled; V from vpT staged [d][key] chunk-swizzled.
// Q pre-scaled by SCALE*log2e; defer-max rescale; native bf16 casts; setprio.
// ---------------------------------------------------------------------------
__global__ __launch_bounds__(512) void attn_kernel(const u16* __restrict__ qp,
                                                   const u16* __restrict__ kp,
                                                   const u16* __restrict__ vpT,
                                                   u16* __restrict__ ctx) {
  constexpr int KB = 64;
  constexpr int PST = 72;   // P row stride (elems)
  constexpr float THR = 11.5f;  // defer-max threshold (log2 units ~ e^8)

  __shared__ u16 Kls[KB * 128];        // 16 KB [key][d] swizzled
  __shared__ u16 Vt[kD * KB];          // 16 KB [d][key] swizzled
  __shared__ u16 Pls[8][2 * 16 * PST]; // 36 KB per-wave P tiles

  const int tid = threadIdx.x, lane = tid & 63, w = tid >> 6;  // w: 0..7
  const int fr = lane & 15, fq = lane >> 4;
  const int bh = blockIdx.y;
  const int b = bh >> 5, h = bh & 31;
  const int q0 = blockIdx.x * 256;

  const u16* qbase = qp + ((size_t)b * kS) * kDM + h * kD;
  const u16* kbase = kp + ((size_t)b * kS) * kDM + h * kD;
  const u16* vtbase = vpT + (size_t)(h * kD) * kDM + b * kS;  // row d, stride kDM

  // Q fragments, pre-scaled by SCALE*log2e (folds softmax scale into QK^T)
  bf16x8 qf[2][4];
#pragma unroll
  for (int rb = 0; rb < 2; ++rb)
#pragma unroll
    for (int kc = 0; kc < 4; ++kc) {
      const u16x8 raw = *(const u16x8*)(qbase +
          (size_t)(q0 + w * 32 + rb * 16 + fr) * kDM + kc * 32 + fq * 8);
      bf16x8 s;
#pragma unroll
      for (int j = 0; j < 8; ++j) s[j] = (short)f2bf(bf2f(raw[j]) * kScaleLog2e);
      qf[rb][kc] = s;
    }

  f32x4 oacc[2][8] = {};
  float mrun[2][4], lrun[2][4];
#pragma unroll
  for (int rb = 0; rb < 2; ++rb)
#pragma unroll
    for (int i = 0; i < 4; ++i) {
      mrun[rb][i] = -1e30f;
      lrun[rb][i] = 0.f;
    }

  const int krl = lane >> 4;   // K staging: row within 4-row group
  const int kdp = lane & 15;   // K staging: 16B chunk within 256B row
  const int vdl = lane >> 3;   // V staging: d within 8-row group
  const int vc = lane & 7;     // V staging: 16B chunk within 128B row

  for (int kt = 0; kt < kS / KB; ++kt) {
    const int kr0 = kt * KB;
    // --- stage K: 16 instrs across 8 waves (2/wave) ---
#pragma unroll
    for (int t = 0; t < 2; ++t) {
      const int u = w * 2 + t;          // 0..15
      const int r = u * 4 + krl;        // 0..63
      const int dps = kdp ^ (r & 7);
      gload_lds16(kbase + (size_t)(kr0 + r) * kDM + dps * 8, &Kls[u * 512]);
    }
    // --- stage V: 16 instrs (2/wave) ---
#pragma unroll
    for (int t = 0; t < 2; ++t) {
      const int u = w * 2 + t;
      const int d = u * 8 + vdl;        // 0..127
      gload_lds16(vtbase + (size_t)d * kDM + kr0 + ((vc ^ (d & 7)) * 8), &Vt[u * 512]);
    }
    __syncthreads();

    // --- QK^T ---
    f32x4 sacc[2][4] = {};
#pragma unroll
    for (int cb = 0; cb < 4; ++cb) {
      const int n = cb * 16 + fr;
      bf16x8 kf[4];
#pragma unroll
      for (int kc = 0; kc < 4; ++kc) {
        const int d0 = kc * 4 + fq;
        kf[kc] = *(const bf16x8*)&Kls[n * 128 + (d0 ^ (n & 7)) * 8];
      }
      __builtin_amdgcn_s_setprio(1);
#pragma unroll
      for (int rb = 0; rb < 2; ++rb)
#pragma unroll
        for (int kc = 0; kc < 4; ++kc)
          sacc[rb][cb] = MFMA_BF16(qf[rb][kc], kf[kc], sacc[rb][cb]);
      __builtin_amdgcn_s_setprio(0);
    }

    // --- online softmax (log2 domain; scale already folded into Q) ---
#pragma unroll
    for (int rb = 0; rb < 2; ++rb) {
      float mt[4];
#pragma unroll
      for (int i = 0; i < 4; ++i)
        mt[i] = fmaxf(fmaxf(sacc[rb][0][i], sacc[rb][1][i]),
                      fmaxf(sacc[rb][2][i], sacc[rb][3][i]));
#pragma unroll
      for (int off = 1; off < 16; off <<= 1)
#pragma unroll
        for (int i = 0; i < 4; ++i) mt[i] = fmaxf(mt[i], __shfl_xor(mt[i], off));

      const float grow = fmaxf(fmaxf(mt[0] - mrun[rb][0], mt[1] - mrun[rb][1]),
                               fmaxf(mt[2] - mrun[rb][2], mt[3] - mrun[rb][3]));
      if (__any(grow > THR)) {  // rescale only when max grew too much (T13)
        float scl[4];
#pragma unroll
        for (int i = 0; i < 4; ++i) {
          const float mnew = fmaxf(mrun[rb][i], mt[i]);
          scl[i] = exp2f(mrun[rb][i] - mnew);
          mrun[rb][i] = mnew;
          lrun[rb][i] *= scl[i];
        }
#pragma unroll
        for (int db = 0; db < 8; ++db)
#pragma unroll
          for (int i = 0; i < 4; ++i) oacc[rb][db][i] *= scl[i];
      }

      float rsum[4] = {0.f, 0.f, 0.f, 0.f};
#pragma unroll
      for (int cb = 0; cb < 4; ++cb)
#pragma unroll
        for (int i = 0; i < 4; ++i) {
          const float p = exp2f(sacc[rb][cb][i] - mrun[rb][i]);
          rsum[i] += p;
          Pls[w][rb * (16 * PST) + (fq * 4 + i) * PST + cb * 16 + fr] = nbf(p);
        }
#pragma unroll
      for (int off = 1; off < 16; off <<= 1)
#pragma unroll
        for (int i = 0; i < 4; ++i) rsum[i] += __shfl_xor(rsum[i], off);
#pragma unroll
      for (int i = 0; i < 4; ++i) lrun[rb][i] += rsum[i];
    }

    asm volatile("s_waitcnt lgkmcnt(0)" ::: "memory");

    // --- PV ---
    bf16x8 pf[2][2];
#pragma unroll
    for (int rb = 0; rb < 2; ++rb)
#pragma unroll
      for (int kb = 0; kb < 2; ++kb)
        pf[rb][kb] = *(const bf16x8*)&Pls[w][rb * (16 * PST) + fr * PST + kb * 32 + fq * 8];
#pragma unroll
    for (int db = 0; db < 8; ++db) {
      const int d = db * 16 + fr;
      bf16x8 vf0 = *(const bf16x8*)&Vt[d * KB + ((fq ^ (d & 7)) << 3)];
      bf16x8 vf1 = *(const bf16x8*)&Vt[d * KB + (((4 + fq) ^ (d & 7)) << 3)];
      __builtin_amdgcn_s_setprio(1);
#pragma unroll
      for (int rb = 0; rb < 2; ++rb) {
        oacc[rb][db] = MFMA_BF16(pf[rb][0], vf0, oacc[rb][db]);
        oacc[rb][db] = MFMA_BF16(pf[rb][1], vf1, oacc[rb][db]);
      }
      __builtin_amdgcn_s_setprio(0);
    }
    __syncthreads();
  }

  u16* cbase = ctx + ((size_t)b * kS) * kDM + h * kD;
#pragma unroll
  for (int rb = 0; rb < 2; ++rb) {
    float inv[4];
#pragma unroll
    for (int i = 0; i < 4; ++i) inv[i] = 1.0f / lrun[rb][i];
#pragma unroll
    for (int db = 0; db < 8; ++db)
#pragma unroll
      for (int i = 0; i < 4; ++i) {
        const int row = q0 + w * 32 + rb * 16 + fq * 4 + i;
        const int col = db * 16 + fr;
        cbase[(size_t)row * kDM + col] = nbf(oacc[rb][db][i] * inv[i]);
      }
  }
}

// ---------------------------------------------------------------------------
extern "C" void kernel_launch(void* const* d_in, const int* in_sizes, int n_in,
                              void* d_out, int out_size, void* d_ws, size_t ws_size,
                              hipStream_t stream) {
  const float* q = (const float*)d_in[0];
  const float* k = (const float*)d_in[1];
  const float* v = (const float*)d_in[2];
  const float* Wq = (const float*)d_in[3];
  const float* Wk = (const float*)d_in[4];
  const float* Wv = (const float*)d_in[5];
  const float* Wo = (const float*)d_in[6];
  float* out = (float*)d_out;

  const size_t needFast = 11 * kMat * sizeof(u16);  // 7 bf16 inputs + qp/kp/vpT/ctx

  if (ws_size >= needFast) {
    u16* wsb = (u16*)d_ws;            // [0..6]: qb kb vb Wqb Wkb Wvb Wob
    u16* qp = wsb + 7 * kMat;
    u16* kp = wsb + 8 * kMat;
    u16* vpT = wsb + 9 * kMat;
    u16* ctx = wsb + 10 * kMat;

    cvt_kernel<<<dim3(1024, 7), 256, 0, stream>>>(q, k, v, Wq, Wk, Wv, Wo, wsb);
    proj_qk256_kernel<<<dim3(16, 16, 2), 512, 0, stream>>>(wsb, qp, kp);
    proj_vT256_kernel<<<dim3(16, 16), 512, 0, stream>>>(wsb, vpT);
    attn_kernel<<<dim3(8, 64), 512, 0, stream>>>(qp, kp, vpT, ctx);
    out_proj256_kernel<<<dim3(16, 16), 512, 0, stream>>>(ctx, wsb + 6 * kMat, out);
  } else {
    u16* qp = (u16*)d_ws;
    u16* kp = qp + kMat;
    u16* vpT = kp + kMat;
    u16* ctx = vpT + kMat;

    proj_qk_conv_kernel<<<dim3(32, 32, 2), 256, 0, stream>>>(q, k, Wq, Wk, qp, kp);
    proj_vT_conv_kernel<<<dim3(32, 32), 256, 0, stream>>>(v, Wv, vpT);
    attn_kernel<<<dim3(8, 64), 512, 0, stream>>>(qp, kp, vpT, ctx);
    out_proj_conv_kernel<<<dim3(32, 32, 1), 256, 0, stream>>>(ctx, Wo, out);
  }
}

// Round 8
// 775.415 us; speedup vs baseline: 2.3099x; 1.0710x over previous
//
#include <hip/hip_runtime.h>
#include <hip/hip_bf16.h>
#include <stdint.h>

// ============================================================================
// MultiHeadAttention: y = softmax((xq Wq^T)(xk Wk^T)^T * scale) (xv Wv^T) Wo^T
// B=2, S=2048, H=32, D=128, DM=4096. I/O float32.
// R8: attn — (1) T14 reg-staged async K/V prefetch (load next tile at tile
// top, ds_write after barrier), (2) softmax row-sum via ones-V MFMA (9th acc
// block replaces shuffle-sum + lrun), (3) bijective XCD swizzle so the 8
// q-blocks of a head share one XCD's L2. GEMMs unchanged (R6 template).
// ============================================================================

using u16 = unsigned short;
using u32 = unsigned int;

typedef __attribute__((ext_vector_type(8))) short bf16x8;  // MFMA A/B frag (8 bf16)
typedef __attribute__((ext_vector_type(8))) u16 u16x8;
typedef __attribute__((ext_vector_type(4))) float f32x4;   // MFMA C/D frag

#define MFMA_BF16(A, B, C) __builtin_amdgcn_mfma_f32_16x16x32_bf16((A), (B), (C), 0, 0, 0)

static constexpr int kS = 2048, kDM = 4096, kD = 128;
static constexpr size_t kMat = (size_t)4096 * 4096;
// SCALE * log2(e): softmax computed in exp2 domain
static constexpr float kScaleLog2e = 0.08838834764831845f * 1.44269504088896340736f;

static __device__ __forceinline__ void gload_lds16(const u16* g, u16* l) {
  __builtin_amdgcn_global_load_lds((const __attribute__((address_space(1))) void*)g,
                                   (__attribute__((address_space(3))) void*)l, 16, 0, 0);
}

static __device__ __forceinline__ u16 f2bf(float f) {  // RNE f32 -> bf16 bits (sw)
  u32 u = __float_as_uint(f);
  u32 r = u + 0x7FFFu + ((u >> 16) & 1u);
  return (u16)(r >> 16);
}

static __device__ __forceinline__ float bf2f(u16 x) {  // exact bf16 -> f32
  return __uint_as_float((u32)x << 16);
}

static __device__ __forceinline__ u16 nbf(float f) {  // native cast (hw cvt)
  union { __hip_bfloat16 h; u16 u; } cv;
  cv.h = __float2bfloat16(f);
  return cv.u;
}

static __device__ __forceinline__ u16x8 cvt8(float4 a, float4 b) {
  u16x8 r;
  r[0] = f2bf(a.x); r[1] = f2bf(a.y); r[2] = f2bf(a.z); r[3] = f2bf(a.w);
  r[4] = f2bf(b.x); r[5] = f2bf(b.y); r[6] = f2bf(b.z); r[7] = f2bf(b.w);
  return r;
}

// ---------------------------------------------------------------------------
// f32 -> bf16 bulk conversion: 7 matrices of kMat elems. Grid (X, 7).
// ---------------------------------------------------------------------------
__global__ __launch_bounds__(256) void cvt_kernel(
    const float* __restrict__ s0, const float* __restrict__ s1,
    const float* __restrict__ s2, const float* __restrict__ s3,
    const float* __restrict__ s4, const float* __restrict__ s5,
    const float* __restrict__ s6, u16* __restrict__ dst) {
  const int y = blockIdx.y;
  const float* s = (y == 0) ? s0 : (y == 1) ? s1 : (y == 2) ? s2 : (y == 3) ? s3
                  : (y == 4) ? s4 : (y == 5) ? s5 : s6;
  u16* d = dst + (size_t)y * kMat;
  const size_t nchunk = kMat / 8;
  const size_t step = (size_t)gridDim.x * 256;
  for (size_t c = (size_t)blockIdx.x * 256 + threadIdx.x; c < nchunk; c += step) {
    const float* p = s + c * 8;
    float4 a = *(const float4*)p;
    float4 b = *(const float4*)(p + 4);
    *(u16x8*)(d + c * 8) = cvt8(a, b);
  }
}

// ---------------------------------------------------------------------------
// 256x256 8-phase GEMM (T2+T3+T4+T5): Y[m][n] = sum_k X[m][k] * W[n][k].
// (unchanged from R6 — verified)
// ---------------------------------------------------------------------------
template <bool TRANS, bool OUT_F32>
static __device__ __forceinline__ void gemm256(const u16* __restrict__ X,
                                               const u16* __restrict__ W,
                                               void* __restrict__ Yv,
                                               u16* __restrict__ lds) {
  constexpr int NT = kDM / 64;
  const int tid = threadIdx.x;
  const int lane = tid & 63;
  const int w = tid >> 6;
  const int fr = lane & 15;
  const int fq = lane >> 4;
  const int wr = w >> 2;  // 0..1  (M half)
  const int wc = w & 3;   // 0..3  (N quarter)
  const int m0 = blockIdx.y * 256;
  const int n0 = blockIdx.x * 256;

  const int srow = tid >> 3;
  const int scol = ((tid & 7) ^ (srow & 7)) * 8;
  const u16* Xrow = X + (size_t)(m0 + srow) * kDM + scol;
  const u16* Wrow = W + (size_t)(n0 + srow) * kDM + scol;
  const int w512 = w * 512;

  const int rBb = wc * 64 + fr;
  const int rAb = wr * 128 + fr;
  const int swz = fr & 7;

  f32x4 acc[8][4] = {};

#define STAGE2(ROWP, qrow, k0, ldq)                                       \
  do {                                                                    \
    gload_lds16((ROWP) + (size_t)(qrow) * kDM + (k0), &lds[(ldq) + w512]); \
    gload_lds16((ROWP) + (size_t)((qrow) + 64) * kDM + (k0),              \
                &lds[(ldq) + 4096 + w512]);                               \
  } while (0)

  STAGE2(Wrow, 0, 0, 0);
  STAGE2(Wrow, 128, 0, 8192);
  STAGE2(Xrow, 0, 0, 16384);
  STAGE2(Xrow, 128, 0, 24576);
  STAGE2(Wrow, 0, 64, 32768);
  STAGE2(Wrow, 128, 64, 32768 + 8192);
  STAGE2(Xrow, 0, 64, 32768 + 16384);
  asm volatile("s_waitcnt vmcnt(6)" ::: "memory");
  __builtin_amdgcn_s_barrier();

  for (int t = 0; t < NT; ++t) {
    const int d = t & 1;
    const int Boff = d * 32768;
    const int Aoff = Boff + 16384;
    bf16x8 bfr[4][2], af[8][2];

    // phase 0
#pragma unroll
    for (int nf = 0; nf < 4; ++nf)
#pragma unroll
      for (int ks = 0; ks < 2; ++ks)
        bfr[nf][ks] = *(const bf16x8*)&lds[Boff + (rBb + nf * 16) * 64 +
                                           (((ks * 4 + fq) ^ swz) * 8)];
#pragma unroll
    for (int mi = 0; mi < 4; ++mi)
#pragma unroll
      for (int ks = 0; ks < 2; ++ks)
        af[mi][ks] = *(const bf16x8*)&lds[Aoff + (rAb + mi * 16) * 64 +
                                          (((ks * 4 + fq) ^ swz) * 8)];
    if (t + 1 < NT) STAGE2(Xrow, 128, (t + 1) * 64, ((t + 1) & 1) * 32768 + 24576);
    __builtin_amdgcn_s_barrier();
    __builtin_amdgcn_s_setprio(1);
#pragma unroll
    for (int mi = 0; mi < 2; ++mi)
#pragma unroll
      for (int nf = 0; nf < 4; ++nf)
#pragma unroll
        for (int ks = 0; ks < 2; ++ks)
          acc[mi][nf] = TRANS ? MFMA_BF16(bfr[nf][ks], af[mi][ks], acc[mi][nf])
                              : MFMA_BF16(af[mi][ks], bfr[nf][ks], acc[mi][nf]);
    __builtin_amdgcn_s_setprio(0);
    __builtin_amdgcn_s_barrier();

    // phase 1
#pragma unroll
    for (int mi = 4; mi < 6; ++mi)
#pragma unroll
      for (int ks = 0; ks < 2; ++ks)
        af[mi][ks] = *(const bf16x8*)&lds[Aoff + (rAb + mi * 16) * 64 +
                                          (((ks * 4 + fq) ^ swz) * 8)];
    if (t + 2 < NT) STAGE2(Wrow, 0, (t + 2) * 64, d * 32768 + 0);
    __builtin_amdgcn_s_barrier();
    __builtin_amdgcn_s_setprio(1);
#pragma unroll
    for (int mi = 2; mi < 4; ++mi)
#pragma unroll
      for (int nf = 0; nf < 4; ++nf)
#pragma unroll
        for (int ks = 0; ks < 2; ++ks)
          acc[mi][nf] = TRANS ? MFMA_BF16(bfr[nf][ks], af[mi][ks], acc[mi][nf])
                              : MFMA_BF16(af[mi][ks], bfr[nf][ks], acc[mi][nf]);
    __builtin_amdgcn_s_setprio(0);
    __builtin_amdgcn_s_barrier();

    // phase 2
#pragma unroll
    for (int mi = 6; mi < 8; ++mi)
#pragma unroll
      for (int ks = 0; ks < 2; ++ks)
        af[mi][ks] = *(const bf16x8*)&lds[Aoff + (rAb + mi * 16) * 64 +
                                          (((ks * 4 + fq) ^ swz) * 8)];
    if (t + 2 < NT) STAGE2(Wrow, 128, (t + 2) * 64, d * 32768 + 8192);
    __builtin_amdgcn_s_barrier();
    __builtin_amdgcn_s_setprio(1);
#pragma unroll
    for (int mi = 4; mi < 6; ++mi)
#pragma unroll
      for (int nf = 0; nf < 4; ++nf)
#pragma unroll
        for (int ks = 0; ks < 2; ++ks)
          acc[mi][nf] = TRANS ? MFMA_BF16(bfr[nf][ks], af[mi][ks], acc[mi][nf])
                              : MFMA_BF16(af[mi][ks], bfr[nf][ks], acc[mi][nf]);
    __builtin_amdgcn_s_setprio(0);
    asm volatile("s_waitcnt lgkmcnt(0)" ::: "memory");
    __builtin_amdgcn_s_barrier();

    // phase 3
    if (t + 2 < NT) STAGE2(Xrow, 0, (t + 2) * 64, d * 32768 + 16384);
    __builtin_amdgcn_s_barrier();
    __builtin_amdgcn_s_setprio(1);
#pragma unroll
    for (int mi = 6; mi < 8; ++mi)
#pragma unroll
      for (int nf = 0; nf < 4; ++nf)
#pragma unroll
        for (int ks = 0; ks < 2; ++ks)
          acc[mi][nf] = TRANS ? MFMA_BF16(bfr[nf][ks], af[mi][ks], acc[mi][nf])
                              : MFMA_BF16(af[mi][ks], bfr[nf][ks], acc[mi][nf]);
    __builtin_amdgcn_s_setprio(0);
    if (t + 2 < NT)
      asm volatile("s_waitcnt vmcnt(6)" ::: "memory");
    else
      asm volatile("s_waitcnt vmcnt(0)" ::: "memory");
    __builtin_amdgcn_s_barrier();
  }
#undef STAGE2

#pragma unroll
  for (int mi = 0; mi < 8; ++mi)
#pragma unroll
    for (int nf = 0; nf < 4; ++nf) {
      int row, col;
      if constexpr (TRANS) {
        row = n0 + wc * 64 + nf * 16 + fq * 4;
        col = m0 + wr * 128 + mi * 16 + fr;
      } else {
        row = m0 + wr * 128 + mi * 16 + fq * 4;
        col = n0 + wc * 64 + nf * 16 + fr;
      }
      if constexpr (OUT_F32) {
        float* yp = (float*)Yv + (size_t)row * kDM + col;
#pragma unroll
        for (int i = 0; i < 4; ++i) yp[(size_t)i * kDM] = acc[mi][nf][i];
      } else {
        u16* yp = (u16*)Yv + (size_t)row * kDM + col;
#pragma unroll
        for (int i = 0; i < 4; ++i) yp[(size_t)i * kDM] = f2bf(acc[mi][nf][i]);
      }
    }
}

__global__ __launch_bounds__(512, 2) void proj_qk256_kernel(const u16* __restrict__ wsb,
                                                            u16* __restrict__ qp,
                                                            u16* __restrict__ kp) {
  __shared__ u16 lds[65536];
  const int z = blockIdx.z;
  gemm256<false, false>(wsb + (size_t)z * kMat, wsb + (size_t)(3 + z) * kMat,
                        z ? kp : qp, lds);
}

__global__ __launch_bounds__(512, 2) void proj_vT256_kernel(const u16* __restrict__ wsb,
                                                            u16* __restrict__ vpT) {
  __shared__ u16 lds[65536];
  gemm256<true, false>(wsb + 2 * kMat, wsb + 5 * kMat, vpT, lds);
}

__global__ __launch_bounds__(512, 2) void out_proj256_kernel(const u16* __restrict__ ctx,
                                                             const u16* __restrict__ Wob,
                                                             float* __restrict__ out) {
  __shared__ u16 lds[65536];
  gemm256<false, true>(ctx, Wob, out, lds);
}

// ---------------------------------------------------------------------------
// FALLBACK path (ws too small): in-GEMM convert staging (R5-verified).
// ---------------------------------------------------------------------------
template <bool A_BF16, bool TRANS, bool OUT_F32>
static __device__ __forceinline__ void gemm_conv(const void* Xv, const float* Wf,
                                                 void* Yv, u16* __restrict__ Als,
                                                 u16* __restrict__ Bls) {
  constexpr int KD = 4096;
  const int tid = threadIdx.x;
  const int lane = tid & 63;
  const int w = tid >> 6;
  const int fr = lane & 15;
  const int fq = lane >> 4;
  const int m0 = blockIdx.y * 128;
  const int n0 = blockIdx.x * 128;

  const int r0 = tid >> 2, cc0 = (tid & 3) * 8;
  const int r1 = r0 + 64;
  const int sr = lane >> 2, sc = (lane & 3) * 8;
  const int u0 = w * 2, u1 = w * 2 + 1;

  const u16* Xb = (const u16*)Xv;
  const float* Xf = (const float*)Xv;

  const int wm = (w >> 1) * 64;
  const int wn = (w & 1) * 64;

  f32x4 acc[4][4] = {};

  for (int kt = 0; kt < KD / 32; ++kt) {
    const int ko = kt * 32;
    if constexpr (A_BF16) {
      gload_lds16(Xb + (size_t)(m0 + u0 * 16 + sr) * KD + ko + sc, &Als[u0 * 512]);
      gload_lds16(Xb + (size_t)(m0 + u1 * 16 + sr) * KD + ko + sc, &Als[u1 * 512]);
    } else {
      const float* p0 = Xf + (size_t)(m0 + r0) * KD + ko + cc0;
      const float* p1 = Xf + (size_t)(m0 + r1) * KD + ko + cc0;
      float4 a0 = *(const float4*)(p0);
      float4 a1 = *(const float4*)(p0 + 4);
      float4 a2 = *(const float4*)(p1);
      float4 a3 = *(const float4*)(p1 + 4);
      *(u16x8*)&Als[r0 * 32 + cc0] = cvt8(a0, a1);
      *(u16x8*)&Als[r1 * 32 + cc0] = cvt8(a2, a3);
    }
    {
      const float* p0 = Wf + (size_t)(n0 + r0) * KD + ko + cc0;
      const float* p1 = Wf + (size_t)(n0 + r1) * KD + ko + cc0;
      float4 b0 = *(const float4*)(p0);
      float4 b1 = *(const float4*)(p0 + 4);
      float4 b2 = *(const float4*)(p1);
      float4 b3 = *(const float4*)(p1 + 4);
      *(u16x8*)&Bls[r0 * 32 + cc0] = cvt8(b0, b1);
      *(u16x8*)&Bls[r1 * 32 + cc0] = cvt8(b2, b3);
    }
    __syncthreads();

    bf16x8 af[4], bfv[4];
#pragma unroll
    for (int i = 0; i < 4; ++i)
      af[i] = *(const bf16x8*)&Als[(wm + i * 16 + fr) * 32 + fq * 8];
#pragma unroll
    for (int i = 0; i < 4; ++i)
      bfv[i] = *(const bf16x8*)&Bls[(wn + i * 16 + fr) * 32 + fq * 8];
#pragma unroll
    for (int a = 0; a < 4; ++a)
#pragma unroll
      for (int bb = 0; bb < 4; ++bb) {
        if constexpr (TRANS)
          acc[a][bb] = MFMA_BF16(bfv[a], af[bb], acc[a][bb]);
        else
          acc[a][bb] = MFMA_BF16(af[a], bfv[bb], acc[a][bb]);
      }
    __syncthreads();
  }

#pragma unroll
  for (int a = 0; a < 4; ++a)
#pragma unroll
    for (int bb = 0; bb < 4; ++bb) {
      const int row = TRANS ? (n0 + wn + a * 16 + fq * 4) : (m0 + wm + a * 16 + fq * 4);
      const int col = TRANS ? (m0 + wm + bb * 16 + fr) : (n0 + wn + bb * 16 + fr);
      if constexpr (OUT_F32) {
        float* yp = (float*)Yv + (size_t)row * kDM + col;
#pragma unroll
        for (int i = 0; i < 4; ++i) yp[(size_t)i * kDM] = acc[a][bb][i];
      } else {
        u16* yp = (u16*)Yv + (size_t)row * kDM + col;
#pragma unroll
        for (int i = 0; i < 4; ++i) yp[(size_t)i * kDM] = f2bf(acc[a][bb][i]);
      }
    }
}

__global__ __launch_bounds__(256) void proj_qk_conv_kernel(
    const float* __restrict__ q, const float* __restrict__ k,
    const float* __restrict__ Wq, const float* __restrict__ Wk,
    u16* __restrict__ qp, u16* __restrict__ kp) {
  __shared__ u16 Als[128 * 32];
  __shared__ u16 Bls[128 * 32];
  const int z = blockIdx.z;
  gemm_conv<false, false, false>(z ? k : q, z ? Wk : Wq, z ? kp : qp, Als, Bls);
}

__global__ __launch_bounds__(256) void proj_vT_conv_kernel(
    const float* __restrict__ v, const float* __restrict__ Wv, u16* __restrict__ vpT) {
  __shared__ u16 Als[128 * 32];
  __shared__ u16 Bls[128 * 32];
  gemm_conv<false, true, false>(v, Wv, vpT, Als, Bls);
}

__global__ __launch_bounds__(256) void out_proj_conv_kernel(const u16* __restrict__ ctx,
                                                            const float* __restrict__ Wo,
                                                            float* __restrict__ out) {
  __shared__ u16 Als[128 * 32];
  __shared__ u16 Bls[128 * 32];
  gemm_conv<true, false, true>(ctx, Wo, out, Als, Bls);
}

// ---------------------------------------------------------------------------
// Flash attention R8: grid (8,64) block 512 = 8 waves; 256 q-rows/block.
// XCD-swizzled block ids; reg-staged async K/V prefetch; ones-V MFMA row-sum;
// defer-max; Q pre-scaled by SCALE*log2e.
// ---------------------------------------------------------------------------
__global__ __launch_bounds__(512) void attn_kernel(const u16* __restrict__ qp,
                                                   const u16* __restrict__ kp,
                                                   const u16* __restrict__ vpT,
                                                   u16* __restrict__ ctx) {
  constexpr int KB = 64;
  constexpr int NT = kS / KB;   // 32 tiles
  constexpr int PST = 72;       // P row stride (elems)
  constexpr float THR = 11.5f;  // defer-max threshold (log2 units ~ e^8)

  __shared__ u16 Kls[KB * 128];        // 16 KB [key][d] chunk-swizzled
  __shared__ u16 Vt[kD * KB];          // 16 KB [d][key] chunk-swizzled
  __shared__ u16 Pls[8][2 * 16 * PST]; // 36 KB per-wave P tiles

  const int tid = threadIdx.x, lane = tid & 63, w = tid >> 6;  // w: 0..7
  const int fr = lane & 15, fq = lane >> 4;

  // XCD-aware bijective swizzle: 512 wgs, 64 per XCD; hw id round-robins XCDs,
  // remap so each XCD owns 8 consecutive bh (the 8 q-blocks of a head share L2)
  const int wg = blockIdx.y * 8 + blockIdx.x;
  const int o = (wg & 7) * 64 + (wg >> 3);
  const int bh = o >> 3;
  const int b = bh >> 5, h = bh & 31;
  const int q0 = (o & 7) * 256;

  const u16* qbase = qp + ((size_t)b * kS) * kDM + h * kD;
  const u16* kbase = kp + ((size_t)b * kS) * kDM + h * kD;
  const u16* vtbase = vpT + (size_t)(h * kD) * kDM + b * kS;  // row d, stride kDM

  // Q fragments, pre-scaled by SCALE*log2e
  bf16x8 qf[2][4];
#pragma unroll
  for (int rb = 0; rb < 2; ++rb)
#pragma unroll
    for (int kc = 0; kc < 4; ++kc) {
      const u16x8 raw = *(const u16x8*)(qbase +
          (size_t)(q0 + w * 32 + rb * 16 + fr) * kDM + kc * 32 + fq * 8);
      bf16x8 s;
#pragma unroll
      for (int j = 0; j < 8; ++j) s[j] = (short)f2bf(bf2f(raw[j]) * kScaleLog2e);
      qf[rb][kc] = s;
    }

  // acc[rb][0..7] = O blocks; acc[rb][8] = row-sum (ones-V) == softmax denom
  f32x4 oacc[2][9] = {};
  float mrun[2][4];
#pragma unroll
  for (int rb = 0; rb < 2; ++rb)
#pragma unroll
    for (int i = 0; i < 4; ++i) mrun[rb][i] = -1e30f;

  bf16x8 ones;
#pragma unroll
  for (int j = 0; j < 8; ++j) ones[j] = (short)0x3F80;  // bf16 1.0

  // staging geometry (reg-staged): K rows rk0/rk1 (4/wave-inst), chunk kdp;
  // V d-rows dv0/dv1 (8/wave-inst), chunk vc. Linear global read; swizzled
  // ds_write (chunk ^= row&7) matches the QK^T / PV read swizzles.
  const int krl = lane >> 4, kdp = lane & 15;
  const int vdl = lane >> 3, vc = lane & 7;
  const int rk0 = (w * 2 + 0) * 4 + krl;
  const int rk1 = (w * 2 + 1) * 4 + krl;
  const int dv0 = (w * 2 + 0) * 8 + vdl;
  const int dv1 = (w * 2 + 1) * 8 + vdl;
  const u16* kg0 = kbase + (size_t)rk0 * kDM + kdp * 8;
  const u16* kg1 = kbase + (size_t)rk1 * kDM + kdp * 8;
  const u16* vg0 = vtbase + (size_t)dv0 * kDM + vc * 8;
  const u16* vg1 = vtbase + (size_t)dv1 * kDM + vc * 8;
  u16* kl0 = &Kls[rk0 * 128 + ((kdp ^ (rk0 & 7)) * 8)];
  u16* kl1 = &Kls[rk1 * 128 + ((kdp ^ (rk1 & 7)) * 8)];
  u16* vl0 = &Vt[dv0 * KB + ((vc ^ (dv0 & 7)) * 8)];
  u16* vl1 = &Vt[dv1 * KB + ((vc ^ (dv1 & 7)) * 8)];

  u16x8 kr0v, kr1v, vr0v, vr1v;
  // prologue: tile 0 -> regs -> LDS
  kr0v = *(const u16x8*)kg0;
  kr1v = *(const u16x8*)kg1;
  vr0v = *(const u16x8*)vg0;
  vr1v = *(const u16x8*)vg1;
  *(u16x8*)kl0 = kr0v; *(u16x8*)kl1 = kr1v;
  *(u16x8*)vl0 = vr0v; *(u16x8*)vl1 = vr1v;
  __syncthreads();

  for (int kt = 0; kt < NT; ++kt) {
    // issue next-tile loads NOW — latency hides under QK^T/softmax/PV (T14)
    if (kt + 1 < NT) {
      const size_t ko = (size_t)(kt + 1) * KB;
      kr0v = *(const u16x8*)(kg0 + ko * kDM);
      kr1v = *(const u16x8*)(kg1 + ko * kDM);
      vr0v = *(const u16x8*)(vg0 + ko);
      vr1v = *(const u16x8*)(vg1 + ko);
    }

    // --- QK^T ---
    f32x4 sacc[2][4] = {};
#pragma unroll
    for (int cb = 0; cb < 4; ++cb) {
      const int n = cb * 16 + fr;
      bf16x8 kf[4];
#pragma unroll
      for (int kc = 0; kc < 4; ++kc) {
        const int d0 = kc * 4 + fq;
        kf[kc] = *(const bf16x8*)&Kls[n * 128 + (d0 ^ (n & 7)) * 8];
      }
      __builtin_amdgcn_s_setprio(1);
#pragma unroll
      for (int rb = 0; rb < 2; ++rb)
#pragma unroll
        for (int kc = 0; kc < 4; ++kc)
          sacc[rb][cb] = MFMA_BF16(qf[rb][kc], kf[kc], sacc[rb][cb]);
      __builtin_amdgcn_s_setprio(0);
    }

    // --- online softmax (log2 domain; denom accumulated by ones-V MFMA) ---
#pragma unroll
    for (int rb = 0; rb < 2; ++rb) {
      float mt[4];
#pragma unroll
      for (int i = 0; i < 4; ++i)
        mt[i] = fmaxf(fmaxf(sacc[rb][0][i], sacc[rb][1][i]),
                      fmaxf(sacc[rb][2][i], sacc[rb][3][i]));
#pragma unroll
      for (int off = 1; off < 16; off <<= 1)
#pragma unroll
        for (int i = 0; i < 4; ++i) mt[i] = fmaxf(mt[i], __shfl_xor(mt[i], off));

      const float grow = fmaxf(fmaxf(mt[0] - mrun[rb][0], mt[1] - mrun[rb][1]),
                               fmaxf(mt[2] - mrun[rb][2], mt[3] - mrun[rb][3]));
      if (__any(grow > THR)) {  // deferred rescale (T13); also scales denom [8]
        float scl[4];
#pragma unroll
        for (int i = 0; i < 4; ++i) {
          const float mnew = fmaxf(mrun[rb][i], mt[i]);
          scl[i] = exp2f(mrun[rb][i] - mnew);
          mrun[rb][i] = mnew;
        }
#pragma unroll
        for (int db = 0; db < 9; ++db)
#pragma unroll
          for (int i = 0; i < 4; ++i) oacc[rb][db][i] *= scl[i];
      }

#pragma unroll
      for (int cb = 0; cb < 4; ++cb)
#pragma unroll
        for (int i = 0; i < 4; ++i) {
          const float p = exp2f(sacc[rb][cb][i] - mrun[rb][i]);
          Pls[w][rb * (16 * PST) + (fq * 4 + i) * PST + cb * 16 + fr] = nbf(p);
        }
    }

    asm volatile("s_waitcnt lgkmcnt(0)" ::: "memory");

    // --- PV (+ denom via ones-V) ---
    bf16x8 pf[2][2];
#pragma unroll
    for (int rb = 0; rb < 2; ++rb)
#pragma unroll
      for (int kb = 0; kb < 2; ++kb)
        pf[rb][kb] = *(const bf16x8*)&Pls[w][rb * (16 * PST) + fr * PST + kb * 32 + fq * 8];
#pragma unroll
    for (int db = 0; db < 8; ++db) {
      const int d = db * 16 + fr;
      bf16x8 vf0 = *(const bf16x8*)&Vt[d * KB + ((fq ^ (d & 7)) << 3)];
      bf16x8 vf1 = *(const bf16x8*)&Vt[d * KB + (((4 + fq) ^ (d & 7)) << 3)];
      __builtin_amdgcn_s_setprio(1);
#pragma unroll
      for (int rb = 0; rb < 2; ++rb) {
        oacc[rb][db] = MFMA_BF16(pf[rb][0], vf0, oacc[rb][db]);
        oacc[rb][db] = MFMA_BF16(pf[rb][1], vf1, oacc[rb][db]);
      }
      __builtin_amdgcn_s_setprio(0);
    }
    __builtin_amdgcn_s_setprio(1);
#pragma unroll
    for (int rb = 0; rb < 2; ++rb) {
      oacc[rb][8] = MFMA_BF16(pf[rb][0], ones, oacc[rb][8]);
      oacc[rb][8] = MFMA_BF16(pf[rb][1], ones, oacc[rb][8]);
    }
    __builtin_amdgcn_s_setprio(0);

    __syncthreads();  // all waves done reading Kls/Vt of tile kt
    if (kt + 1 < NT) {
      *(u16x8*)kl0 = kr0v; *(u16x8*)kl1 = kr1v;
      *(u16x8*)vl0 = vr0v; *(u16x8*)vl1 = vr1v;
    }
    __syncthreads();  // tile kt+1 staged
  }

  u16* cbase = ctx + ((size_t)b * kS) * kDM + h * kD;
#pragma unroll
  for (int rb = 0; rb < 2; ++rb) {
    float inv[4];
#pragma unroll
    for (int i = 0; i < 4; ++i) inv[i] = 1.0f / oacc[rb][8][i];
#pragma unroll
    for (int db = 0; db < 8; ++db)
#pragma unroll
      for (int i = 0; i < 4; ++i) {
        const int row = q0 + w * 32 + rb * 16 + fq * 4 + i;
        const int col = db * 16 + fr;
        cbase[(size_t)row * kDM + col] = nbf(oacc[rb][db][i] * inv[i]);
      }
  }
}

// ---------------------------------------------------------------------------
extern "C" void kernel_launch(void* const* d_in, const int* in_sizes, int n_in,
                              void* d_out, int out_size, void* d_ws, size_t ws_size,
                              hipStream_t stream) {
  const float* q = (const float*)d_in[0];
  const float* k = (const float*)d_in[1];
  const float* v = (const float*)d_in[2];
  const float* Wq = (const float*)d_in[3];
  const float* Wk = (const float*)d_in[4];
  const float* Wv = (const float*)d_in[5];
  const float* Wo = (const float*)d_in[6];
  float* out = (float*)d_out;

  const size_t needFast = 11 * kMat * sizeof(u16);  // 7 bf16 inputs + qp/kp/vpT/ctx

  if (ws_size >= needFast) {
    u16* wsb = (u16*)d_ws;            // [0..6]: qb kb vb Wqb Wkb Wvb Wob
    u16* qp = wsb + 7 * kMat;
    u16* kp = wsb + 8 * kMat;
    u16* vpT = wsb + 9 * kMat;
    u16* ctx = wsb + 10 * kMat;

    cvt_kernel<<<dim3(1024, 7), 256, 0, stream>>>(q, k, v, Wq, Wk, Wv, Wo, wsb);
    proj_qk256_kernel<<<dim3(16, 16, 2), 512, 0, stream>>>(wsb, qp, kp);
    proj_vT256_kernel<<<dim3(16, 16), 512, 0, stream>>>(wsb, vpT);
    attn_kernel<<<dim3(8, 64), 512, 0, stream>>>(qp, kp, vpT, ctx);
    out_proj256_kernel<<<dim3(16, 16), 512, 0, stream>>>(ctx, wsb + 6 * kMat, out);
  } else {
    u16* qp = (u16*)d_ws;
    u16* kp = qp + kMat;
    u16* vpT = kp + kMat;
    u16* ctx = vpT + kMat;

    proj_qk_conv_kernel<<<dim3(32, 32, 2), 256, 0, stream>>>(q, k, Wq, Wk, qp, kp);
    proj_vT_conv_kernel<<<dim3(32, 32), 256, 0, stream>>>(v, Wv, vpT);
    attn_kernel<<<dim3(8, 64), 512, 0, stream>>>(qp, kp, vpT, ctx);
    out_proj_conv_kernel<<<dim3(32, 32, 1), 256, 0, stream>>>(ctx, Wo, out);
  }
}

// Round 9
// 743.869 us; speedup vs baseline: 2.4079x; 1.0424x over previous
//
#include <hip/hip_runtime.h>
#include <hip/hip_bf16.h>
#include <stdint.h>

// ============================================================================
// MultiHeadAttention: y = softmax((xq Wq^T)(xk Wk^T)^T * scale) (xv Wv^T) Wo^T
// B=2, S=2048, H=32, D=128, DM=4096. I/O float32.
// R9: attn — swapped QK^T (mfma(K,Q)): lane owns one q-row -> P-stores become
// conflict-free ds_write_b64 (was 32 scalar u16, 4-way conflicted = the stuck
// 1.05e7 SQ_LDS_BANK_CONFLICT), row-max = in-lane + 2 shfl, scalar mrun.
// GEMMs: bijective XCD swizzle on block ids. Rest unchanged from R8.
// ============================================================================

using u16 = unsigned short;
using u32 = unsigned int;

typedef __attribute__((ext_vector_type(8))) short bf16x8;  // MFMA A/B frag (8 bf16)
typedef __attribute__((ext_vector_type(8))) u16 u16x8;
typedef __attribute__((ext_vector_type(4))) u16 u16x4;
typedef __attribute__((ext_vector_type(4))) float f32x4;   // MFMA C/D frag

#define MFMA_BF16(A, B, C) __builtin_amdgcn_mfma_f32_16x16x32_bf16((A), (B), (C), 0, 0, 0)

static constexpr int kS = 2048, kDM = 4096, kD = 128;
static constexpr size_t kMat = (size_t)4096 * 4096;
// SCALE * log2(e): softmax computed in exp2 domain
static constexpr float kScaleLog2e = 0.08838834764831845f * 1.44269504088896340736f;

static __device__ __forceinline__ void gload_lds16(const u16* g, u16* l) {
  __builtin_amdgcn_global_load_lds((const __attribute__((address_space(1))) void*)g,
                                   (__attribute__((address_space(3))) void*)l, 16, 0, 0);
}

static __device__ __forceinline__ u16 f2bf(float f) {  // RNE f32 -> bf16 bits (sw)
  u32 u = __float_as_uint(f);
  u32 r = u + 0x7FFFu + ((u >> 16) & 1u);
  return (u16)(r >> 16);
}

static __device__ __forceinline__ float bf2f(u16 x) {  // exact bf16 -> f32
  return __uint_as_float((u32)x << 16);
}

static __device__ __forceinline__ u16 nbf(float f) {  // native cast (hw cvt)
  union { __hip_bfloat16 h; u16 u; } cv;
  cv.h = __float2bfloat16(f);
  return cv.u;
}

static __device__ __forceinline__ u16x8 cvt8(float4 a, float4 b) {
  u16x8 r;
  r[0] = f2bf(a.x); r[1] = f2bf(a.y); r[2] = f2bf(a.z); r[3] = f2bf(a.w);
  r[4] = f2bf(b.x); r[5] = f2bf(b.y); r[6] = f2bf(b.z); r[7] = f2bf(b.w);
  return r;
}

// ---------------------------------------------------------------------------
// f32 -> bf16 bulk conversion: 7 matrices of kMat elems. Grid (X, 7).
// ---------------------------------------------------------------------------
__global__ __launch_bounds__(256) void cvt_kernel(
    const float* __restrict__ s0, const float* __restrict__ s1,
    const float* __restrict__ s2, const float* __restrict__ s3,
    const float* __restrict__ s4, const float* __restrict__ s5,
    const float* __restrict__ s6, u16* __restrict__ dst) {
  const int y = blockIdx.y;
  const float* s = (y == 0) ? s0 : (y == 1) ? s1 : (y == 2) ? s2 : (y == 3) ? s3
                  : (y == 4) ? s4 : (y == 5) ? s5 : s6;
  u16* d = dst + (size_t)y * kMat;
  const size_t nchunk = kMat / 8;
  const size_t step = (size_t)gridDim.x * 256;
  for (size_t c = (size_t)blockIdx.x * 256 + threadIdx.x; c < nchunk; c += step) {
    const float* p = s + c * 8;
    float4 a = *(const float4*)p;
    float4 b = *(const float4*)(p + 4);
    *(u16x8*)(d + c * 8) = cvt8(a, b);
  }
}

// ---------------------------------------------------------------------------
// 256x256 8-phase GEMM (T2+T3+T4+T5): Y[m][n] = sum_k X[m][k] * W[n][k].
// m0/n0 passed in (XCD-swizzled by the wrapper kernels).
// ---------------------------------------------------------------------------
template <bool TRANS, bool OUT_F32>
static __device__ __forceinline__ void gemm256(const u16* __restrict__ X,
                                               const u16* __restrict__ W,
                                               void* __restrict__ Yv,
                                               u16* __restrict__ lds,
                                               int m0, int n0) {
  constexpr int NT = kDM / 64;
  const int tid = threadIdx.x;
  const int lane = tid & 63;
  const int w = tid >> 6;
  const int fr = lane & 15;
  const int fq = lane >> 4;
  const int wr = w >> 2;  // 0..1  (M half)
  const int wc = w & 3;   // 0..3  (N quarter)

  const int srow = tid >> 3;
  const int scol = ((tid & 7) ^ (srow & 7)) * 8;
  const u16* Xrow = X + (size_t)(m0 + srow) * kDM + scol;
  const u16* Wrow = W + (size_t)(n0 + srow) * kDM + scol;
  const int w512 = w * 512;

  const int rBb = wc * 64 + fr;
  const int rAb = wr * 128 + fr;
  const int swz = fr & 7;

  f32x4 acc[8][4] = {};

#define STAGE2(ROWP, qrow, k0, ldq)                                       \
  do {                                                                    \
    gload_lds16((ROWP) + (size_t)(qrow) * kDM + (k0), &lds[(ldq) + w512]); \
    gload_lds16((ROWP) + (size_t)((qrow) + 64) * kDM + (k0),              \
                &lds[(ldq) + 4096 + w512]);                               \
  } while (0)

  STAGE2(Wrow, 0, 0, 0);
  STAGE2(Wrow, 128, 0, 8192);
  STAGE2(Xrow, 0, 0, 16384);
  STAGE2(Xrow, 128, 0, 24576);
  STAGE2(Wrow, 0, 64, 32768);
  STAGE2(Wrow, 128, 64, 32768 + 8192);
  STAGE2(Xrow, 0, 64, 32768 + 16384);
  asm volatile("s_waitcnt vmcnt(6)" ::: "memory");
  __builtin_amdgcn_s_barrier();

  for (int t = 0; t < NT; ++t) {
    const int d = t & 1;
    const int Boff = d * 32768;
    const int Aoff = Boff + 16384;
    bf16x8 bfr[4][2], af[8][2];

    // phase 0
#pragma unroll
    for (int nf = 0; nf < 4; ++nf)
#pragma unroll
      for (int ks = 0; ks < 2; ++ks)
        bfr[nf][ks] = *(const bf16x8*)&lds[Boff + (rBb + nf * 16) * 64 +
                                           (((ks * 4 + fq) ^ swz) * 8)];
#pragma unroll
    for (int mi = 0; mi < 4; ++mi)
#pragma unroll
      for (int ks = 0; ks < 2; ++ks)
        af[mi][ks] = *(const bf16x8*)&lds[Aoff + (rAb + mi * 16) * 64 +
                                          (((ks * 4 + fq) ^ swz) * 8)];
    if (t + 1 < NT) STAGE2(Xrow, 128, (t + 1) * 64, ((t + 1) & 1) * 32768 + 24576);
    __builtin_amdgcn_s_barrier();
    __builtin_amdgcn_s_setprio(1);
#pragma unroll
    for (int mi = 0; mi < 2; ++mi)
#pragma unroll
      for (int nf = 0; nf < 4; ++nf)
#pragma unroll
        for (int ks = 0; ks < 2; ++ks)
          acc[mi][nf] = TRANS ? MFMA_BF16(bfr[nf][ks], af[mi][ks], acc[mi][nf])
                              : MFMA_BF16(af[mi][ks], bfr[nf][ks], acc[mi][nf]);
    __builtin_amdgcn_s_setprio(0);
    __builtin_amdgcn_s_barrier();

    // phase 1
#pragma unroll
    for (int mi = 4; mi < 6; ++mi)
#pragma unroll
      for (int ks = 0; ks < 2; ++ks)
        af[mi][ks] = *(const bf16x8*)&lds[Aoff + (rAb + mi * 16) * 64 +
                                          (((ks * 4 + fq) ^ swz) * 8)];
    if (t + 2 < NT) STAGE2(Wrow, 0, (t + 2) * 64, d * 32768 + 0);
    __builtin_amdgcn_s_barrier();
    __builtin_amdgcn_s_setprio(1);
#pragma unroll
    for (int mi = 2; mi < 4; ++mi)
#pragma unroll
      for (int nf = 0; nf < 4; ++nf)
#pragma unroll
        for (int ks = 0; ks < 2; ++ks)
          acc[mi][nf] = TRANS ? MFMA_BF16(bfr[nf][ks], af[mi][ks], acc[mi][nf])
                              : MFMA_BF16(af[mi][ks], bfr[nf][ks], acc[mi][nf]);
    __builtin_amdgcn_s_setprio(0);
    __builtin_amdgcn_s_barrier();

    // phase 2
#pragma unroll
    for (int mi = 6; mi < 8; ++mi)
#pragma unroll
      for (int ks = 0; ks < 2; ++ks)
        af[mi][ks] = *(const bf16x8*)&lds[Aoff + (rAb + mi * 16) * 64 +
                                          (((ks * 4 + fq) ^ swz) * 8)];
    if (t + 2 < NT) STAGE2(Wrow, 128, (t + 2) * 64, d * 32768 + 8192);
    __builtin_amdgcn_s_barrier();
    __builtin_amdgcn_s_setprio(1);
#pragma unroll
    for (int mi = 4; mi < 6; ++mi)
#pragma unroll
      for (int nf = 0; nf < 4; ++nf)
#pragma unroll
        for (int ks = 0; ks < 2; ++ks)
          acc[mi][nf] = TRANS ? MFMA_BF16(bfr[nf][ks], af[mi][ks], acc[mi][nf])
                              : MFMA_BF16(af[mi][ks], bfr[nf][ks], acc[mi][nf]);
    __builtin_amdgcn_s_setprio(0);
    asm volatile("s_waitcnt lgkmcnt(0)" ::: "memory");
    __builtin_amdgcn_s_barrier();

    // phase 3
    if (t + 2 < NT) STAGE2(Xrow, 0, (t + 2) * 64, d * 32768 + 16384);
    __builtin_amdgcn_s_barrier();
    __builtin_amdgcn_s_setprio(1);
#pragma unroll
    for (int mi = 6; mi < 8; ++mi)
#pragma unroll
      for (int nf = 0; nf < 4; ++nf)
#pragma unroll
        for (int ks = 0; ks < 2; ++ks)
          acc[mi][nf] = TRANS ? MFMA_BF16(bfr[nf][ks], af[mi][ks], acc[mi][nf])
                              : MFMA_BF16(af[mi][ks], bfr[nf][ks], acc[mi][nf]);
    __builtin_amdgcn_s_setprio(0);
    if (t + 2 < NT)
      asm volatile("s_waitcnt vmcnt(6)" ::: "memory");
    else
      asm volatile("s_waitcnt vmcnt(0)" ::: "memory");
    __builtin_amdgcn_s_barrier();
  }
#undef STAGE2

#pragma unroll
  for (int mi = 0; mi < 8; ++mi)
#pragma unroll
    for (int nf = 0; nf < 4; ++nf) {
      int row, col;
      if constexpr (TRANS) {
        row = n0 + wc * 64 + nf * 16 + fq * 4;
        col = m0 + wr * 128 + mi * 16 + fr;
      } else {
        row = m0 + wr * 128 + mi * 16 + fq * 4;
        col = n0 + wc * 64 + nf * 16 + fr;
      }
      if constexpr (OUT_F32) {
        float* yp = (float*)Yv + (size_t)row * kDM + col;
#pragma unroll
        for (int i = 0; i < 4; ++i) yp[(size_t)i * kDM] = acc[mi][nf][i];
      } else {
        u16* yp = (u16*)Yv + (size_t)row * kDM + col;
#pragma unroll
        for (int i = 0; i < 4; ++i) yp[(size_t)i * kDM] = f2bf(acc[mi][nf][i]);
      }
    }
}

// XCD-aware bijective remap (hw flat id -> work id; 8 XCDs, nwg%8==0)
static __device__ __forceinline__ int xcd_swz(int id, int cpx) {
  return (id & 7) * cpx + (id >> 3);
}

__global__ __launch_bounds__(512, 2) void proj_qk256_kernel(const u16* __restrict__ wsb,
                                                            u16* __restrict__ qp,
                                                            u16* __restrict__ kp) {
  __shared__ u16 lds[65536];
  const int id = blockIdx.z * 256 + blockIdx.y * 16 + blockIdx.x;
  const int s = xcd_swz(id, 64);  // 512 blocks
  const int z = s >> 8;
  const int m0 = ((s >> 4) & 15) * 256, n0 = (s & 15) * 256;
  gemm256<false, false>(wsb + (size_t)z * kMat, wsb + (size_t)(3 + z) * kMat,
                        z ? kp : qp, lds, m0, n0);
}

__global__ __launch_bounds__(512, 2) void proj_vT256_kernel(const u16* __restrict__ wsb,
                                                            u16* __restrict__ vpT) {
  __shared__ u16 lds[65536];
  const int id = blockIdx.y * 16 + blockIdx.x;
  const int s = xcd_swz(id, 32);  // 256 blocks
  gemm256<true, false>(wsb + 2 * kMat, wsb + 5 * kMat, vpT, lds,
                       (s >> 4) * 256, (s & 15) * 256);
}

__global__ __launch_bounds__(512, 2) void out_proj256_kernel(const u16* __restrict__ ctx,
                                                             const u16* __restrict__ Wob,
                                                             float* __restrict__ out) {
  __shared__ u16 lds[65536];
  const int id = blockIdx.y * 16 + blockIdx.x;
  const int s = xcd_swz(id, 32);
  gemm256<false, true>(ctx, Wob, out, lds, (s >> 4) * 256, (s & 15) * 256);
}

// ---------------------------------------------------------------------------
// FALLBACK path (ws too small): in-GEMM convert staging (R5-verified).
// ---------------------------------------------------------------------------
template <bool A_BF16, bool TRANS, bool OUT_F32>
static __device__ __forceinline__ void gemm_conv(const void* Xv, const float* Wf,
                                                 void* Yv, u16* __restrict__ Als,
                                                 u16* __restrict__ Bls) {
  constexpr int KD = 4096;
  const int tid = threadIdx.x;
  const int lane = tid & 63;
  const int w = tid >> 6;
  const int fr = lane & 15;
  const int fq = lane >> 4;
  const int m0 = blockIdx.y * 128;
  const int n0 = blockIdx.x * 128;

  const int r0 = tid >> 2, cc0 = (tid & 3) * 8;
  const int r1 = r0 + 64;
  const int sr = lane >> 2, sc = (lane & 3) * 8;
  const int u0 = w * 2, u1 = w * 2 + 1;

  const u16* Xb = (const u16*)Xv;
  const float* Xf = (const float*)Xv;

  const int wm = (w >> 1) * 64;
  const int wn = (w & 1) * 64;

  f32x4 acc[4][4] = {};

  for (int kt = 0; kt < KD / 32; ++kt) {
    const int ko = kt * 32;
    if constexpr (A_BF16) {
      gload_lds16(Xb + (size_t)(m0 + u0 * 16 + sr) * KD + ko + sc, &Als[u0 * 512]);
      gload_lds16(Xb + (size_t)(m0 + u1 * 16 + sr) * KD + ko + sc, &Als[u1 * 512]);
    } else {
      const float* p0 = Xf + (size_t)(m0 + r0) * KD + ko + cc0;
      const float* p1 = Xf + (size_t)(m0 + r1) * KD + ko + cc0;
      float4 a0 = *(const float4*)(p0);
      float4 a1 = *(const float4*)(p0 + 4);
      float4 a2 = *(const float4*)(p1);
      float4 a3 = *(const float4*)(p1 + 4);
      *(u16x8*)&Als[r0 * 32 + cc0] = cvt8(a0, a1);
      *(u16x8*)&Als[r1 * 32 + cc0] = cvt8(a2, a3);
    }
    {
      const float* p0 = Wf + (size_t)(n0 + r0) * KD + ko + cc0;
      const float* p1 = Wf + (size_t)(n0 + r1) * KD + ko + cc0;
      float4 b0 = *(const float4*)(p0);
      float4 b1 = *(const float4*)(p0 + 4);
      float4 b2 = *(const float4*)(p1);
      float4 b3 = *(const float4*)(p1 + 4);
      *(u16x8*)&Bls[r0 * 32 + cc0] = cvt8(b0, b1);
      *(u16x8*)&Bls[r1 * 32 + cc0] = cvt8(b2, b3);
    }
    __syncthreads();

    bf16x8 af[4], bfv[4];
#pragma unroll
    for (int i = 0; i < 4; ++i)
      af[i] = *(const bf16x8*)&Als[(wm + i * 16 + fr) * 32 + fq * 8];
#pragma unroll
    for (int i = 0; i < 4; ++i)
      bfv[i] = *(const bf16x8*)&Bls[(wn + i * 16 + fr) * 32 + fq * 8];
#pragma unroll
    for (int a = 0; a < 4; ++a)
#pragma unroll
      for (int bb = 0; bb < 4; ++bb) {
        if constexpr (TRANS)
          acc[a][bb] = MFMA_BF16(bfv[a], af[bb], acc[a][bb]);
        else
          acc[a][bb] = MFMA_BF16(af[a], bfv[bb], acc[a][bb]);
      }
    __syncthreads();
  }

#pragma unroll
  for (int a = 0; a < 4; ++a)
#pragma unroll
    for (int bb = 0; bb < 4; ++bb) {
      const int row = TRANS ? (n0 + wn + a * 16 + fq * 4) : (m0 + wm + a * 16 + fq * 4);
      const int col = TRANS ? (m0 + wm + bb * 16 + fr) : (n0 + wn + bb * 16 + fr);
      if constexpr (OUT_F32) {
        float* yp = (float*)Yv + (size_t)row * kDM + col;
#pragma unroll
        for (int i = 0; i < 4; ++i) yp[(size_t)i * kDM] = acc[a][bb][i];
      } else {
        u16* yp = (u16*)Yv + (size_t)row * kDM + col;
#pragma unroll
        for (int i = 0; i < 4; ++i) yp[(size_t)i * kDM] = f2bf(acc[a][bb][i]);
      }
    }
}

__global__ __launch_bounds__(256) void proj_qk_conv_kernel(
    const float* __restrict__ q, const float* __restrict__ k,
    const float* __restrict__ Wq, const float* __restrict__ Wk,
    u16* __restrict__ qp, u16* __restrict__ kp) {
  __shared__ u16 Als[128 * 32];
  __shared__ u16 Bls[128 * 32];
  const int z = blockIdx.z;
  gemm_conv<false, false, false>(z ? k : q, z ? Wk : Wq, z ? kp : qp, Als, Bls);
}

__global__ __launch_bounds__(256) void proj_vT_conv_kernel(
    const float* __restrict__ v, const float* __restrict__ Wv, u16* __restrict__ vpT) {
  __shared__ u16 Als[128 * 32];
  __shared__ u16 Bls[128 * 32];
  gemm_conv<false, true, false>(v, Wv, vpT, Als, Bls);
}

__global__ __launch_bounds__(256) void out_proj_conv_kernel(const u16* __restrict__ ctx,
                                                            const float* __restrict__ Wo,
                                                            float* __restrict__ out) {
  __shared__ u16 Als[128 * 32];
  __shared__ u16 Bls[128 * 32];
  gemm_conv<true, false, true>(ctx, Wo, out, Als, Bls);
}

// ---------------------------------------------------------------------------
// Flash attention R9: grid (8,64) block 512 = 8 waves; 256 q-rows/block.
// Swapped QK^T: sacc[rb][cb][i] = S[q = q0+w*32+rb*16+fr][key = cb*16+fq*4+i].
// Row-max = in-lane 16 + 2 shfl; P packed to ds_write_b64 (conflict-free);
// ones-V MFMA denom; defer-max (scalar mrun); reg-staged async K/V prefetch.
// ---------------------------------------------------------------------------
__global__ __launch_bounds__(512) void attn_kernel(const u16* __restrict__ qp,
                                                   const u16* __restrict__ kp,
                                                   const u16* __restrict__ vpT,
                                                   u16* __restrict__ ctx) {
  constexpr int KB = 64;
  constexpr int NT = kS / KB;   // 32 tiles
  constexpr int PST = 72;       // P row stride (elems, 16B-aligned rows)
  constexpr float THR = 11.5f;  // defer-max threshold (log2 units ~ e^8)

  __shared__ u16 Kls[KB * 128];        // 16 KB [key][d] chunk-swizzled
  __shared__ u16 Vt[kD * KB];          // 16 KB [d][key] chunk-swizzled
  __shared__ u16 Pls[8][2 * 16 * PST]; // 36 KB per-wave P tiles [q][key]

  const int tid = threadIdx.x, lane = tid & 63, w = tid >> 6;  // w: 0..7
  const int fr = lane & 15, fq = lane >> 4;

  // XCD-aware bijective swizzle (as R8)
  const int wg = blockIdx.y * 8 + blockIdx.x;
  const int o = (wg & 7) * 64 + (wg >> 3);
  const int bh = o >> 3;
  const int b = bh >> 5, h = bh & 31;
  const int q0 = (o & 7) * 256;

  const u16* qbase = qp + ((size_t)b * kS) * kDM + h * kD;
  const u16* kbase = kp + ((size_t)b * kS) * kDM + h * kD;
  const u16* vtbase = vpT + (size_t)(h * kD) * kDM + b * kS;  // row d, stride kDM

  // Q fragments, pre-scaled by SCALE*log2e
  bf16x8 qf[2][4];
#pragma unroll
  for (int rb = 0; rb < 2; ++rb)
#pragma unroll
    for (int kc = 0; kc < 4; ++kc) {
      const u16x8 raw = *(const u16x8*)(qbase +
          (size_t)(q0 + w * 32 + rb * 16 + fr) * kDM + kc * 32 + fq * 8);
      bf16x8 s;
#pragma unroll
      for (int j = 0; j < 8; ++j) s[j] = (short)f2bf(bf2f(raw[j]) * kScaleLog2e);
      qf[rb][kc] = s;
    }

  // acc[rb][0..7] = O blocks; acc[rb][8] = row-sum (ones-V) == softmax denom
  f32x4 oacc[2][9] = {};
  float mrun[2] = {-1e30f, -1e30f};  // per-lane scalar: running max of row q=fr

  bf16x8 ones;
#pragma unroll
  for (int j = 0; j < 8; ++j) ones[j] = (short)0x3F80;  // bf16 1.0

  // staging geometry (reg-staged, as R8)
  const int krl = lane >> 4, kdp = lane & 15;
  const int vdl = lane >> 3, vc = lane & 7;
  const int rk0 = (w * 2 + 0) * 4 + krl;
  const int rk1 = (w * 2 + 1) * 4 + krl;
  const int dv0 = (w * 2 + 0) * 8 + vdl;
  const int dv1 = (w * 2 + 1) * 8 + vdl;
  const u16* kg0 = kbase + (size_t)rk0 * kDM + kdp * 8;
  const u16* kg1 = kbase + (size_t)rk1 * kDM + kdp * 8;
  const u16* vg0 = vtbase + (size_t)dv0 * kDM + vc * 8;
  const u16* vg1 = vtbase + (size_t)dv1 * kDM + vc * 8;
  u16* kl0 = &Kls[rk0 * 128 + ((kdp ^ (rk0 & 7)) * 8)];
  u16* kl1 = &Kls[rk1 * 128 + ((kdp ^ (rk1 & 7)) * 8)];
  u16* vl0 = &Vt[dv0 * KB + ((vc ^ (dv0 & 7)) * 8)];
  u16* vl1 = &Vt[dv1 * KB + ((vc ^ (dv1 & 7)) * 8)];

  u16x8 kr0v, kr1v, vr0v, vr1v;
  kr0v = *(const u16x8*)kg0;
  kr1v = *(const u16x8*)kg1;
  vr0v = *(const u16x8*)vg0;
  vr1v = *(const u16x8*)vg1;
  *(u16x8*)kl0 = kr0v; *(u16x8*)kl1 = kr1v;
  *(u16x8*)vl0 = vr0v; *(u16x8*)vl1 = vr1v;
  __syncthreads();

  for (int kt = 0; kt < NT; ++kt) {
    // issue next-tile loads NOW — latency hides under QK^T/softmax/PV (T14)
    if (kt + 1 < NT) {
      const size_t ko = (size_t)(kt + 1) * KB;
      kr0v = *(const u16x8*)(kg0 + ko * kDM);
      kr1v = *(const u16x8*)(kg1 + ko * kDM);
      vr0v = *(const u16x8*)(vg0 + ko);
      vr1v = *(const u16x8*)(vg1 + ko);
    }

    // --- QK^T (swapped: mfma(K, Q)) ---
    f32x4 sacc[2][4] = {};
#pragma unroll
    for (int cb = 0; cb < 4; ++cb) {
      const int n = cb * 16 + fr;
      bf16x8 kf[4];
#pragma unroll
      for (int kc = 0; kc < 4; ++kc) {
        const int d0 = kc * 4 + fq;
        kf[kc] = *(const bf16x8*)&Kls[n * 128 + (d0 ^ (n & 7)) * 8];
      }
      __builtin_amdgcn_s_setprio(1);
#pragma unroll
      for (int rb = 0; rb < 2; ++rb)
#pragma unroll
        for (int kc = 0; kc < 4; ++kc)
          sacc[rb][cb] = MFMA_BF16(kf[kc], qf[rb][kc], sacc[rb][cb]);
      __builtin_amdgcn_s_setprio(0);
    }

    // --- online softmax: lane owns row q=fr; keys = cb*16 + fq*4 + i ---
#pragma unroll
    for (int rb = 0; rb < 2; ++rb) {
      float m = sacc[rb][0][0];
#pragma unroll
      for (int cb = 0; cb < 4; ++cb)
#pragma unroll
        for (int i = 0; i < 4; ++i) m = fmaxf(m, sacc[rb][cb][i]);
      m = fmaxf(m, __shfl_xor(m, 16));
      m = fmaxf(m, __shfl_xor(m, 32));  // full row-max for q=fr

      if (__any(m - mrun[rb] > THR)) {  // deferred rescale (T13)
        const float mnew = fmaxf(mrun[rb], m);
        const float sclS = exp2f(mrun[rb] - mnew);
        mrun[rb] = mnew;
        float scl[4];
#pragma unroll
        for (int i = 0; i < 4; ++i) scl[i] = __shfl(sclS, fq * 4 + i);
#pragma unroll
        for (int db = 0; db < 9; ++db)
#pragma unroll
          for (int i = 0; i < 4; ++i) oacc[rb][db][i] *= scl[i];
      }

#pragma unroll
      for (int cb = 0; cb < 4; ++cb) {
        u16x4 pk;
#pragma unroll
        for (int i = 0; i < 4; ++i)
          pk[i] = nbf(exp2f(sacc[rb][cb][i] - mrun[rb]));
        *(u16x4*)&Pls[w][rb * (16 * PST) + fr * PST + cb * 16 + fq * 4] = pk;
      }
    }

    asm volatile("s_waitcnt lgkmcnt(0)" ::: "memory");

    // --- PV (+ denom via ones-V); P layout in LDS unchanged: [q][key] ---
    bf16x8 pf[2][2];
#pragma unroll
    for (int rb = 0; rb < 2; ++rb)
#pragma unroll
      for (int kb = 0; kb < 2; ++kb)
        pf[rb][kb] = *(const bf16x8*)&Pls[w][rb * (16 * PST) + fr * PST + kb * 32 + fq * 8];
#pragma unroll
    for (int db = 0; db < 8; ++db) {
      const int d = db * 16 + fr;
      bf16x8 vf0 = *(const bf16x8*)&Vt[d * KB + ((fq ^ (d & 7)) << 3)];
      bf16x8 vf1 = *(const bf16x8*)&Vt[d * KB + (((4 + fq) ^ (d & 7)) << 3)];
      __builtin_amdgcn_s_setprio(1);
#pragma unroll
      for (int rb = 0; rb < 2; ++rb) {
        oacc[rb][db] = MFMA_BF16(pf[rb][0], vf0, oacc[rb][db]);
        oacc[rb][db] = MFMA_BF16(pf[rb][1], vf1, oacc[rb][db]);
      }
      __builtin_amdgcn_s_setprio(0);
    }
    __builtin_amdgcn_s_setprio(1);
#pragma unroll
    for (int rb = 0; rb < 2; ++rb) {
      oacc[rb][8] = MFMA_BF16(pf[rb][0], ones, oacc[rb][8]);
      oacc[rb][8] = MFMA_BF16(pf[rb][1], ones, oacc[rb][8]);
    }
    __builtin_amdgcn_s_setprio(0);

    __syncthreads();  // all waves done reading Kls/Vt of tile kt
    if (kt + 1 < NT) {
      *(u16x8*)kl0 = kr0v; *(u16x8*)kl1 = kr1v;
      *(u16x8*)vl0 = vr0v; *(u16x8*)vl1 = vr1v;
    }
    __syncthreads();  // tile kt+1 staged
  }

  u16* cbase = ctx + ((size_t)b * kS) * kDM + h * kD;
#pragma unroll
  for (int rb = 0; rb < 2; ++rb) {
    float inv[4];
#pragma unroll
    for (int i = 0; i < 4; ++i) inv[i] = 1.0f / oacc[rb][8][i];
#pragma unroll
    for (int db = 0; db < 8; ++db)
#pragma unroll
      for (int i = 0; i < 4; ++i) {
        const int row = q0 + w * 32 + rb * 16 + fq * 4 + i;
        const int col = db * 16 + fr;
        cbase[(size_t)row * kDM + col] = nbf(oacc[rb][db][i] * inv[i]);
      }
  }
}

// ---------------------------------------------------------------------------
extern "C" void kernel_launch(void* const* d_in, const int* in_sizes, int n_in,
                              void* d_out, int out_size, void* d_ws, size_t ws_size,
                              hipStream_t stream) {
  const float* q = (const float*)d_in[0];
  const float* k = (const float*)d_in[1];
  const float* v = (const float*)d_in[2];
  const float* Wq = (const float*)d_in[3];
  const float* Wk = (const float*)d_in[4];
  const float* Wv = (const float*)d_in[5];
  const float* Wo = (const float*)d_in[6];
  float* out = (float*)d_out;

  const size_t needFast = 11 * kMat * sizeof(u16);  // 7 bf16 inputs + qp/kp/vpT/ctx

  if (ws_size >= needFast) {
    u16* wsb = (u16*)d_ws;            // [0..6]: qb kb vb Wqb Wkb Wvb Wob
    u16* qp = wsb + 7 * kMat;
    u16* kp = wsb + 8 * kMat;
    u16* vpT = wsb + 9 * kMat;
    u16* ctx = wsb + 10 * kMat;

    cvt_kernel<<<dim3(1024, 7), 256, 0, stream>>>(q, k, v, Wq, Wk, Wv, Wo, wsb);
    proj_qk256_kernel<<<dim3(16, 16, 2), 512, 0, stream>>>(wsb, qp, kp);
    proj_vT256_kernel<<<dim3(16, 16), 512, 0, stream>>>(wsb, vpT);
    attn_kernel<<<dim3(8, 64), 512, 0, stream>>>(qp, kp, vpT, ctx);
    out_proj256_kernel<<<dim3(16, 16), 512, 0, stream>>>(ctx, wsb + 6 * kMat, out);
  } else {
    u16* qp = (u16*)d_ws;
    u16* kp = qp + kMat;
    u16* vpT = kp + kMat;
    u16* ctx = vpT + kMat;

    proj_qk_conv_kernel<<<dim3(32, 32, 2), 256, 0, stream>>>(q, k, Wq, Wk, qp, kp);
    proj_vT_conv_kernel<<<dim3(32, 32), 256, 0, stream>>>(v, Wv, vpT);
    attn_kernel<<<dim3(8, 64), 512, 0, stream>>>(qp, kp, vpT, ctx);
    out_proj_conv_kernel<<<dim3(32, 32, 1), 256, 0, stream>>>(ctx, Wo, out);
  }
}

// Round 10
// 741.729 us; speedup vs baseline: 2.4148x; 1.0029x over previous
//
#include <hip/hip_runtime.h>
#include <hip/hip_bf16.h>
#include <stdint.h>

// ============================================================================
// MultiHeadAttention: y = softmax((xq Wq^T)(xk Wk^T)^T * scale) (xv Wv^T) Wo^T
// B=2, S=2048, H=32, D=128, DM=4096. I/O float32.
// R10: gemm256 loop re-shaped to the exact m201 8-phase schedule — in-phase
// ds_reads (12/4/4/4 per K-tile), one half-tile stage per phase with rolling
// stagger {A1(t+1)@p0, B0(t+2)@p1, B1(t+2)@p2, A0(t+2)@p3}, vmcnt(6) once
// per K-tile. Attn (R9 swapped-QK^T) and cvt unchanged.
// ============================================================================

using u16 = unsigned short;
using u32 = unsigned int;

typedef __attribute__((ext_vector_type(8))) short bf16x8;  // MFMA A/B frag (8 bf16)
typedef __attribute__((ext_vector_type(8))) u16 u16x8;
typedef __attribute__((ext_vector_type(4))) u16 u16x4;
typedef __attribute__((ext_vector_type(4))) float f32x4;   // MFMA C/D frag

#define MFMA_BF16(A, B, C) __builtin_amdgcn_mfma_f32_16x16x32_bf16((A), (B), (C), 0, 0, 0)

static constexpr int kS = 2048, kDM = 4096, kD = 128;
static constexpr size_t kMat = (size_t)4096 * 4096;
// SCALE * log2(e): softmax computed in exp2 domain
static constexpr float kScaleLog2e = 0.08838834764831845f * 1.44269504088896340736f;

static __device__ __forceinline__ void gload_lds16(const u16* g, u16* l) {
  __builtin_amdgcn_global_load_lds((const __attribute__((address_space(1))) void*)g,
                                   (__attribute__((address_space(3))) void*)l, 16, 0, 0);
}

static __device__ __forceinline__ u16 f2bf(float f) {  // RNE f32 -> bf16 bits (sw)
  u32 u = __float_as_uint(f);
  u32 r = u + 0x7FFFu + ((u >> 16) & 1u);
  return (u16)(r >> 16);
}

static __device__ __forceinline__ float bf2f(u16 x) {  // exact bf16 -> f32
  return __uint_as_float((u32)x << 16);
}

static __device__ __forceinline__ u16 nbf(float f) {  // native cast (hw cvt)
  union { __hip_bfloat16 h; u16 u; } cv;
  cv.h = __float2bfloat16(f);
  return cv.u;
}

static __device__ __forceinline__ u16x8 cvt8(float4 a, float4 b) {
  u16x8 r;
  r[0] = f2bf(a.x); r[1] = f2bf(a.y); r[2] = f2bf(a.z); r[3] = f2bf(a.w);
  r[4] = f2bf(b.x); r[5] = f2bf(b.y); r[6] = f2bf(b.z); r[7] = f2bf(b.w);
  return r;
}

// ---------------------------------------------------------------------------
// f32 -> bf16 bulk conversion: 7 matrices of kMat elems. Grid (X, 7).
// ---------------------------------------------------------------------------
__global__ __launch_bounds__(256) void cvt_kernel(
    const float* __restrict__ s0, const float* __restrict__ s1,
    const float* __restrict__ s2, const float* __restrict__ s3,
    const float* __restrict__ s4, const float* __restrict__ s5,
    const float* __restrict__ s6, u16* __restrict__ dst) {
  const int y = blockIdx.y;
  const float* s = (y == 0) ? s0 : (y == 1) ? s1 : (y == 2) ? s2 : (y == 3) ? s3
                  : (y == 4) ? s4 : (y == 5) ? s5 : s6;
  u16* d = dst + (size_t)y * kMat;
  const size_t nchunk = kMat / 8;
  const size_t step = (size_t)gridDim.x * 256;
  for (size_t c = (size_t)blockIdx.x * 256 + threadIdx.x; c < nchunk; c += step) {
    const float* p = s + c * 8;
    float4 a = *(const float4*)p;
    float4 b = *(const float4*)(p + 4);
    *(u16x8*)(d + c * 8) = cvt8(a, b);
  }
}

// ---------------------------------------------------------------------------
// 256x256 8-phase GEMM, m201-exact schedule. Y[m][n] = sum_k X[m][k]*W[n][k].
// 512 thr = 8 waves (2M x 4N), per-wave 128x64, BK=64, 128KB LDS dbuf.
// Per K-tile: 4 phases {in-phase ds_reads; stage 1 half; barrier; 16 MFMA;
// barrier}; stages target: p0->A1(t+1), p1->B0(t+2), p2->B1(t+2), p3->A0(t+2);
// vmcnt(6) at p3 end (drains tile t+1 fully; 3 halves stay in flight).
// Safety: a staged region's previous-tile reads are all complete before the
// stage issues (reads are consumed by same-phase MFMA before the closing
// barrier; stages issue in a later phase).
// ---------------------------------------------------------------------------
template <bool TRANS, bool OUT_F32>
static __device__ __forceinline__ void gemm256(const u16* __restrict__ X,
                                               const u16* __restrict__ W,
                                               void* __restrict__ Yv,
                                               u16* __restrict__ lds,
                                               int m0, int n0) {
  constexpr int NT = kDM / 64;
  const int tid = threadIdx.x;
  const int lane = tid & 63;
  const int w = tid >> 6;
  const int fr = lane & 15;
  const int fq = lane >> 4;
  const int wr = w >> 2;  // 0..1  (M half)
  const int wc = w & 3;   // 0..3  (N quarter)

  const int srow = tid >> 3;
  const int scol = ((tid & 7) ^ (srow & 7)) * 8;
  const u16* Xrow = X + (size_t)(m0 + srow) * kDM + scol;
  const u16* Wrow = W + (size_t)(n0 + srow) * kDM + scol;
  const int w512 = w * 512;

  const int rBb = wc * 64 + fr;
  const int rAb = wr * 128 + fr;
  const int swz = fr & 7;

  f32x4 acc[8][4] = {};

#define STAGE2(ROWP, qrow, k0, ldq)                                        \
  do {                                                                     \
    gload_lds16((ROWP) + (size_t)(qrow) * kDM + (k0), &lds[(ldq) + w512]); \
    gload_lds16((ROWP) + (size_t)((qrow) + 64) * kDM + (k0),               \
                &lds[(ldq) + 4096 + w512]);                                \
  } while (0)

#define RD_B(nf, ks) \
  (*(const bf16x8*)&lds[Boff + (rBb + (nf) * 16) * 64 + ((((ks) * 4 + fq) ^ swz) * 8)])
#define RD_A(mi, ks) \
  (*(const bf16x8*)&lds[Aoff + (rAb + (mi) * 16) * 64 + ((((ks) * 4 + fq) ^ swz) * 8)])

#define CLUSTER(mia)                                                            \
  do {                                                                          \
    __builtin_amdgcn_s_setprio(1);                                              \
    _Pragma("unroll") for (int mj = 0; mj < 2; ++mj)                            \
    _Pragma("unroll") for (int nf = 0; nf < 4; ++nf)                            \
    _Pragma("unroll") for (int ks = 0; ks < 2; ++ks)                            \
      acc[(mia) + mj][nf] =                                                     \
          TRANS ? MFMA_BF16(bfr[nf][ks], af[mj][ks], acc[(mia) + mj][nf])       \
                : MFMA_BF16(af[mj][ks], bfr[nf][ks], acc[(mia) + mj][nf]);      \
    __builtin_amdgcn_s_setprio(0);                                              \
  } while (0)

  // prologue: t0 {B0,B1,A0,A1}, t1 {B0,B1,A0}; A1(t1) staged at p0(t0).
  STAGE2(Wrow, 0, 0, 0);
  STAGE2(Wrow, 128, 0, 8192);
  STAGE2(Xrow, 0, 0, 16384);
  STAGE2(Xrow, 128, 0, 24576);
  STAGE2(Wrow, 0, 64, 32768);
  STAGE2(Wrow, 128, 64, 32768 + 8192);
  STAGE2(Xrow, 0, 64, 32768 + 16384);
  asm volatile("s_waitcnt vmcnt(6)" ::: "memory");
  __builtin_amdgcn_s_barrier();

  for (int t = 0; t < NT; ++t) {
    const int d = t & 1;
    const int Boff = d * 32768;
    const int Aoff = Boff + 16384;
    bf16x8 bfr[4][2], af[2][2];

    // ---- phase 0: read B(8) + A[mi0,1](4); stage A1(t+1) ----
#pragma unroll
    for (int nf = 0; nf < 4; ++nf)
#pragma unroll
      for (int ks = 0; ks < 2; ++ks) bfr[nf][ks] = RD_B(nf, ks);
#pragma unroll
    for (int mj = 0; mj < 2; ++mj)
#pragma unroll
      for (int ks = 0; ks < 2; ++ks) af[mj][ks] = RD_A(mj, ks);
    if (t + 1 < NT) STAGE2(Xrow, 128, (t + 1) * 64, ((t + 1) & 1) * 32768 + 24576);
    asm volatile("s_waitcnt lgkmcnt(8)" ::: "memory");  // 12 reads: early drain
    __builtin_amdgcn_s_barrier();
    CLUSTER(0);
    __builtin_amdgcn_s_barrier();

    // ---- phase 1: read A[mi2,3]; stage B0(t+2) ----
#pragma unroll
    for (int mj = 0; mj < 2; ++mj)
#pragma unroll
      for (int ks = 0; ks < 2; ++ks) af[mj][ks] = RD_A(2 + mj, ks);
    if (t + 2 < NT) STAGE2(Wrow, 0, (t + 2) * 64, d * 32768 + 0);
    __builtin_amdgcn_s_barrier();
    CLUSTER(2);
    __builtin_amdgcn_s_barrier();

    // ---- phase 2: read A[mi4,5]; stage B1(t+2) ----
#pragma unroll
    for (int mj = 0; mj < 2; ++mj)
#pragma unroll
      for (int ks = 0; ks < 2; ++ks) af[mj][ks] = RD_A(4 + mj, ks);
    if (t + 2 < NT) STAGE2(Wrow, 128, (t + 2) * 64, d * 32768 + 8192);
    __builtin_amdgcn_s_barrier();
    CLUSTER(4);
    __builtin_amdgcn_s_barrier();

    // ---- phase 3: read A[mi6,7]; stage A0(t+2); vmcnt(6) ----
#pragma unroll
    for (int mj = 0; mj < 2; ++mj)
#pragma unroll
      for (int ks = 0; ks < 2; ++ks) af[mj][ks] = RD_A(6 + mj, ks);
    if (t + 2 < NT) STAGE2(Xrow, 0, (t + 2) * 64, d * 32768 + 16384);
    __builtin_amdgcn_s_barrier();
    CLUSTER(6);
    if (t + 2 < NT)
      asm volatile("s_waitcnt vmcnt(6)" ::: "memory");
    else
      asm volatile("s_waitcnt vmcnt(0)" ::: "memory");
    __builtin_amdgcn_s_barrier();
  }
#undef CLUSTER
#undef RD_A
#undef RD_B
#undef STAGE2

  // epilogue: C/D layout col=lane&15, row=(lane>>4)*4+i [m89/m91]
#pragma unroll
  for (int mi = 0; mi < 8; ++mi)
#pragma unroll
    for (int nf = 0; nf < 4; ++nf) {
      int row, col;
      if constexpr (TRANS) {
        row = n0 + wc * 64 + nf * 16 + fq * 4;
        col = m0 + wr * 128 + mi * 16 + fr;
      } else {
        row = m0 + wr * 128 + mi * 16 + fq * 4;
        col = n0 + wc * 64 + nf * 16 + fr;
      }
      if constexpr (OUT_F32) {
        float* yp = (float*)Yv + (size_t)row * kDM + col;
#pragma unroll
        for (int i = 0; i < 4; ++i) yp[(size_t)i * kDM] = acc[mi][nf][i];
      } else {
        u16* yp = (u16*)Yv + (size_t)row * kDM + col;
#pragma unroll
        for (int i = 0; i < 4; ++i) yp[(size_t)i * kDM] = f2bf(acc[mi][nf][i]);
      }
    }
}

// XCD-aware bijective remap (hw flat id -> work id; 8 XCDs, nwg%8==0)
static __device__ __forceinline__ int xcd_swz(int id, int cpx) {
  return (id & 7) * cpx + (id >> 3);
}

__global__ __launch_bounds__(512, 2) void proj_qk256_kernel(const u16* __restrict__ wsb,
                                                            u16* __restrict__ qp,
                                                            u16* __restrict__ kp) {
  __shared__ u16 lds[65536];
  const int id = blockIdx.z * 256 + blockIdx.y * 16 + blockIdx.x;
  const int s = xcd_swz(id, 64);  // 512 blocks
  const int z = s >> 8;
  const int m0 = ((s >> 4) & 15) * 256, n0 = (s & 15) * 256;
  gemm256<false, false>(wsb + (size_t)z * kMat, wsb + (size_t)(3 + z) * kMat,
                        z ? kp : qp, lds, m0, n0);
}

__global__ __launch_bounds__(512, 2) void proj_vT256_kernel(const u16* __restrict__ wsb,
                                                            u16* __restrict__ vpT) {
  __shared__ u16 lds[65536];
  const int id = blockIdx.y * 16 + blockIdx.x;
  const int s = xcd_swz(id, 32);  // 256 blocks
  gemm256<true, false>(wsb + 2 * kMat, wsb + 5 * kMat, vpT, lds,
                       (s >> 4) * 256, (s & 15) * 256);
}

__global__ __launch_bounds__(512, 2) void out_proj256_kernel(const u16* __restrict__ ctx,
                                                             const u16* __restrict__ Wob,
                                                             float* __restrict__ out) {
  __shared__ u16 lds[65536];
  const int id = blockIdx.y * 16 + blockIdx.x;
  const int s = xcd_swz(id, 32);
  gemm256<false, true>(ctx, Wob, out, lds, (s >> 4) * 256, (s & 15) * 256);
}

// ---------------------------------------------------------------------------
// FALLBACK path (ws too small): in-GEMM convert staging (R5-verified).
// ---------------------------------------------------------------------------
template <bool A_BF16, bool TRANS, bool OUT_F32>
static __device__ __forceinline__ void gemm_conv(const void* Xv, const float* Wf,
                                                 void* Yv, u16* __restrict__ Als,
                                                 u16* __restrict__ Bls) {
  constexpr int KD = 4096;
  const int tid = threadIdx.x;
  const int lane = tid & 63;
  const int w = tid >> 6;
  const int fr = lane & 15;
  const int fq = lane >> 4;
  const int m0 = blockIdx.y * 128;
  const int n0 = blockIdx.x * 128;

  const int r0 = tid >> 2, cc0 = (tid & 3) * 8;
  const int r1 = r0 + 64;
  const int sr = lane >> 2, sc = (lane & 3) * 8;
  const int u0 = w * 2, u1 = w * 2 + 1;

  const u16* Xb = (const u16*)Xv;
  const float* Xf = (const float*)Xv;

  const int wm = (w >> 1) * 64;
  const int wn = (w & 1) * 64;

  f32x4 acc[4][4] = {};

  for (int kt = 0; kt < KD / 32; ++kt) {
    const int ko = kt * 32;
    if constexpr (A_BF16) {
      gload_lds16(Xb + (size_t)(m0 + u0 * 16 + sr) * KD + ko + sc, &Als[u0 * 512]);
      gload_lds16(Xb + (size_t)(m0 + u1 * 16 + sr) * KD + ko + sc, &Als[u1 * 512]);
    } else {
      const float* p0 = Xf + (size_t)(m0 + r0) * KD + ko + cc0;
      const float* p1 = Xf + (size_t)(m0 + r1) * KD + ko + cc0;
      float4 a0 = *(const float4*)(p0);
      float4 a1 = *(const float4*)(p0 + 4);
      float4 a2 = *(const float4*)(p1);
      float4 a3 = *(const float4*)(p1 + 4);
      *(u16x8*)&Als[r0 * 32 + cc0] = cvt8(a0, a1);
      *(u16x8*)&Als[r1 * 32 + cc0] = cvt8(a2, a3);
    }
    {
      const float* p0 = Wf + (size_t)(n0 + r0) * KD + ko + cc0;
      const float* p1 = Wf + (size_t)(n0 + r1) * KD + ko + cc0;
      float4 b0 = *(const float4*)(p0);
      float4 b1 = *(const float4*)(p0 + 4);
      float4 b2 = *(const float4*)(p1);
      float4 b3 = *(const float4*)(p1 + 4);
      *(u16x8*)&Bls[r0 * 32 + cc0] = cvt8(b0, b1);
      *(u16x8*)&Bls[r1 * 32 + cc0] = cvt8(b2, b3);
    }
    __syncthreads();

    bf16x8 af[4], bfv[4];
#pragma unroll
    for (int i = 0; i < 4; ++i)
      af[i] = *(const bf16x8*)&Als[(wm + i * 16 + fr) * 32 + fq * 8];
#pragma unroll
    for (int i = 0; i < 4; ++i)
      bfv[i] = *(const bf16x8*)&Bls[(wn + i * 16 + fr) * 32 + fq * 8];
#pragma unroll
    for (int a = 0; a < 4; ++a)
#pragma unroll
      for (int bb = 0; bb < 4; ++bb) {
        if constexpr (TRANS)
          acc[a][bb] = MFMA_BF16(bfv[a], af[bb], acc[a][bb]);
        else
          acc[a][bb] = MFMA_BF16(af[a], bfv[bb], acc[a][bb]);
      }
    __syncthreads();
  }

#pragma unroll
  for (int a = 0; a < 4; ++a)
#pragma unroll
    for (int bb = 0; bb < 4; ++bb) {
      const int row = TRANS ? (n0 + wn + a * 16 + fq * 4) : (m0 + wm + a * 16 + fq * 4);
      const int col = TRANS ? (m0 + wm + bb * 16 + fr) : (n0 + wn + bb * 16 + fr);
      if constexpr (OUT_F32) {
        float* yp = (float*)Yv + (size_t)row * kDM + col;
#pragma unroll
        for (int i = 0; i < 4; ++i) yp[(size_t)i * kDM] = acc[a][bb][i];
      } else {
        u16* yp = (u16*)Yv + (size_t)row * kDM + col;
#pragma unroll
        for (int i = 0; i < 4; ++i) yp[(size_t)i * kDM] = f2bf(acc[a][bb][i]);
      }
    }
}

__global__ __launch_bounds__(256) void proj_qk_conv_kernel(
    const float* __restrict__ q, const float* __restrict__ k,
    const float* __restrict__ Wq, const float* __restrict__ Wk,
    u16* __restrict__ qp, u16* __restrict__ kp) {
  __shared__ u16 Als[128 * 32];
  __shared__ u16 Bls[128 * 32];
  const int z = blockIdx.z;
  gemm_conv<false, false, false>(z ? k : q, z ? Wk : Wq, z ? kp : qp, Als, Bls);
}

__global__ __launch_bounds__(256) void proj_vT_conv_kernel(
    const float* __restrict__ v, const float* __restrict__ Wv, u16* __restrict__ vpT) {
  __shared__ u16 Als[128 * 32];
  __shared__ u16 Bls[128 * 32];
  gemm_conv<false, true, false>(v, Wv, vpT, Als, Bls);
}

__global__ __launch_bounds__(256) void out_proj_conv_kernel(const u16* __restrict__ ctx,
                                                            const float* __restrict__ Wo,
                                                            float* __restrict__ out) {
  __shared__ u16 Als[128 * 32];
  __shared__ u16 Bls[128 * 32];
  gemm_conv<true, false, true>(ctx, Wo, out, Als, Bls);
}

// ---------------------------------------------------------------------------
// Flash attention (R9, unchanged): grid (8,64) block 512 = 8 waves.
// Swapped QK^T; conflict-free b64 P-stores; ones-V denom; defer-max;
// reg-staged async K/V prefetch; XCD swizzle.
// ---------------------------------------------------------------------------
__global__ __launch_bounds__(512) void attn_kernel(const u16* __restrict__ qp,
                                                   const u16* __restrict__ kp,
                                                   const u16* __restrict__ vpT,
                                                   u16* __restrict__ ctx) {
  constexpr int KB = 64;
  constexpr int NT = kS / KB;   // 32 tiles
  constexpr int PST = 72;       // P row stride (elems, 16B-aligned rows)
  constexpr float THR = 11.5f;  // defer-max threshold (log2 units ~ e^8)

  __shared__ u16 Kls[KB * 128];        // 16 KB [key][d] chunk-swizzled
  __shared__ u16 Vt[kD * KB];          // 16 KB [d][key] chunk-swizzled
  __shared__ u16 Pls[8][2 * 16 * PST]; // 36 KB per-wave P tiles [q][key]

  const int tid = threadIdx.x, lane = tid & 63, w = tid >> 6;  // w: 0..7
  const int fr = lane & 15, fq = lane >> 4;

  const int wg = blockIdx.y * 8 + blockIdx.x;
  const int o = (wg & 7) * 64 + (wg >> 3);
  const int bh = o >> 3;
  const int b = bh >> 5, h = bh & 31;
  const int q0 = (o & 7) * 256;

  const u16* qbase = qp + ((size_t)b * kS) * kDM + h * kD;
  const u16* kbase = kp + ((size_t)b * kS) * kDM + h * kD;
  const u16* vtbase = vpT + (size_t)(h * kD) * kDM + b * kS;  // row d, stride kDM

  bf16x8 qf[2][4];
#pragma unroll
  for (int rb = 0; rb < 2; ++rb)
#pragma unroll
    for (int kc = 0; kc < 4; ++kc) {
      const u16x8 raw = *(const u16x8*)(qbase +
          (size_t)(q0 + w * 32 + rb * 16 + fr) * kDM + kc * 32 + fq * 8);
      bf16x8 s;
#pragma unroll
      for (int j = 0; j < 8; ++j) s[j] = (short)f2bf(bf2f(raw[j]) * kScaleLog2e);
      qf[rb][kc] = s;
    }

  f32x4 oacc[2][9] = {};
  float mrun[2] = {-1e30f, -1e30f};

  bf16x8 ones;
#pragma unroll
  for (int j = 0; j < 8; ++j) ones[j] = (short)0x3F80;  // bf16 1.0

  const int krl = lane >> 4, kdp = lane & 15;
  const int vdl = lane >> 3, vc = lane & 7;
  const int rk0 = (w * 2 + 0) * 4 + krl;
  const int rk1 = (w * 2 + 1) * 4 + krl;
  const int dv0 = (w * 2 + 0) * 8 + vdl;
  const int dv1 = (w * 2 + 1) * 8 + vdl;
  const u16* kg0 = kbase + (size_t)rk0 * kDM + kdp * 8;
  const u16* kg1 = kbase + (size_t)rk1 * kDM + kdp * 8;
  const u16* vg0 = vtbase + (size_t)dv0 * kDM + vc * 8;
  const u16* vg1 = vtbase + (size_t)dv1 * kDM + vc * 8;
  u16* kl0 = &Kls[rk0 * 128 + ((kdp ^ (rk0 & 7)) * 8)];
  u16* kl1 = &Kls[rk1 * 128 + ((kdp ^ (rk1 & 7)) * 8)];
  u16* vl0 = &Vt[dv0 * KB + ((vc ^ (dv0 & 7)) * 8)];
  u16* vl1 = &Vt[dv1 * KB + ((vc ^ (dv1 & 7)) * 8)];

  u16x8 kr0v, kr1v, vr0v, vr1v;
  kr0v = *(const u16x8*)kg0;
  kr1v = *(const u16x8*)kg1;
  vr0v = *(const u16x8*)vg0;
  vr1v = *(const u16x8*)vg1;
  *(u16x8*)kl0 = kr0v; *(u16x8*)kl1 = kr1v;
  *(u16x8*)vl0 = vr0v; *(u16x8*)vl1 = vr1v;
  __syncthreads();

  for (int kt = 0; kt < NT; ++kt) {
    if (kt + 1 < NT) {
      const size_t ko = (size_t)(kt + 1) * KB;
      kr0v = *(const u16x8*)(kg0 + ko * kDM);
      kr1v = *(const u16x8*)(kg1 + ko * kDM);
      vr0v = *(const u16x8*)(vg0 + ko);
      vr1v = *(const u16x8*)(vg1 + ko);
    }

    // --- QK^T (swapped: mfma(K, Q)) ---
    f32x4 sacc[2][4] = {};
#pragma unroll
    for (int cb = 0; cb < 4; ++cb) {
      const int n = cb * 16 + fr;
      bf16x8 kf[4];
#pragma unroll
      for (int kc = 0; kc < 4; ++kc) {
        const int d0 = kc * 4 + fq;
        kf[kc] = *(const bf16x8*)&Kls[n * 128 + (d0 ^ (n & 7)) * 8];
      }
      __builtin_amdgcn_s_setprio(1);
#pragma unroll
      for (int rb = 0; rb < 2; ++rb)
#pragma unroll
        for (int kc = 0; kc < 4; ++kc)
          sacc[rb][cb] = MFMA_BF16(kf[kc], qf[rb][kc], sacc[rb][cb]);
      __builtin_amdgcn_s_setprio(0);
    }

    // --- online softmax: lane owns row q=fr; keys = cb*16 + fq*4 + i ---
#pragma unroll
    for (int rb = 0; rb < 2; ++rb) {
      float m = sacc[rb][0][0];
#pragma unroll
      for (int cb = 0; cb < 4; ++cb)
#pragma unroll
        for (int i = 0; i < 4; ++i) m = fmaxf(m, sacc[rb][cb][i]);
      m = fmaxf(m, __shfl_xor(m, 16));
      m = fmaxf(m, __shfl_xor(m, 32));

      if (__any(m - mrun[rb] > THR)) {
        const float mnew = fmaxf(mrun[rb], m);
        const float sclS = exp2f(mrun[rb] - mnew);
        mrun[rb] = mnew;
        float scl[4];
#pragma unroll
        for (int i = 0; i < 4; ++i) scl[i] = __shfl(sclS, fq * 4 + i);
#pragma unroll
        for (int db = 0; db < 9; ++db)
#pragma unroll
          for (int i = 0; i < 4; ++i) oacc[rb][db][i] *= scl[i];
      }

#pragma unroll
      for (int cb = 0; cb < 4; ++cb) {
        u16x4 pk;
#pragma unroll
        for (int i = 0; i < 4; ++i)
          pk[i] = nbf(exp2f(sacc[rb][cb][i] - mrun[rb]));
        *(u16x4*)&Pls[w][rb * (16 * PST) + fr * PST + cb * 16 + fq * 4] = pk;
      }
    }

    asm volatile("s_waitcnt lgkmcnt(0)" ::: "memory");

    // --- PV (+ denom via ones-V) ---
    bf16x8 pf[2][2];
#pragma unroll
    for (int rb = 0; rb < 2; ++rb)
#pragma unroll
      for (int kb = 0; kb < 2; ++kb)
        pf[rb][kb] = *(const bf16x8*)&Pls[w][rb * (16 * PST) + fr * PST + kb * 32 + fq * 8];
#pragma unroll
    for (int db = 0; db < 8; ++db) {
      const int d = db * 16 + fr;
      bf16x8 vf0 = *(const bf16x8*)&Vt[d * KB + ((fq ^ (d & 7)) << 3)];
      bf16x8 vf1 = *(const bf16x8*)&Vt[d * KB + (((4 + fq) ^ (d & 7)) << 3)];
      __builtin_amdgcn_s_setprio(1);
#pragma unroll
      for (int rb = 0; rb < 2; ++rb) {
        oacc[rb][db] = MFMA_BF16(pf[rb][0], vf0, oacc[rb][db]);
        oacc[rb][db] = MFMA_BF16(pf[rb][1], vf1, oacc[rb][db]);
      }
      __builtin_amdgcn_s_setprio(0);
    }
    __builtin_amdgcn_s_setprio(1);
#pragma unroll
    for (int rb = 0; rb < 2; ++rb) {
      oacc[rb][8] = MFMA_BF16(pf[rb][0], ones, oacc[rb][8]);
      oacc[rb][8] = MFMA_BF16(pf[rb][1], ones, oacc[rb][8]);
    }
    __builtin_amdgcn_s_setprio(0);

    __syncthreads();
    if (kt + 1 < NT) {
      *(u16x8*)kl0 = kr0v; *(u16x8*)kl1 = kr1v;
      *(u16x8*)vl0 = vr0v; *(u16x8*)vl1 = vr1v;
    }
    __syncthreads();
  }

  u16* cbase = ctx + ((size_t)b * kS) * kDM + h * kD;
#pragma unroll
  for (int rb = 0; rb < 2; ++rb) {
    float inv[4];
#pragma unroll
    for (int i = 0; i < 4; ++i) inv[i] = 1.0f / oacc[rb][8][i];
#pragma unroll
    for (int db = 0; db < 8; ++db)
#pragma unroll
      for (int i = 0; i < 4; ++i) {
        const int row = q0 + w * 32 + rb * 16 + fq * 4 + i;
        const int col = db * 16 + fr;
        cbase[(size_t)row * kDM + col] = nbf(oacc[rb][db][i] * inv[i]);
      }
  }
}

// ---------------------------------------------------------------------------
extern "C" void kernel_launch(void* const* d_in, const int* in_sizes, int n_in,
                              void* d_out, int out_size, void* d_ws, size_t ws_size,
                              hipStream_t stream) {
  const float* q = (const float*)d_in[0];
  const float* k = (const float*)d_in[1];
  const float* v = (const float*)d_in[2];
  const float* Wq = (const float*)d_in[3];
  const float* Wk = (const float*)d_in[4];
  const float* Wv = (const float*)d_in[5];
  const float* Wo = (const float*)d_in[6];
  float* out = (float*)d_out;

  const size_t needFast = 11 * kMat * sizeof(u16);  // 7 bf16 inputs + qp/kp/vpT/ctx

  if (ws_size >= needFast) {
    u16* wsb = (u16*)d_ws;            // [0..6]: qb kb vb Wqb Wkb Wvb Wob
    u16* qp = wsb + 7 * kMat;
    u16* kp = wsb + 8 * kMat;
    u16* vpT = wsb + 9 * kMat;
    u16* ctx = wsb + 10 * kMat;

    cvt_kernel<<<dim3(1024, 7), 256, 0, stream>>>(q, k, v, Wq, Wk, Wv, Wo, wsb);
    proj_qk256_kernel<<<dim3(16, 16, 2), 512, 0, stream>>>(wsb, qp, kp);
    proj_vT256_kernel<<<dim3(16, 16), 512, 0, stream>>>(wsb, vpT);
    attn_kernel<<<dim3(8, 64), 512, 0, stream>>>(qp, kp, vpT, ctx);
    out_proj256_kernel<<<dim3(16, 16), 512, 0, stream>>>(ctx, wsb + 6 * kMat, out);
  } else {
    u16* qp = (u16*)d_ws;
    u16* kp = qp + kMat;
    u16* vpT = kp + kMat;
    u16* ctx = vpT + kMat;

    proj_qk_conv_kernel<<<dim3(32, 32, 2), 256, 0, stream>>>(q, k, Wq, Wk, qp, kp);
    proj_vT_conv_kernel<<<dim3(32, 32), 256, 0, stream>>>(v, Wv, vpT);
    attn_kernel<<<dim3(8, 64), 512, 0, stream>>>(qp, kp, vpT, ctx);
    out_proj_conv_kernel<<<dim3(32, 32, 1), 256, 0, stream>>>(ctx, Wo, out);
  }
}